// Round 1
// baseline (2231.745 us; speedup 1.0000x reference)
//
#include <hip/hip_runtime.h>
#include <hip/hip_bf16.h>

// Dims (compile-time constants from the reference)
#define D_MODEL 1024
#define D_STATE 16
#define D_CONV  4
#define D_INNER 2048
#define DT_RANK 64
#define BATCH   2
#define SEQLEN  1024
#define NROWS   (BATCH * SEQLEN)        // 2048
#define XDBL_W  (DT_RANK + 2 * D_STATE) // 96

// ---------------------------------------------------------------------------
// LayerNorm: one block per row of 1024, 256 threads x float4
// ---------------------------------------------------------------------------
__global__ __launch_bounds__(256)
void layernorm_kernel(const float* __restrict__ x, const float* __restrict__ g,
                      const float* __restrict__ bb, float* __restrict__ xn)
{
    int row = blockIdx.x;
    const float* xr = x + (size_t)row * D_MODEL;
    int tid = threadIdx.x;
    float4 v = reinterpret_cast<const float4*>(xr)[tid];
    float s  = v.x + v.y + v.z + v.w;
    float ss = v.x * v.x + v.y * v.y + v.z * v.z + v.w * v.w;
    #pragma unroll
    for (int off = 32; off; off >>= 1) {
        s  += __shfl_down(s, off);
        ss += __shfl_down(ss, off);
    }
    __shared__ float sbuf[4], ssbuf[4];
    int wid = tid >> 6, lane = tid & 63;
    if (lane == 0) { sbuf[wid] = s; ssbuf[wid] = ss; }
    __syncthreads();
    if (tid == 0) {
        float st = 0.f, sst = 0.f;
        #pragma unroll
        for (int i = 0; i < 4; ++i) { st += sbuf[i]; sst += ssbuf[i]; }
        sbuf[0] = st; ssbuf[0] = sst;
    }
    __syncthreads();
    float mu  = sbuf[0] * (1.f / D_MODEL);
    float var = ssbuf[0] * (1.f / D_MODEL) - mu * mu;
    float inv = rsqrtf(var + 1e-5f);
    float4 gv = reinterpret_cast<const float4*>(g)[tid];
    float4 bv = reinterpret_cast<const float4*>(bb)[tid];
    float4 o;
    o.x = (v.x - mu) * inv * gv.x + bv.x;
    o.y = (v.y - mu) * inv * gv.y + bv.y;
    o.z = (v.z - mu) * inv * gv.z + bv.z;
    o.w = (v.w - mu) * inv * gv.w + bv.w;
    reinterpret_cast<float4*>(xn + (size_t)row * D_MODEL)[tid] = o;
}

// ---------------------------------------------------------------------------
// Generic fp32 tiled GEMM: C[M,N] = A[M,K] @ B[K,N] (+ optional residual)
// 64x64 tile, K-step 16, 256 threads, each 4x4
// ---------------------------------------------------------------------------
template<bool RESIDUAL>
__global__ __launch_bounds__(256)
void gemm_tiled(const float* __restrict__ A, const float* __restrict__ B,
                float* __restrict__ C,
                int M, int N, int K, int lda, int ldb, int ldc,
                const float* __restrict__ xres, const float* __restrict__ res_scale)
{
    __shared__ float As[16][68];
    __shared__ float Bs[16][64];
    int tid = threadIdx.x;
    int tx = tid & 15, ty = tid >> 4;
    int row0 = blockIdx.y * 64, col0 = blockIdx.x * 64;
    float acc[4][4] = {};

    for (int k0 = 0; k0 < K; k0 += 16) {
        // A tile: 64 rows x 16 k. consecutive tid -> consecutive k (coalesced)
        {
            int kk = tid & 15;
            int m0 = tid >> 4;
            #pragma unroll
            for (int r = 0; r < 4; ++r) {
                int mm = m0 + 16 * r;
                int grow = row0 + mm, gk = k0 + kk;
                float v = 0.f;
                if (grow < M && gk < K) v = A[(size_t)grow * lda + gk];
                As[kk][mm] = v;
            }
        }
        // B tile: 16 k x 64 n. consecutive tid -> consecutive n (coalesced)
        {
            int nn = tid & 63;
            int kb = tid >> 6;
            #pragma unroll
            for (int r = 0; r < 4; ++r) {
                int kk = kb + 4 * r;
                int gk = k0 + kk, gcol = col0 + nn;
                float v = 0.f;
                if (gk < K && gcol < N) v = B[(size_t)gk * ldb + gcol];
                Bs[kk][nn] = v;
            }
        }
        __syncthreads();
        #pragma unroll
        for (int kk = 0; kk < 16; ++kk) {
            float4 a4 = *reinterpret_cast<const float4*>(&As[kk][ty * 4]);
            float4 b4 = *reinterpret_cast<const float4*>(&Bs[kk][tx * 4]);
            float av[4] = {a4.x, a4.y, a4.z, a4.w};
            float bv[4] = {b4.x, b4.y, b4.z, b4.w};
            #pragma unroll
            for (int i = 0; i < 4; ++i)
                #pragma unroll
                for (int j = 0; j < 4; ++j)
                    acc[i][j] += av[i] * bv[j];
        }
        __syncthreads();
    }

    float rs = RESIDUAL ? res_scale[0] : 0.f;
    #pragma unroll
    for (int i = 0; i < 4; ++i) {
        int r = row0 + ty * 4 + i;
        if (r >= M) continue;
        #pragma unroll
        for (int j = 0; j < 4; ++j) {
            int c = col0 + tx * 4 + j;
            if (c >= N) continue;
            float v = acc[i][j];
            if (RESIDUAL) v = xres[(size_t)r * ldc + c] + rs * v;
            C[(size_t)r * ldc + c] = v;
        }
    }
}

// ---------------------------------------------------------------------------
// Depthwise causal conv (K=4) + bias + SiLU. One thread per (b,l,e).
// u lives in xz columns [0, 2048).
// ---------------------------------------------------------------------------
__global__ __launch_bounds__(256)
void conv_silu_kernel(const float* __restrict__ xz, const float* __restrict__ cw,
                      const float* __restrict__ cb, float* __restrict__ u2)
{
    int idx = blockIdx.x * 256 + threadIdx.x;   // < 2*1024*2048
    int e = idx & (D_INNER - 1);
    int l = (idx >> 11) & (SEQLEN - 1);
    int b = idx >> 21;
    const float* base = xz + (size_t)b * SEQLEN * (2 * D_INNER) + e;
    float w0 = cw[e * 4 + 0], w1 = cw[e * 4 + 1];
    float w2 = cw[e * 4 + 2], w3 = cw[e * 4 + 3];
    float acc = cb[e];
    if (l >= 3) acc += base[(size_t)(l - 3) * (2 * D_INNER)] * w0;
    if (l >= 2) acc += base[(size_t)(l - 2) * (2 * D_INNER)] * w1;
    if (l >= 1) acc += base[(size_t)(l - 1) * (2 * D_INNER)] * w2;
    acc += base[(size_t)l * (2 * D_INNER)] * w3;
    float sv = acc / (1.f + expf(-acc));        // SiLU
    u2[idx] = sv;
}

// ---------------------------------------------------------------------------
// Selective scan. 16 lanes per (b,e) channel (lane = state n), 16 channels
// per block. Fuses: dt = softplus(dt_raw + b_dt), D-skip, SiLU(z) gating.
// Writes y in-place over u2.
// ---------------------------------------------------------------------------
__global__ __launch_bounds__(256)
void scan_kernel(const float* __restrict__ dtraw, const float* __restrict__ xdbl,
                 const float* __restrict__ xz, float* __restrict__ u2y,
                 const float* __restrict__ b_dt, const float* __restrict__ A_log,
                 const float* __restrict__ D_param)
{
    int tid = threadIdx.x;
    int g = tid >> 4;            // group within block
    int n = tid & 15;            // state index
    int p = blockIdx.x * 16 + g; // (b,e) pair, 0..4095
    int b = p >> 11;
    int e = p & (D_INNER - 1);
    float An  = -expf(A_log[e * D_STATE + n]);
    float De  = D_param[e];
    float bdt = b_dt[e];
    float h = 0.f;
    size_t rowbase = (size_t)b * SEQLEN;
    for (int l = 0; l < SEQLEN; ++l) {
        size_t row = rowbase + l;
        float dtr = dtraw[row * D_INNER + e] + bdt;
        float dt  = (dtr > 20.f) ? dtr : log1pf(expf(dtr));
        float u   = u2y[row * D_INNER + e];
        float Bn  = xdbl[row * XDBL_W + DT_RANK + n];
        float Cn  = xdbl[row * XDBL_W + DT_RANK + D_STATE + n];
        float dA  = expf(dt * An);
        h = dA * h + (dt * u) * Bn;
        float ps = h * Cn;
        ps += __shfl_xor(ps, 1, 16);
        ps += __shfl_xor(ps, 2, 16);
        ps += __shfl_xor(ps, 4, 16);
        ps += __shfl_xor(ps, 8, 16);
        if (n == 0) {
            float z  = xz[row * (2 * D_INNER) + D_INNER + e];
            float sz = z / (1.f + expf(-z));
            u2y[row * D_INNER + e] = (ps + u * De) * sz;
        }
    }
}

// ---------------------------------------------------------------------------
extern "C" void kernel_launch(void* const* d_in, const int* in_sizes, int n_in,
                              void* d_out, int out_size, void* d_ws, size_t ws_size,
                              hipStream_t stream)
{
    const float* x       = (const float*)d_in[0];
    const float* ln_g    = (const float*)d_in[1];
    const float* ln_b    = (const float*)d_in[2];
    const float* W_in    = (const float*)d_in[3];
    const float* conv_w  = (const float*)d_in[4];
    const float* conv_b  = (const float*)d_in[5];
    const float* W_xp    = (const float*)d_in[6];
    const float* W_dt    = (const float*)d_in[7];
    const float* b_dt    = (const float*)d_in[8];
    const float* A_log   = (const float*)d_in[9];
    const float* D_param = (const float*)d_in[10];
    const float* W_out   = (const float*)d_in[11];
    const float* res_sc  = (const float*)d_in[12];
    float* out = (float*)d_out;

    char* ws = (char*)d_ws;
    // Workspace layout (bytes):
    //   xz     : [0, 32M)         2048 x 4096 fp32
    //   u2/y   : [32M, 48M)       2048 x 2048 fp32 (y written in-place by scan)
    //   dt_raw : [48M, 64M)       2048 x 2048 fp32  -- shares space with xn
    //   xn     : [48M, 56M)       2048 x 1024 fp32  (dead before dt_raw written)
    //   xdbl   : [64M, 64.75M)    2048 x 96 fp32
    float* xz    = (float*)(ws);
    float* u2    = (float*)(ws + (size_t)32 * 1024 * 1024);
    float* dtraw = (float*)(ws + (size_t)48 * 1024 * 1024);
    float* xn    = (float*)(ws + (size_t)48 * 1024 * 1024);
    float* xdbl  = (float*)(ws + (size_t)64 * 1024 * 1024);

    // 1. LayerNorm
    layernorm_kernel<<<NROWS, 256, 0, stream>>>(x, ln_g, ln_b, xn);

    // 2. xz = xn @ W_in   [2048 x 4096, K=1024]
    {
        dim3 grid((2 * D_INNER) / 64, NROWS / 64);
        gemm_tiled<false><<<grid, 256, 0, stream>>>(
            xn, W_in, xz, NROWS, 2 * D_INNER, D_MODEL,
            D_MODEL, 2 * D_INNER, 2 * D_INNER, nullptr, nullptr);
    }

    // 3. u2 = silu(causal_conv(u) + conv_b)
    conv_silu_kernel<<<(BATCH * SEQLEN * D_INNER) / 256, 256, 0, stream>>>(
        xz, conv_w, conv_b, u2);

    // 4. xdbl = u2 @ W_xp  [2048 x 96, K=2048]
    {
        dim3 grid((XDBL_W + 63) / 64, NROWS / 64);
        gemm_tiled<false><<<grid, 256, 0, stream>>>(
            u2, W_xp, xdbl, NROWS, XDBL_W, D_INNER,
            D_INNER, XDBL_W, XDBL_W, nullptr, nullptr);
    }

    // 5. dt_raw = xdbl[:, :64] @ W_dt  [2048 x 2048, K=64]
    {
        dim3 grid(D_INNER / 64, NROWS / 64);
        gemm_tiled<false><<<grid, 256, 0, stream>>>(
            xdbl, W_dt, dtraw, NROWS, D_INNER, DT_RANK,
            XDBL_W, D_INNER, D_INNER, nullptr, nullptr);
    }

    // 6. selective scan (+softplus, +D skip, +silu(z) gate), y in-place in u2
    scan_kernel<<<(BATCH * D_INNER) / 16, 256, 0, stream>>>(
        dtraw, xdbl, xz, u2, b_dt, A_log, D_param);

    // 7. out = x + res_scale * (y @ W_out)  [2048 x 1024, K=2048]
    {
        dim3 grid(D_MODEL / 64, NROWS / 64);
        gemm_tiled<true><<<grid, 256, 0, stream>>>(
            u2, W_out, out, NROWS, D_MODEL, D_INNER,
            D_INNER, D_MODEL, D_MODEL, x, res_sc);
    }
}

// Round 2
// 1489.419 us; speedup vs baseline: 1.4984x; 1.4984x over previous
//
#include <hip/hip_runtime.h>
#include <hip/hip_bf16.h>

// Dims (compile-time constants from the reference)
#define D_MODEL 1024
#define D_STATE 16
#define D_CONV  4
#define D_INNER 2048
#define DT_RANK 64
#define BATCH   2
#define SEQLEN  1024
#define NROWS   (BATCH * SEQLEN)        // 2048
#define XDBL_W  (DT_RANK + 2 * D_STATE) // 96
#define NCHUNK  64                      // chunks per sequence
#define LCHUNK  16                      // steps per chunk
#define NCHAN   (BATCH * D_INNER)       // 4096 (b,e) channels

// ---------------------------------------------------------------------------
// LayerNorm: one block per row of 1024, 256 threads x float4
// ---------------------------------------------------------------------------
__global__ __launch_bounds__(256)
void layernorm_kernel(const float* __restrict__ x, const float* __restrict__ g,
                      const float* __restrict__ bb, float* __restrict__ xn)
{
    int row = blockIdx.x;
    const float* xr = x + (size_t)row * D_MODEL;
    int tid = threadIdx.x;
    float4 v = reinterpret_cast<const float4*>(xr)[tid];
    float s  = v.x + v.y + v.z + v.w;
    float ss = v.x * v.x + v.y * v.y + v.z * v.z + v.w * v.w;
    #pragma unroll
    for (int off = 32; off; off >>= 1) {
        s  += __shfl_down(s, off);
        ss += __shfl_down(ss, off);
    }
    __shared__ float sbuf[4], ssbuf[4];
    int wid = tid >> 6, lane = tid & 63;
    if (lane == 0) { sbuf[wid] = s; ssbuf[wid] = ss; }
    __syncthreads();
    if (tid == 0) {
        float st = 0.f, sst = 0.f;
        #pragma unroll
        for (int i = 0; i < 4; ++i) { st += sbuf[i]; sst += ssbuf[i]; }
        sbuf[0] = st; ssbuf[0] = sst;
    }
    __syncthreads();
    float mu  = sbuf[0] * (1.f / D_MODEL);
    float var = ssbuf[0] * (1.f / D_MODEL) - mu * mu;
    float inv = rsqrtf(var + 1e-5f);
    float4 gv = reinterpret_cast<const float4*>(g)[tid];
    float4 bv = reinterpret_cast<const float4*>(bb)[tid];
    float4 o;
    o.x = (v.x - mu) * inv * gv.x + bv.x;
    o.y = (v.y - mu) * inv * gv.y + bv.y;
    o.z = (v.z - mu) * inv * gv.z + bv.z;
    o.w = (v.w - mu) * inv * gv.w + bv.w;
    reinterpret_cast<float4*>(xn + (size_t)row * D_MODEL)[tid] = o;
}

// ---------------------------------------------------------------------------
// Generic fp32 tiled GEMM: C[M,N] = A[M,K] @ B[K,N] (+ optional residual)
// 64x64 tile, K-step 16, 256 threads, each 4x4
// ---------------------------------------------------------------------------
template<bool RESIDUAL>
__global__ __launch_bounds__(256)
void gemm_tiled(const float* __restrict__ A, const float* __restrict__ B,
                float* __restrict__ C,
                int M, int N, int K, int lda, int ldb, int ldc,
                const float* __restrict__ xres, const float* __restrict__ res_scale)
{
    __shared__ float As[16][68];
    __shared__ float Bs[16][64];
    int tid = threadIdx.x;
    int tx = tid & 15, ty = tid >> 4;
    int row0 = blockIdx.y * 64, col0 = blockIdx.x * 64;
    float acc[4][4] = {};

    for (int k0 = 0; k0 < K; k0 += 16) {
        {
            int kk = tid & 15;
            int m0 = tid >> 4;
            #pragma unroll
            for (int r = 0; r < 4; ++r) {
                int mm = m0 + 16 * r;
                int grow = row0 + mm, gk = k0 + kk;
                float v = 0.f;
                if (grow < M && gk < K) v = A[(size_t)grow * lda + gk];
                As[kk][mm] = v;
            }
        }
        {
            int nn = tid & 63;
            int kb = tid >> 6;
            #pragma unroll
            for (int r = 0; r < 4; ++r) {
                int kk = kb + 4 * r;
                int gk = k0 + kk, gcol = col0 + nn;
                float v = 0.f;
                if (gk < K && gcol < N) v = B[(size_t)gk * ldb + gcol];
                Bs[kk][nn] = v;
            }
        }
        __syncthreads();
        #pragma unroll
        for (int kk = 0; kk < 16; ++kk) {
            float4 a4 = *reinterpret_cast<const float4*>(&As[kk][ty * 4]);
            float4 b4 = *reinterpret_cast<const float4*>(&Bs[kk][tx * 4]);
            float av[4] = {a4.x, a4.y, a4.z, a4.w};
            float bv[4] = {b4.x, b4.y, b4.z, b4.w};
            #pragma unroll
            for (int i = 0; i < 4; ++i)
                #pragma unroll
                for (int j = 0; j < 4; ++j)
                    acc[i][j] += av[i] * bv[j];
        }
        __syncthreads();
    }

    float rs = RESIDUAL ? res_scale[0] : 0.f;
    #pragma unroll
    for (int i = 0; i < 4; ++i) {
        int r = row0 + ty * 4 + i;
        if (r >= M) continue;
        #pragma unroll
        for (int j = 0; j < 4; ++j) {
            int c = col0 + tx * 4 + j;
            if (c >= N) continue;
            float v = acc[i][j];
            if (RESIDUAL) v = xres[(size_t)r * ldc + c] + rs * v;
            C[(size_t)r * ldc + c] = v;
        }
    }
}

// ---------------------------------------------------------------------------
// Depthwise causal conv (K=4) + bias + SiLU. One thread per (b,l,e).
// ---------------------------------------------------------------------------
__global__ __launch_bounds__(256)
void conv_silu_kernel(const float* __restrict__ xz, const float* __restrict__ cw,
                      const float* __restrict__ cb, float* __restrict__ u2)
{
    int idx = blockIdx.x * 256 + threadIdx.x;   // < 2*1024*2048
    int e = idx & (D_INNER - 1);
    int l = (idx >> 11) & (SEQLEN - 1);
    int b = idx >> 21;
    const float* base = xz + (size_t)b * SEQLEN * (2 * D_INNER) + e;
    float w0 = cw[e * 4 + 0], w1 = cw[e * 4 + 1];
    float w2 = cw[e * 4 + 2], w3 = cw[e * 4 + 3];
    float acc = cb[e];
    if (l >= 3) acc += base[(size_t)(l - 3) * (2 * D_INNER)] * w0;
    if (l >= 2) acc += base[(size_t)(l - 2) * (2 * D_INNER)] * w1;
    if (l >= 1) acc += base[(size_t)(l - 1) * (2 * D_INNER)] * w2;
    acc += base[(size_t)l * (2 * D_INNER)] * w3;
    float sv = acc / (1.f + expf(-acc));        // SiLU
    u2[idx] = sv;
}

// ---------------------------------------------------------------------------
// Chunked parallel scan, pass A: per-chunk partials from h=0.
// 16 lanes per (channel, chunk) unit; block = 16 consecutive channels at one
// chunk (so dt/u loads per wave hit one cache line).
// Writes hend[p][c][n] and sumdt[p][c].
// ---------------------------------------------------------------------------
__global__ __launch_bounds__(256)
void scan_partial_kernel(const float* __restrict__ dtraw, const float* __restrict__ xdbl,
                         const float* __restrict__ u2,
                         const float* __restrict__ b_dt, const float* __restrict__ A_log,
                         float* __restrict__ hend, float* __restrict__ sumdt_buf)
{
    int tid = threadIdx.x;
    int g = tid >> 4, n = tid & 15;
    int c = blockIdx.x >> 8;                     // chunk 0..63
    int p = ((blockIdx.x & 255) << 4) + g;       // channel 0..4095
    int b = p >> 11, e = p & (D_INNER - 1);
    float An  = -expf(A_log[e * D_STATE + n]);
    float bdt = b_dt[e];
    float h = 0.f, sdt = 0.f;
    size_t rowbase = (size_t)b * SEQLEN + c * LCHUNK;
    #pragma unroll
    for (int j = 0; j < LCHUNK; ++j) {
        size_t row = rowbase + j;
        float dtr = dtraw[row * D_INNER + e] + bdt;
        float dt  = (dtr > 20.f) ? dtr : log1pf(expf(dtr));
        sdt += dt;
        float u  = u2[row * D_INNER + e];
        float Bn = xdbl[row * XDBL_W + DT_RANK + n];
        h = expf(dt * An) * h + (dt * u) * Bn;
    }
    hend[(size_t)p * (NCHUNK * D_STATE) + c * D_STATE + n] = h;
    if (n == 0) sumdt_buf[p * NCHUNK + c] = sdt;
}

// ---------------------------------------------------------------------------
// Pass B: per-channel inter-chunk scan (Hillis-Steele over 64 affine maps
// (P,H), P = exp(A_n * sumdt_chunk)). Writes the EXCLUSIVE carry in place
// over hend.
// ---------------------------------------------------------------------------
__global__ __launch_bounds__(1024)
void scan_combine_kernel(const float* __restrict__ A_log,
                         const float* __restrict__ sumdt_buf,
                         float* __restrict__ hend /* in: hend, out: hcarry */)
{
    __shared__ float Ps[NCHUNK][D_STATE];
    __shared__ float Hs[NCHUNK][D_STATE];
    int tid = threadIdx.x;
    int c = tid >> 4, n = tid & 15;
    int p = blockIdx.x;
    int e = p & (D_INNER - 1);
    float An = -expf(A_log[e * D_STATE + n]);
    float P = expf(An * sumdt_buf[p * NCHUNK + c]);
    float H = hend[(size_t)p * (NCHUNK * D_STATE) + c * D_STATE + n];
    Ps[c][n] = P; Hs[c][n] = H;
    __syncthreads();
    #pragma unroll
    for (int d = 1; d < NCHUNK; d <<= 1) {
        float Pl = 1.f, Hl = 0.f;
        if (c >= d) { Pl = Ps[c - d][n]; Hl = Hs[c - d][n]; }
        __syncthreads();
        H = P * Hl + H;   // (P,H) ∘ (Pl,Hl)
        P = P * Pl;
        Ps[c][n] = P; Hs[c][n] = H;
        __syncthreads();
    }
    float carry = (c == 0) ? 0.f : Hs[c - 1][n];
    hend[(size_t)p * (NCHUNK * D_STATE) + c * D_STATE + n] = carry;
}

// ---------------------------------------------------------------------------
// Pass C: re-scan each chunk seeded with its carry; fuse softplus, D-skip,
// SiLU(z) gate; write y IN PLACE over u2 (each (row,e) read-then-written by
// exactly one unit; block's 16 units cover one 64B line per step).
// ---------------------------------------------------------------------------
__global__ __launch_bounds__(256)
void scan_final_kernel(const float* __restrict__ dtraw, const float* __restrict__ xdbl,
                       const float* __restrict__ xz, float* __restrict__ u2y,
                       const float* __restrict__ b_dt, const float* __restrict__ A_log,
                       const float* __restrict__ D_param,
                       const float* __restrict__ hcarry)
{
    int tid = threadIdx.x;
    int g = tid >> 4, n = tid & 15;
    int c = blockIdx.x >> 8;
    int p = ((blockIdx.x & 255) << 4) + g;
    int b = p >> 11, e = p & (D_INNER - 1);
    float An  = -expf(A_log[e * D_STATE + n]);
    float bdt = b_dt[e];
    float De  = D_param[e];
    float h = hcarry[(size_t)p * (NCHUNK * D_STATE) + c * D_STATE + n];
    size_t rowbase = (size_t)b * SEQLEN + c * LCHUNK;
    #pragma unroll
    for (int j = 0; j < LCHUNK; ++j) {
        size_t row = rowbase + j;
        float dtr = dtraw[row * D_INNER + e] + bdt;
        float dt  = (dtr > 20.f) ? dtr : log1pf(expf(dtr));
        float u   = u2y[row * D_INNER + e];
        float Bn  = xdbl[row * XDBL_W + DT_RANK + n];
        float Cn  = xdbl[row * XDBL_W + DT_RANK + D_STATE + n];
        h = expf(dt * An) * h + (dt * u) * Bn;
        float ps = h * Cn;
        ps += __shfl_xor(ps, 1, 16);
        ps += __shfl_xor(ps, 2, 16);
        ps += __shfl_xor(ps, 4, 16);
        ps += __shfl_xor(ps, 8, 16);
        if (n == j) {
            float z  = xz[row * (2 * D_INNER) + D_INNER + e];
            float sz = z / (1.f + expf(-z));
            u2y[row * D_INNER + e] = (ps + u * De) * sz;
        }
    }
}

// ---------------------------------------------------------------------------
extern "C" void kernel_launch(void* const* d_in, const int* in_sizes, int n_in,
                              void* d_out, int out_size, void* d_ws, size_t ws_size,
                              hipStream_t stream)
{
    const float* x       = (const float*)d_in[0];
    const float* ln_g    = (const float*)d_in[1];
    const float* ln_b    = (const float*)d_in[2];
    const float* W_in    = (const float*)d_in[3];
    const float* conv_w  = (const float*)d_in[4];
    const float* conv_b  = (const float*)d_in[5];
    const float* W_xp    = (const float*)d_in[6];
    const float* W_dt    = (const float*)d_in[7];
    const float* b_dt    = (const float*)d_in[8];
    const float* A_log   = (const float*)d_in[9];
    const float* D_param = (const float*)d_in[10];
    const float* W_out   = (const float*)d_in[11];
    const float* res_sc  = (const float*)d_in[12];
    float* out = (float*)d_out;

    char* ws = (char*)d_ws;
    // Workspace layout (bytes):
    //   xz     : [0, 32M)         2048 x 4096 fp32
    //   u2/y   : [32M, 48M)       2048 x 2048 fp32 (y written in-place, pass C)
    //   dt_raw : [48M, 64M)       2048 x 2048 fp32  -- shares space with xn
    //   xn     : [48M, 56M)       2048 x 1024 fp32  (dead before dt_raw written)
    //   xdbl   : [64M, 64.75M)    2048 x 96 fp32
    //   hend   : [65M, 81M)       4096 x 64 x 16 fp32 (carry written in place)
    //   sumdt  : [81M, 82M)       4096 x 64 fp32
    float* xz    = (float*)(ws);
    float* u2    = (float*)(ws + (size_t)32 * 1024 * 1024);
    float* dtraw = (float*)(ws + (size_t)48 * 1024 * 1024);
    float* xn    = (float*)(ws + (size_t)48 * 1024 * 1024);
    float* xdbl  = (float*)(ws + (size_t)64 * 1024 * 1024);
    float* hend  = (float*)(ws + (size_t)65 * 1024 * 1024);
    float* sumdt = (float*)(ws + (size_t)81 * 1024 * 1024);

    // 1. LayerNorm
    layernorm_kernel<<<NROWS, 256, 0, stream>>>(x, ln_g, ln_b, xn);

    // 2. xz = xn @ W_in   [2048 x 4096, K=1024]
    {
        dim3 grid((2 * D_INNER) / 64, NROWS / 64);
        gemm_tiled<false><<<grid, 256, 0, stream>>>(
            xn, W_in, xz, NROWS, 2 * D_INNER, D_MODEL,
            D_MODEL, 2 * D_INNER, 2 * D_INNER, nullptr, nullptr);
    }

    // 3. u2 = silu(causal_conv(u) + conv_b)
    conv_silu_kernel<<<(BATCH * SEQLEN * D_INNER) / 256, 256, 0, stream>>>(
        xz, conv_w, conv_b, u2);

    // 4. xdbl = u2 @ W_xp  [2048 x 96, K=2048]
    {
        dim3 grid((XDBL_W + 63) / 64, NROWS / 64);
        gemm_tiled<false><<<grid, 256, 0, stream>>>(
            u2, W_xp, xdbl, NROWS, XDBL_W, D_INNER,
            D_INNER, XDBL_W, XDBL_W, nullptr, nullptr);
    }

    // 5. dt_raw = xdbl[:, :64] @ W_dt  [2048 x 2048, K=64]
    {
        dim3 grid(D_INNER / 64, NROWS / 64);
        gemm_tiled<false><<<grid, 256, 0, stream>>>(
            xdbl, W_dt, dtraw, NROWS, D_INNER, DT_RANK,
            XDBL_W, D_INNER, D_INNER, nullptr, nullptr);
    }

    // 6. chunked parallel scan (A: partials, B: inter-chunk, C: final+gate)
    scan_partial_kernel<<<NCHUNK * (NCHAN / 16), 256, 0, stream>>>(
        dtraw, xdbl, u2, b_dt, A_log, hend, sumdt);
    scan_combine_kernel<<<NCHAN, 1024, 0, stream>>>(A_log, sumdt, hend);
    scan_final_kernel<<<NCHUNK * (NCHAN / 16), 256, 0, stream>>>(
        dtraw, xdbl, xz, u2, b_dt, A_log, D_param, hend);

    // 7. out = x + res_scale * (y @ W_out)  [2048 x 1024, K=2048]
    {
        dim3 grid(D_MODEL / 64, NROWS / 64);
        gemm_tiled<true><<<grid, 256, 0, stream>>>(
            u2, W_out, out, NROWS, D_MODEL, D_INNER,
            D_INNER, D_MODEL, D_MODEL, x, res_sc);
    }
}

// Round 3
// 967.344 us; speedup vs baseline: 2.3071x; 1.5397x over previous
//
#include <hip/hip_runtime.h>
#include <hip/hip_bf16.h>

// Dims (compile-time constants from the reference)
#define D_MODEL 1024
#define D_STATE 16
#define D_CONV  4
#define D_INNER 2048
#define DT_RANK 64
#define BATCH   2
#define SEQLEN  1024
#define NROWS   (BATCH * SEQLEN)        // 2048
#define XDBL_W  (DT_RANK + 2 * D_STATE) // 96
#define NCHUNK  64                      // chunks per sequence
#define LCHUNK  16                      // steps per chunk
#define NCHAN   (BATCH * D_INNER)       // 4096 (b,e) channels
#define KSPLIT  8                       // split-K factor for W_xp GEMM

typedef unsigned short ushort_t;
typedef __attribute__((ext_vector_type(8))) short bf16x8;
typedef __attribute__((ext_vector_type(4))) float f32x4;

// fp32 -> bf16 (round-to-nearest-even), bit-level (deterministic)
__device__ __forceinline__ ushort_t f2bf(float f) {
    union { float f; unsigned u; } v; v.f = f;
    unsigned r = v.u + 0x7fffu + ((v.u >> 16) & 1u);
    return (ushort_t)(r >> 16);
}

// ---------------------------------------------------------------------------
// LayerNorm: one block per row of 1024, 256 threads x float4. Emits bf16.
// ---------------------------------------------------------------------------
__global__ __launch_bounds__(256)
void layernorm_kernel(const float* __restrict__ x, const float* __restrict__ g,
                      const float* __restrict__ bb, ushort_t* __restrict__ xnbf)
{
    int row = blockIdx.x;
    const float* xr = x + (size_t)row * D_MODEL;
    int tid = threadIdx.x;
    float4 v = reinterpret_cast<const float4*>(xr)[tid];
    float s  = v.x + v.y + v.z + v.w;
    float ss = v.x * v.x + v.y * v.y + v.z * v.z + v.w * v.w;
    #pragma unroll
    for (int off = 32; off; off >>= 1) {
        s  += __shfl_down(s, off);
        ss += __shfl_down(ss, off);
    }
    __shared__ float sbuf[4], ssbuf[4];
    int wid = tid >> 6, lane = tid & 63;
    if (lane == 0) { sbuf[wid] = s; ssbuf[wid] = ss; }
    __syncthreads();
    if (tid == 0) {
        float st = 0.f, sst = 0.f;
        #pragma unroll
        for (int i = 0; i < 4; ++i) { st += sbuf[i]; sst += ssbuf[i]; }
        sbuf[0] = st; ssbuf[0] = sst;
    }
    __syncthreads();
    float mu  = sbuf[0] * (1.f / D_MODEL);
    float var = ssbuf[0] * (1.f / D_MODEL) - mu * mu;
    float inv = rsqrtf(var + 1e-5f);
    float4 gv = reinterpret_cast<const float4*>(g)[tid];
    float4 bv = reinterpret_cast<const float4*>(bb)[tid];
    ushort4 o;
    o.x = f2bf((v.x - mu) * inv * gv.x + bv.x);
    o.y = f2bf((v.y - mu) * inv * gv.y + bv.y);
    o.z = f2bf((v.z - mu) * inv * gv.z + bv.z);
    o.w = f2bf((v.w - mu) * inv * gv.w + bv.w);
    reinterpret_cast<ushort4*>(xnbf + (size_t)row * D_MODEL)[tid] = o;
}

// ---------------------------------------------------------------------------
// Transpose + fp32->bf16 convert: Wt[c][r] = bf16(W[r][c]).  W is [R][C].
// ---------------------------------------------------------------------------
__global__ __launch_bounds__(256)
void transpose_convert_kernel(const float* __restrict__ W, ushort_t* __restrict__ Wt,
                              int R, int C)
{
    __shared__ float t[32][33];
    int c0 = blockIdx.x * 32, r0 = blockIdx.y * 32;
    int tx = threadIdx.x, ty = threadIdx.y;
    #pragma unroll
    for (int i = 0; i < 32; i += 8)
        t[ty + i][tx] = W[(size_t)(r0 + ty + i) * C + c0 + tx];
    __syncthreads();
    #pragma unroll
    for (int i = 0; i < 32; i += 8)
        Wt[(size_t)(c0 + ty + i) * R + r0 + tx] = f2bf(t[tx][ty + i]);
}

// ---------------------------------------------------------------------------
// bf16 MFMA GEMM (m97 structure): C[M,N] = A[M,K] x Bt[N,K]^T, fp32 out.
// 128x128 tile, BK=32, 256 thr (4 waves, 2x2 of 64x64), 16x16x32 MFMA.
// global -> LDS via global_load_lds width 16 (linear LDS [128][32] bf16).
// M,N multiples of 128; K multiple of 32.
// ---------------------------------------------------------------------------
__device__ __forceinline__ void stage128x32(const ushort_t* __restrict__ gbase,
                                            size_t ld, ushort_t* ldsb, int tid)
{
    int l = tid & 63;
    int w = tid >> 6;
    int row = w * 16 + (l >> 2);     // 0..63 within issue
    int kg  = l & 3;                 // 8-elem group
    char* lb = (char*)ldsb + w * 1024;
    const ushort_t* g0 = gbase + (size_t)row * ld + kg * 8;
    __builtin_amdgcn_global_load_lds(
        (const __attribute__((address_space(1))) unsigned*)g0,
        (__attribute__((address_space(3))) unsigned*)lb, 16, 0, 0);
    const ushort_t* g1 = g0 + (size_t)64 * ld;
    __builtin_amdgcn_global_load_lds(
        (const __attribute__((address_space(1))) unsigned*)g1,
        (__attribute__((address_space(3))) unsigned*)(lb + 4096), 16, 0, 0);
}

template<bool RESIDUAL>
__global__ __launch_bounds__(256)
void gemm_bf16_mfma(const ushort_t* __restrict__ A, const ushort_t* __restrict__ Bt,
                    float* __restrict__ C, int M, int N, int K,
                    const float* __restrict__ xres, const float* __restrict__ res_scale)
{
    __shared__ ushort_t As[128 * 32];
    __shared__ ushort_t Bs[128 * 32];
    int tid = threadIdx.x;
    int l = tid & 63, wid = tid >> 6;
    int wr = wid >> 1, wc = wid & 1;           // wave's 64x64 quadrant
    int row0 = blockIdx.y * 128, col0 = blockIdx.x * 128;

    f32x4 acc[4][4];
    #pragma unroll
    for (int m = 0; m < 4; ++m)
        #pragma unroll
        for (int n = 0; n < 4; ++n)
            acc[m][n] = (f32x4){0.f, 0.f, 0.f, 0.f};

    const ushort_t* Ab = A  + (size_t)row0 * K;
    const ushort_t* Bb = Bt + (size_t)col0 * K;
    int arow = wr * 64 + (l & 15);
    int brow = wc * 64 + (l & 15);
    int kb   = (l >> 4) * 8;

    for (int k0 = 0; k0 < K; k0 += 32) {
        stage128x32(Ab + k0, K, As, tid);
        stage128x32(Bb + k0, K, Bs, tid);
        __syncthreads();
        bf16x8 af[4], bfr[4];
        #pragma unroll
        for (int m = 0; m < 4; ++m)
            af[m] = *reinterpret_cast<const bf16x8*>(&As[(arow + m * 16) * 32 + kb]);
        #pragma unroll
        for (int n = 0; n < 4; ++n)
            bfr[n] = *reinterpret_cast<const bf16x8*>(&Bs[(brow + n * 16) * 32 + kb]);
        #pragma unroll
        for (int m = 0; m < 4; ++m)
            #pragma unroll
            for (int n = 0; n < 4; ++n)
                acc[m][n] = __builtin_amdgcn_mfma_f32_16x16x32_bf16(
                    af[m], bfr[n], acc[m][n], 0, 0, 0);
        __syncthreads();
    }

    float rs = RESIDUAL ? res_scale[0] : 0.f;
    int ro = (l >> 4) * 4, co = l & 15;
    #pragma unroll
    for (int m = 0; m < 4; ++m) {
        #pragma unroll
        for (int n = 0; n < 4; ++n) {
            int c = col0 + wc * 64 + n * 16 + co;
            #pragma unroll
            for (int reg = 0; reg < 4; ++reg) {
                int r = row0 + wr * 64 + m * 16 + ro + reg;
                float v = acc[m][n][reg];
                if (RESIDUAL) v = xres[(size_t)r * N + c] + rs * v;
                C[(size_t)r * N + c] = v;
            }
        }
    }
}

// ---------------------------------------------------------------------------
// Generic fp32 tiled GEMM with K-range (for split-K and small GEMMs).
// ---------------------------------------------------------------------------
__global__ __launch_bounds__(256)
void gemm_tiled(const float* __restrict__ A, const float* __restrict__ B,
                float* __restrict__ C,
                int M, int N, int kbeg, int kend, int lda, int ldb, int ldc)
{
    __shared__ float As[16][68];
    __shared__ float Bs[16][64];
    int tid = threadIdx.x;
    int tx = tid & 15, ty = tid >> 4;
    int row0 = blockIdx.y * 64, col0 = blockIdx.x * 64;
    float acc[4][4] = {};

    for (int k0 = kbeg; k0 < kend; k0 += 16) {
        {
            int kk = tid & 15;
            int m0 = tid >> 4;
            #pragma unroll
            for (int r = 0; r < 4; ++r) {
                int mm = m0 + 16 * r;
                int grow = row0 + mm, gk = k0 + kk;
                float v = 0.f;
                if (grow < M && gk < kend) v = A[(size_t)grow * lda + gk];
                As[kk][mm] = v;
            }
        }
        {
            int nn = tid & 63;
            int kbw = tid >> 6;
            #pragma unroll
            for (int r = 0; r < 4; ++r) {
                int kk = kbw + 4 * r;
                int gk = k0 + kk, gcol = col0 + nn;
                float v = 0.f;
                if (gk < kend && gcol < N) v = B[(size_t)gk * ldb + gcol];
                Bs[kk][nn] = v;
            }
        }
        __syncthreads();
        #pragma unroll
        for (int kk = 0; kk < 16; ++kk) {
            float4 a4 = *reinterpret_cast<const float4*>(&As[kk][ty * 4]);
            float4 b4 = *reinterpret_cast<const float4*>(&Bs[kk][tx * 4]);
            float av[4] = {a4.x, a4.y, a4.z, a4.w};
            float bv[4] = {b4.x, b4.y, b4.z, b4.w};
            #pragma unroll
            for (int i = 0; i < 4; ++i)
                #pragma unroll
                for (int j = 0; j < 4; ++j)
                    acc[i][j] += av[i] * bv[j];
        }
        __syncthreads();
    }

    #pragma unroll
    for (int i = 0; i < 4; ++i) {
        int r = row0 + ty * 4 + i;
        if (r >= M) continue;
        #pragma unroll
        for (int j = 0; j < 4; ++j) {
            int c = col0 + tx * 4 + j;
            if (c >= N) continue;
            C[(size_t)r * ldc + c] = acc[i][j];
        }
    }
}

// Split-K reduction: out[i] = sum_s partials[s][i]
__global__ __launch_bounds__(256)
void reduce_partials_kernel(const float* __restrict__ p, float* __restrict__ out, int n)
{
    int i = blockIdx.x * 256 + threadIdx.x;
    if (i >= n) return;
    float s = 0.f;
    #pragma unroll
    for (int k = 0; k < KSPLIT; ++k) s += p[(size_t)k * n + i];
    out[i] = s;
}

// ---------------------------------------------------------------------------
// Depthwise causal conv (K=4) + bias + SiLU. One thread per (b,l,e).
// ---------------------------------------------------------------------------
__global__ __launch_bounds__(256)
void conv_silu_kernel(const float* __restrict__ xz, const float* __restrict__ cw,
                      const float* __restrict__ cb, float* __restrict__ u2)
{
    int idx = blockIdx.x * 256 + threadIdx.x;   // < 2*1024*2048
    int e = idx & (D_INNER - 1);
    int l = (idx >> 11) & (SEQLEN - 1);
    int b = idx >> 21;
    const float* base = xz + (size_t)b * SEQLEN * (2 * D_INNER) + e;
    float w0 = cw[e * 4 + 0], w1 = cw[e * 4 + 1];
    float w2 = cw[e * 4 + 2], w3 = cw[e * 4 + 3];
    float acc = cb[e];
    if (l >= 3) acc += base[(size_t)(l - 3) * (2 * D_INNER)] * w0;
    if (l >= 2) acc += base[(size_t)(l - 2) * (2 * D_INNER)] * w1;
    if (l >= 1) acc += base[(size_t)(l - 1) * (2 * D_INNER)] * w2;
    acc += base[(size_t)l * (2 * D_INNER)] * w3;
    float sv = acc / (1.f + expf(-acc));        // SiLU
    u2[idx] = sv;
}

// ---------------------------------------------------------------------------
// Chunked parallel scan, pass A: per-chunk partials from h=0.
// ---------------------------------------------------------------------------
__global__ __launch_bounds__(256)
void scan_partial_kernel(const float* __restrict__ dtraw, const float* __restrict__ xdbl,
                         const float* __restrict__ u2,
                         const float* __restrict__ b_dt, const float* __restrict__ A_log,
                         float* __restrict__ hend, float* __restrict__ sumdt_buf)
{
    int tid = threadIdx.x;
    int g = tid >> 4, n = tid & 15;
    int c = blockIdx.x >> 8;                     // chunk 0..63
    int p = ((blockIdx.x & 255) << 4) + g;       // channel 0..4095
    int b = p >> 11, e = p & (D_INNER - 1);
    float An  = -expf(A_log[e * D_STATE + n]);
    float bdt = b_dt[e];
    float h = 0.f, sdt = 0.f;
    size_t rowbase = (size_t)b * SEQLEN + c * LCHUNK;
    #pragma unroll
    for (int j = 0; j < LCHUNK; ++j) {
        size_t row = rowbase + j;
        float dtr = dtraw[row * D_INNER + e] + bdt;
        float dt  = (dtr > 20.f) ? dtr : log1pf(expf(dtr));
        sdt += dt;
        float u  = u2[row * D_INNER + e];
        float Bn = xdbl[row * XDBL_W + DT_RANK + n];
        h = expf(dt * An) * h + (dt * u) * Bn;
    }
    hend[(size_t)p * (NCHUNK * D_STATE) + c * D_STATE + n] = h;
    if (n == 0) sumdt_buf[p * NCHUNK + c] = sdt;
}

// ---------------------------------------------------------------------------
// Pass B: per-channel inter-chunk Hillis-Steele scan; exclusive carry in place.
// ---------------------------------------------------------------------------
__global__ __launch_bounds__(1024)
void scan_combine_kernel(const float* __restrict__ A_log,
                         const float* __restrict__ sumdt_buf,
                         float* __restrict__ hend /* in: hend, out: hcarry */)
{
    __shared__ float Ps[NCHUNK][D_STATE];
    __shared__ float Hs[NCHUNK][D_STATE];
    int tid = threadIdx.x;
    int c = tid >> 4, n = tid & 15;
    int p = blockIdx.x;
    int e = p & (D_INNER - 1);
    float An = -expf(A_log[e * D_STATE + n]);
    float P = expf(An * sumdt_buf[p * NCHUNK + c]);
    float H = hend[(size_t)p * (NCHUNK * D_STATE) + c * D_STATE + n];
    Ps[c][n] = P; Hs[c][n] = H;
    __syncthreads();
    #pragma unroll
    for (int d = 1; d < NCHUNK; d <<= 1) {
        float Pl = 1.f, Hl = 0.f;
        if (c >= d) { Pl = Ps[c - d][n]; Hl = Hs[c - d][n]; }
        __syncthreads();
        H = P * Hl + H;   // (P,H) o (Pl,Hl)
        P = P * Pl;
        Ps[c][n] = P; Hs[c][n] = H;
        __syncthreads();
    }
    float carry = (c == 0) ? 0.f : Hs[c - 1][n];
    hend[(size_t)p * (NCHUNK * D_STATE) + c * D_STATE + n] = carry;
}

// ---------------------------------------------------------------------------
// Pass C: re-scan each chunk seeded with its carry; fuse softplus, D-skip,
// SiLU(z) gate; write y as bf16 into ybf.
// ---------------------------------------------------------------------------
__global__ __launch_bounds__(256)
void scan_final_kernel(const float* __restrict__ dtraw, const float* __restrict__ xdbl,
                       const float* __restrict__ xz, const float* __restrict__ u2,
                       ushort_t* __restrict__ ybf,
                       const float* __restrict__ b_dt, const float* __restrict__ A_log,
                       const float* __restrict__ D_param,
                       const float* __restrict__ hcarry)
{
    int tid = threadIdx.x;
    int g = tid >> 4, n = tid & 15;
    int c = blockIdx.x >> 8;
    int p = ((blockIdx.x & 255) << 4) + g;
    int b = p >> 11, e = p & (D_INNER - 1);
    float An  = -expf(A_log[e * D_STATE + n]);
    float bdt = b_dt[e];
    float De  = D_param[e];
    float h = hcarry[(size_t)p * (NCHUNK * D_STATE) + c * D_STATE + n];
    size_t rowbase = (size_t)b * SEQLEN + c * LCHUNK;
    #pragma unroll
    for (int j = 0; j < LCHUNK; ++j) {
        size_t row = rowbase + j;
        float dtr = dtraw[row * D_INNER + e] + bdt;
        float dt  = (dtr > 20.f) ? dtr : log1pf(expf(dtr));
        float u   = u2[row * D_INNER + e];
        float Bn  = xdbl[row * XDBL_W + DT_RANK + n];
        float Cn  = xdbl[row * XDBL_W + DT_RANK + D_STATE + n];
        h = expf(dt * An) * h + (dt * u) * Bn;
        float ps = h * Cn;
        ps += __shfl_xor(ps, 1, 16);
        ps += __shfl_xor(ps, 2, 16);
        ps += __shfl_xor(ps, 4, 16);
        ps += __shfl_xor(ps, 8, 16);
        if (n == j) {
            float z  = xz[row * (2 * D_INNER) + D_INNER + e];
            float sz = z / (1.f + expf(-z));
            ybf[row * D_INNER + e] = f2bf((ps + u * De) * sz);
        }
    }
}

// ---------------------------------------------------------------------------
extern "C" void kernel_launch(void* const* d_in, const int* in_sizes, int n_in,
                              void* d_out, int out_size, void* d_ws, size_t ws_size,
                              hipStream_t stream)
{
    const float* x       = (const float*)d_in[0];
    const float* ln_g    = (const float*)d_in[1];
    const float* ln_b    = (const float*)d_in[2];
    const float* W_in    = (const float*)d_in[3];
    const float* conv_w  = (const float*)d_in[4];
    const float* conv_b  = (const float*)d_in[5];
    const float* W_xp    = (const float*)d_in[6];
    const float* W_dt    = (const float*)d_in[7];
    const float* b_dt    = (const float*)d_in[8];
    const float* A_log   = (const float*)d_in[9];
    const float* D_param = (const float*)d_in[10];
    const float* W_out   = (const float*)d_in[11];
    const float* res_sc  = (const float*)d_in[12];
    float* out = (float*)d_out;

    char* ws = (char*)d_ws;
    const size_t MB = 1024 * 1024;
    float*    xz    = (float*)(ws);
    float*    u2    = (float*)(ws + 32 * MB);
    float*    dtraw = (float*)(ws + 48 * MB);
    float*    xdbl  = (float*)(ws + 64 * MB);
    float*    hend  = (float*)(ws + 65 * MB);
    float*    sumdt = (float*)(ws + 81 * MB);
    ushort_t* xnbf  = (ushort_t*)(ws + 82 * MB);
    ushort_t* WtIn  = (ushort_t*)(ws + 86 * MB);
    ushort_t* WtOut = (ushort_t*)(ws + 94 * MB);
    ushort_t* ybf   = (ushort_t*)(ws + 98 * MB);
    float*    parts = (float*)(ws + 106 * MB);

    // 0. weight transpose+convert (bf16)
    {
        dim3 blk(32, 8);
        dim3 g1((2 * D_INNER) / 32, D_MODEL / 32);   // W_in: [1024][4096]
        transpose_convert_kernel<<<g1, blk, 0, stream>>>(W_in, WtIn, D_MODEL, 2 * D_INNER);
        dim3 g2(D_MODEL / 32, D_INNER / 32);         // W_out: [2048][1024]
        transpose_convert_kernel<<<g2, blk, 0, stream>>>(W_out, WtOut, D_INNER, D_MODEL);
    }

    // 1. LayerNorm -> bf16 A operand
    layernorm_kernel<<<NROWS, 256, 0, stream>>>(x, ln_g, ln_b, xnbf);

    // 2. xz = xn @ W_in   [2048 x 4096, K=1024]  (bf16 MFMA)
    {
        dim3 grid((2 * D_INNER) / 128, NROWS / 128);
        gemm_bf16_mfma<false><<<grid, 256, 0, stream>>>(
            xnbf, WtIn, xz, NROWS, 2 * D_INNER, D_MODEL, nullptr, nullptr);
    }

    // 3. u2 = silu(causal_conv(u) + conv_b)
    conv_silu_kernel<<<(BATCH * SEQLEN * D_INNER) / 256, 256, 0, stream>>>(
        xz, conv_w, conv_b, u2);

    // 4. xdbl = u2 @ W_xp  [2048 x 96, K=2048]  split-K x8 + reduce
    for (int s = 0; s < KSPLIT; ++s) {
        dim3 grid((XDBL_W + 63) / 64, NROWS / 64);
        gemm_tiled<<<grid, 256, 0, stream>>>(
            u2, W_xp, parts + (size_t)s * NROWS * XDBL_W,
            NROWS, XDBL_W, s * (D_INNER / KSPLIT), (s + 1) * (D_INNER / KSPLIT),
            D_INNER, XDBL_W, XDBL_W);
    }
    reduce_partials_kernel<<<(NROWS * XDBL_W + 255) / 256, 256, 0, stream>>>(
        parts, xdbl, NROWS * XDBL_W);

    // 5. dt_raw = xdbl[:, :64] @ W_dt  [2048 x 2048, K=64]
    {
        dim3 grid(D_INNER / 64, NROWS / 64);
        gemm_tiled<<<grid, 256, 0, stream>>>(
            xdbl, W_dt, dtraw, NROWS, D_INNER, 0, DT_RANK,
            XDBL_W, D_INNER, D_INNER);
    }

    // 6. chunked parallel scan (A: partials, B: inter-chunk, C: final+gate)
    scan_partial_kernel<<<NCHUNK * (NCHAN / 16), 256, 0, stream>>>(
        dtraw, xdbl, u2, b_dt, A_log, hend, sumdt);
    scan_combine_kernel<<<NCHAN, 1024, 0, stream>>>(A_log, sumdt, hend);
    scan_final_kernel<<<NCHUNK * (NCHAN / 16), 256, 0, stream>>>(
        dtraw, xdbl, xz, u2, ybf, b_dt, A_log, D_param, hend);

    // 7. out = x + res_scale * (y @ W_out)  [2048 x 1024, K=2048]  (bf16 MFMA)
    {
        dim3 grid(D_MODEL / 128, NROWS / 128);
        gemm_bf16_mfma<true><<<grid, 256, 0, stream>>>(
            ybf, WtOut, out, NROWS, D_MODEL, D_INNER, x, res_sc);
    }
}

// Round 4
// 305.775 us; speedup vs baseline: 7.2986x; 3.1636x over previous
//
#include <hip/hip_runtime.h>
#include <hip/hip_bf16.h>

// Dims (compile-time constants from the reference)
#define D_MODEL 1024
#define D_STATE 16
#define D_CONV  4
#define D_INNER 2048
#define DT_RANK 64
#define BATCH   2
#define SEQLEN  1024
#define NROWS   (BATCH * SEQLEN)        // 2048
#define XDBL_W  (DT_RANK + 2 * D_STATE) // 96
#define NCHUNK  64                      // chunks per sequence
#define LCHUNK  16                      // steps per chunk
#define NCHAN   (BATCH * D_INNER)       // 4096 (b,e) channels
#define KSPLIT  8                       // split-K factor for W_xp GEMM

typedef unsigned short ushort_t;
typedef __attribute__((ext_vector_type(8))) short bf16x8;
typedef __attribute__((ext_vector_type(4))) float f32x4;

// fp32 -> bf16 (round-to-nearest-even), bit-level (deterministic)
__device__ __forceinline__ ushort_t f2bf(float f) {
    union { float f; unsigned u; } v; v.f = f;
    unsigned r = v.u + 0x7fffu + ((v.u >> 16) & 1u);
    return (ushort_t)(r >> 16);
}

__device__ __forceinline__ float fast_sigmoid(float z) {
    return __builtin_amdgcn_rcpf(1.f + __expf(-z));
}

// ---------------------------------------------------------------------------
// LayerNorm: one block per row of 1024, 256 threads x float4. Emits bf16.
// ---------------------------------------------------------------------------
__global__ __launch_bounds__(256)
void layernorm_kernel(const float* __restrict__ x, const float* __restrict__ g,
                      const float* __restrict__ bb, ushort_t* __restrict__ xnbf)
{
    int row = blockIdx.x;
    const float* xr = x + (size_t)row * D_MODEL;
    int tid = threadIdx.x;
    float4 v = reinterpret_cast<const float4*>(xr)[tid];
    float s  = v.x + v.y + v.z + v.w;
    float ss = v.x * v.x + v.y * v.y + v.z * v.z + v.w * v.w;
    #pragma unroll
    for (int off = 32; off; off >>= 1) {
        s  += __shfl_down(s, off);
        ss += __shfl_down(ss, off);
    }
    __shared__ float sbuf[4], ssbuf[4];
    int wid = tid >> 6, lane = tid & 63;
    if (lane == 0) { sbuf[wid] = s; ssbuf[wid] = ss; }
    __syncthreads();
    if (tid == 0) {
        float st = 0.f, sst = 0.f;
        #pragma unroll
        for (int i = 0; i < 4; ++i) { st += sbuf[i]; sst += ssbuf[i]; }
        sbuf[0] = st; ssbuf[0] = sst;
    }
    __syncthreads();
    float mu  = sbuf[0] * (1.f / D_MODEL);
    float var = ssbuf[0] * (1.f / D_MODEL) - mu * mu;
    float inv = rsqrtf(var + 1e-5f);
    float4 gv = reinterpret_cast<const float4*>(g)[tid];
    float4 bv = reinterpret_cast<const float4*>(bb)[tid];
    ushort4 o;
    o.x = f2bf((v.x - mu) * inv * gv.x + bv.x);
    o.y = f2bf((v.y - mu) * inv * gv.y + bv.y);
    o.z = f2bf((v.z - mu) * inv * gv.z + bv.z);
    o.w = f2bf((v.w - mu) * inv * gv.w + bv.w);
    reinterpret_cast<ushort4*>(xnbf + (size_t)row * D_MODEL)[tid] = o;
}

// ---------------------------------------------------------------------------
// Transpose + fp32->bf16 convert: Wt[c][r] = bf16(W[r][c]).  W is [R][C].
// ---------------------------------------------------------------------------
__global__ __launch_bounds__(256)
void transpose_convert_kernel(const float* __restrict__ W, ushort_t* __restrict__ Wt,
                              int R, int C)
{
    __shared__ float t[32][33];
    int c0 = blockIdx.x * 32, r0 = blockIdx.y * 32;
    int tx = threadIdx.x, ty = threadIdx.y;
    #pragma unroll
    for (int i = 0; i < 32; i += 8)
        t[ty + i][tx] = W[(size_t)(r0 + ty + i) * C + c0 + tx];
    __syncthreads();
    #pragma unroll
    for (int i = 0; i < 32; i += 8)
        Wt[(size_t)(c0 + ty + i) * R + r0 + tx] = f2bf(t[tx][ty + i]);
}

// ---------------------------------------------------------------------------
// bf16 MFMA GEMM (m97 structure): C[M,N] = A[M,K] x Bt[N,K]^T, fp32 out.
// 128x128 tile, BK=32, 256 thr (4 waves, 2x2 of 64x64), 16x16x32 MFMA.
// ---------------------------------------------------------------------------
__device__ __forceinline__ void stage128x32(const ushort_t* __restrict__ gbase,
                                            size_t ld, ushort_t* ldsb, int tid)
{
    int l = tid & 63;
    int w = tid >> 6;
    int row = w * 16 + (l >> 2);     // 0..63 within issue
    int kg  = l & 3;                 // 8-elem group
    char* lb = (char*)ldsb + w * 1024;
    const ushort_t* g0 = gbase + (size_t)row * ld + kg * 8;
    __builtin_amdgcn_global_load_lds(
        (const __attribute__((address_space(1))) unsigned*)g0,
        (__attribute__((address_space(3))) unsigned*)lb, 16, 0, 0);
    const ushort_t* g1 = g0 + (size_t)64 * ld;
    __builtin_amdgcn_global_load_lds(
        (const __attribute__((address_space(1))) unsigned*)g1,
        (__attribute__((address_space(3))) unsigned*)(lb + 4096), 16, 0, 0);
}

template<bool RESIDUAL>
__global__ __launch_bounds__(256)
void gemm_bf16_mfma(const ushort_t* __restrict__ A, const ushort_t* __restrict__ Bt,
                    float* __restrict__ C, int M, int N, int K,
                    const float* __restrict__ xres, const float* __restrict__ res_scale)
{
    __shared__ ushort_t As[128 * 32];
    __shared__ ushort_t Bs[128 * 32];
    int tid = threadIdx.x;
    int l = tid & 63, wid = tid >> 6;
    int wr = wid >> 1, wc = wid & 1;           // wave's 64x64 quadrant
    int row0 = blockIdx.y * 128, col0 = blockIdx.x * 128;

    f32x4 acc[4][4];
    #pragma unroll
    for (int m = 0; m < 4; ++m)
        #pragma unroll
        for (int n = 0; n < 4; ++n)
            acc[m][n] = (f32x4){0.f, 0.f, 0.f, 0.f};

    const ushort_t* Ab = A  + (size_t)row0 * K;
    const ushort_t* Bb = Bt + (size_t)col0 * K;
    int arow = wr * 64 + (l & 15);
    int brow = wc * 64 + (l & 15);
    int kb   = (l >> 4) * 8;

    for (int k0 = 0; k0 < K; k0 += 32) {
        stage128x32(Ab + k0, K, As, tid);
        stage128x32(Bb + k0, K, Bs, tid);
        __syncthreads();
        bf16x8 af[4], bfr[4];
        #pragma unroll
        for (int m = 0; m < 4; ++m)
            af[m] = *reinterpret_cast<const bf16x8*>(&As[(arow + m * 16) * 32 + kb]);
        #pragma unroll
        for (int n = 0; n < 4; ++n)
            bfr[n] = *reinterpret_cast<const bf16x8*>(&Bs[(brow + n * 16) * 32 + kb]);
        #pragma unroll
        for (int m = 0; m < 4; ++m)
            #pragma unroll
            for (int n = 0; n < 4; ++n)
                acc[m][n] = __builtin_amdgcn_mfma_f32_16x16x32_bf16(
                    af[m], bfr[n], acc[m][n], 0, 0, 0);
        __syncthreads();
    }

    float rs = RESIDUAL ? res_scale[0] : 0.f;
    int ro = (l >> 4) * 4, co = l & 15;
    #pragma unroll
    for (int m = 0; m < 4; ++m) {
        #pragma unroll
        for (int n = 0; n < 4; ++n) {
            int c = col0 + wc * 64 + n * 16 + co;
            #pragma unroll
            for (int reg = 0; reg < 4; ++reg) {
                int r = row0 + wr * 64 + m * 16 + ro + reg;
                float v = acc[m][n][reg];
                if (RESIDUAL) v = xres[(size_t)r * N + c] + rs * v;
                C[(size_t)r * N + c] = v;
            }
        }
    }
}

// ---------------------------------------------------------------------------
// Split-K bf16 MFMA GEMM for xdbl: A[2048,2048] x Bt[128(pad),2048]^T.
// Grid (1, M/128, KSPLIT). Stores fp32 partials [z][M][96] with col guard.
// ---------------------------------------------------------------------------
__global__ __launch_bounds__(256)
void gemm_bf16_mfma_splitk(const ushort_t* __restrict__ A, const ushort_t* __restrict__ Bt,
                           float* __restrict__ parts)
{
    __shared__ ushort_t As[128 * 32];
    __shared__ ushort_t Bs[128 * 32];
    const int K = D_INNER;
    const int KS = D_INNER / KSPLIT;           // 256
    int tid = threadIdx.x;
    int l = tid & 63, wid = tid >> 6;
    int wr = wid >> 1, wc = wid & 1;
    int row0 = blockIdx.y * 128;
    int kbeg = blockIdx.z * KS;

    f32x4 acc[4][4];
    #pragma unroll
    for (int m = 0; m < 4; ++m)
        #pragma unroll
        for (int n = 0; n < 4; ++n)
            acc[m][n] = (f32x4){0.f, 0.f, 0.f, 0.f};

    const ushort_t* Ab = A  + (size_t)row0 * K + kbeg;
    const ushort_t* Bb = Bt + kbeg;
    int arow = wr * 64 + (l & 15);
    int brow = wc * 64 + (l & 15);
    int kb   = (l >> 4) * 8;

    for (int k0 = 0; k0 < KS; k0 += 32) {
        stage128x32(Ab + k0, K, As, tid);
        stage128x32(Bb + k0, K, Bs, tid);
        __syncthreads();
        bf16x8 af[4], bfr[4];
        #pragma unroll
        for (int m = 0; m < 4; ++m)
            af[m] = *reinterpret_cast<const bf16x8*>(&As[(arow + m * 16) * 32 + kb]);
        #pragma unroll
        for (int n = 0; n < 4; ++n)
            bfr[n] = *reinterpret_cast<const bf16x8*>(&Bs[(brow + n * 16) * 32 + kb]);
        #pragma unroll
        for (int m = 0; m < 4; ++m)
            #pragma unroll
            for (int n = 0; n < 4; ++n)
                acc[m][n] = __builtin_amdgcn_mfma_f32_16x16x32_bf16(
                    af[m], bfr[n], acc[m][n], 0, 0, 0);
        __syncthreads();
    }

    float* Cp = parts + (size_t)blockIdx.z * NROWS * XDBL_W;
    int ro = (l >> 4) * 4, co = l & 15;
    #pragma unroll
    for (int m = 0; m < 4; ++m) {
        #pragma unroll
        for (int n = 0; n < 4; ++n) {
            int c = wc * 64 + n * 16 + co;
            if (c >= XDBL_W) continue;
            #pragma unroll
            for (int reg = 0; reg < 4; ++reg) {
                int r = row0 + wr * 64 + m * 16 + ro + reg;
                Cp[(size_t)r * XDBL_W + c] = acc[m][n][reg];
            }
        }
    }
}

// Split-K reduction: out[i] = sum_s partials[s][i]
__global__ __launch_bounds__(256)
void reduce_partials_kernel(const float* __restrict__ p, float* __restrict__ out, int n)
{
    int i = blockIdx.x * 256 + threadIdx.x;
    if (i >= n) return;
    float s = 0.f;
    #pragma unroll
    for (int k = 0; k < KSPLIT; ++k) s += p[(size_t)k * n + i];
    out[i] = s;
}

// ---------------------------------------------------------------------------
// fp32 tiled GEMM (used for the dt GEMM, K=64). Optional fused
// epilogue: C = softplus(acc + bias[col]).
// ---------------------------------------------------------------------------
template<bool SPBIAS>
__global__ __launch_bounds__(256)
void gemm_tiled(const float* __restrict__ A, const float* __restrict__ B,
                float* __restrict__ C,
                int M, int N, int kbeg, int kend, int lda, int ldb, int ldc,
                const float* __restrict__ bias)
{
    __shared__ float As[16][68];
    __shared__ float Bs[16][64];
    int tid = threadIdx.x;
    int tx = tid & 15, ty = tid >> 4;
    int row0 = blockIdx.y * 64, col0 = blockIdx.x * 64;
    float acc[4][4] = {};

    for (int k0 = kbeg; k0 < kend; k0 += 16) {
        {
            int kk = tid & 15;
            int m0 = tid >> 4;
            #pragma unroll
            for (int r = 0; r < 4; ++r) {
                int mm = m0 + 16 * r;
                int grow = row0 + mm, gk = k0 + kk;
                float v = 0.f;
                if (grow < M && gk < kend) v = A[(size_t)grow * lda + gk];
                As[kk][mm] = v;
            }
        }
        {
            int nn = tid & 63;
            int kbw = tid >> 6;
            #pragma unroll
            for (int r = 0; r < 4; ++r) {
                int kk = kbw + 4 * r;
                int gk = k0 + kk, gcol = col0 + nn;
                float v = 0.f;
                if (gk < kend && gcol < N) v = B[(size_t)gk * ldb + gcol];
                Bs[kk][nn] = v;
            }
        }
        __syncthreads();
        #pragma unroll
        for (int kk = 0; kk < 16; ++kk) {
            float4 a4 = *reinterpret_cast<const float4*>(&As[kk][ty * 4]);
            float4 b4 = *reinterpret_cast<const float4*>(&Bs[kk][tx * 4]);
            float av[4] = {a4.x, a4.y, a4.z, a4.w};
            float bv[4] = {b4.x, b4.y, b4.z, b4.w};
            #pragma unroll
            for (int i = 0; i < 4; ++i)
                #pragma unroll
                for (int j = 0; j < 4; ++j)
                    acc[i][j] += av[i] * bv[j];
        }
        __syncthreads();
    }

    #pragma unroll
    for (int i = 0; i < 4; ++i) {
        int r = row0 + ty * 4 + i;
        if (r >= M) continue;
        #pragma unroll
        for (int j = 0; j < 4; ++j) {
            int c = col0 + tx * 4 + j;
            if (c >= N) continue;
            float v = acc[i][j];
            if (SPBIAS) {
                v += bias[c];
                v = (v > 20.f) ? v : log1pf(expf(v));   // softplus, once per elem
            }
            C[(size_t)r * ldc + c] = v;
        }
    }
}

// ---------------------------------------------------------------------------
// Depthwise causal conv (K=4) + bias + SiLU. Writes u2 (fp32) and u2bf (bf16).
// ---------------------------------------------------------------------------
__global__ __launch_bounds__(256)
void conv_silu_kernel(const float* __restrict__ xz, const float* __restrict__ cw,
                      const float* __restrict__ cb, float* __restrict__ u2,
                      ushort_t* __restrict__ u2bf)
{
    int idx = blockIdx.x * 256 + threadIdx.x;   // < 2*1024*2048
    int e = idx & (D_INNER - 1);
    int l = (idx >> 11) & (SEQLEN - 1);
    int b = idx >> 21;
    const float* base = xz + (size_t)b * SEQLEN * (2 * D_INNER) + e;
    float w0 = cw[e * 4 + 0], w1 = cw[e * 4 + 1];
    float w2 = cw[e * 4 + 2], w3 = cw[e * 4 + 3];
    float acc = cb[e];
    if (l >= 3) acc += base[(size_t)(l - 3) * (2 * D_INNER)] * w0;
    if (l >= 2) acc += base[(size_t)(l - 2) * (2 * D_INNER)] * w1;
    if (l >= 1) acc += base[(size_t)(l - 1) * (2 * D_INNER)] * w2;
    acc += base[(size_t)l * (2 * D_INNER)] * w3;
    float sv = acc * fast_sigmoid(acc);         // SiLU
    u2[idx] = sv;
    u2bf[idx] = f2bf(sv);
}

// ---------------------------------------------------------------------------
// Chunked parallel scan, pass A: per-chunk partials from h=0. dt precomputed.
// ---------------------------------------------------------------------------
__global__ __launch_bounds__(256)
void scan_partial_kernel(const float* __restrict__ dtbuf, const float* __restrict__ xdbl,
                         const float* __restrict__ u2,
                         const float* __restrict__ A_log,
                         float* __restrict__ hend, float* __restrict__ sumdt_buf)
{
    int tid = threadIdx.x;
    int g = tid >> 4, n = tid & 15;
    int c = blockIdx.x >> 8;                     // chunk 0..63
    int p = ((blockIdx.x & 255) << 4) + g;       // channel 0..4095
    int b = p >> 11, e = p & (D_INNER - 1);
    float An  = -__expf(A_log[e * D_STATE + n]);
    float h = 0.f, sdt = 0.f;
    size_t rowbase = (size_t)b * SEQLEN + c * LCHUNK;
    #pragma unroll
    for (int j = 0; j < LCHUNK; ++j) {
        size_t row = rowbase + j;
        float dt = dtbuf[row * D_INNER + e];
        sdt += dt;
        float u  = u2[row * D_INNER + e];
        float Bn = xdbl[row * XDBL_W + DT_RANK + n];
        h = __expf(dt * An) * h + (dt * u) * Bn;
    }
    hend[(size_t)p * (NCHUNK * D_STATE) + c * D_STATE + n] = h;
    if (n == 0) sumdt_buf[p * NCHUNK + c] = sdt;
}

// ---------------------------------------------------------------------------
// Pass B: per-channel inter-chunk Hillis-Steele scan; exclusive carry in place.
// ---------------------------------------------------------------------------
__global__ __launch_bounds__(1024)
void scan_combine_kernel(const float* __restrict__ A_log,
                         const float* __restrict__ sumdt_buf,
                         float* __restrict__ hend /* in: hend, out: hcarry */)
{
    __shared__ float Ps[NCHUNK][D_STATE];
    __shared__ float Hs[NCHUNK][D_STATE];
    int tid = threadIdx.x;
    int c = tid >> 4, n = tid & 15;
    int p = blockIdx.x;
    int e = p & (D_INNER - 1);
    float An = -__expf(A_log[e * D_STATE + n]);
    float P = __expf(An * sumdt_buf[p * NCHUNK + c]);
    float H = hend[(size_t)p * (NCHUNK * D_STATE) + c * D_STATE + n];
    Ps[c][n] = P; Hs[c][n] = H;
    __syncthreads();
    #pragma unroll
    for (int d = 1; d < NCHUNK; d <<= 1) {
        float Pl = 1.f, Hl = 0.f;
        if (c >= d) { Pl = Ps[c - d][n]; Hl = Hs[c - d][n]; }
        __syncthreads();
        H = P * Hl + H;   // (P,H) o (Pl,Hl)
        P = P * Pl;
        Ps[c][n] = P; Hs[c][n] = H;
        __syncthreads();
    }
    float carry = (c == 0) ? 0.f : Hs[c - 1][n];
    hend[(size_t)p * (NCHUNK * D_STATE) + c * D_STATE + n] = carry;
}

// ---------------------------------------------------------------------------
// Pass C: re-scan each chunk seeded with its carry; fused D-skip + SiLU(z)
// gate; writes y as bf16.
// ---------------------------------------------------------------------------
__global__ __launch_bounds__(256)
void scan_final_kernel(const float* __restrict__ dtbuf, const float* __restrict__ xdbl,
                       const float* __restrict__ xz, const float* __restrict__ u2,
                       ushort_t* __restrict__ ybf,
                       const float* __restrict__ A_log,
                       const float* __restrict__ D_param,
                       const float* __restrict__ hcarry)
{
    int tid = threadIdx.x;
    int g = tid >> 4, n = tid & 15;
    int c = blockIdx.x >> 8;
    int p = ((blockIdx.x & 255) << 4) + g;
    int b = p >> 11, e = p & (D_INNER - 1);
    float An  = -__expf(A_log[e * D_STATE + n]);
    float De  = D_param[e];
    float h = hcarry[(size_t)p * (NCHUNK * D_STATE) + c * D_STATE + n];
    size_t rowbase = (size_t)b * SEQLEN + c * LCHUNK;
    #pragma unroll
    for (int j = 0; j < LCHUNK; ++j) {
        size_t row = rowbase + j;
        float dt = dtbuf[row * D_INNER + e];
        float u  = u2[row * D_INNER + e];
        float Bn = xdbl[row * XDBL_W + DT_RANK + n];
        float Cn = xdbl[row * XDBL_W + DT_RANK + D_STATE + n];
        h = __expf(dt * An) * h + (dt * u) * Bn;
        float ps = h * Cn;
        ps += __shfl_xor(ps, 1, 16);
        ps += __shfl_xor(ps, 2, 16);
        ps += __shfl_xor(ps, 4, 16);
        ps += __shfl_xor(ps, 8, 16);
        if (n == j) {
            float z  = xz[row * (2 * D_INNER) + D_INNER + e];
            float sz = z * fast_sigmoid(z);
            ybf[row * D_INNER + e] = f2bf((ps + u * De) * sz);
        }
    }
}

// ---------------------------------------------------------------------------
extern "C" void kernel_launch(void* const* d_in, const int* in_sizes, int n_in,
                              void* d_out, int out_size, void* d_ws, size_t ws_size,
                              hipStream_t stream)
{
    const float* x       = (const float*)d_in[0];
    const float* ln_g    = (const float*)d_in[1];
    const float* ln_b    = (const float*)d_in[2];
    const float* W_in    = (const float*)d_in[3];
    const float* conv_w  = (const float*)d_in[4];
    const float* conv_b  = (const float*)d_in[5];
    const float* W_xp    = (const float*)d_in[6];
    const float* W_dt    = (const float*)d_in[7];
    const float* b_dt    = (const float*)d_in[8];
    const float* A_log   = (const float*)d_in[9];
    const float* D_param = (const float*)d_in[10];
    const float* W_out   = (const float*)d_in[11];
    const float* res_sc  = (const float*)d_in[12];
    float* out = (float*)d_out;

    char* ws = (char*)d_ws;
    const size_t MB = 1024 * 1024;
    // Workspace (liveness-overlapped):
    //   xz     [0,32M)      2048x4096 fp32
    //   u2     [32M,48M)    2048x2048 fp32
    //   dt     [48M,64M)    2048x2048 fp32 (softplus'd in GEMM epilogue)
    //   xdbl   [64M,65M)    2048x96 fp32
    //   hend   [65M,81M)    4096x64x16 fp32    (written step 6)
    //   u2bf   [65M,73M)    2048x2048 bf16     (dead before hend written)
    //   sumdt  [81M,82M)
    //   xnbf   [82M,86M)    2048x1024 bf16
    //   WtIn   [86M,94M)    4096x1024 bf16
    //   WtOut  [94M,98M)    1024x2048 bf16
    //   ybf    [98M,106M)   2048x2048 bf16     (written step 6c)
    //   parts  [98M,104M)   8x2048x96 fp32     (dead before ybf written)
    //   WtXp   [106M,106.5M) 128x2048 bf16 (rows 96..127 zero)
    float*    xz    = (float*)(ws);
    float*    u2    = (float*)(ws + 32 * MB);
    float*    dtbuf = (float*)(ws + 48 * MB);
    float*    xdbl  = (float*)(ws + 64 * MB);
    float*    hend  = (float*)(ws + 65 * MB);
    ushort_t* u2bf  = (ushort_t*)(ws + 65 * MB);
    float*    sumdt = (float*)(ws + 81 * MB);
    ushort_t* xnbf  = (ushort_t*)(ws + 82 * MB);
    ushort_t* WtIn  = (ushort_t*)(ws + 86 * MB);
    ushort_t* WtOut = (ushort_t*)(ws + 94 * MB);
    ushort_t* ybf   = (ushort_t*)(ws + 98 * MB);
    float*    parts = (float*)(ws + 98 * MB);
    ushort_t* WtXp  = (ushort_t*)(ws + 106 * MB);

    // 0. weight transpose+convert (bf16); zero WtXp pad rows [96,128)
    {
        dim3 blk(32, 8);
        dim3 g1((2 * D_INNER) / 32, D_MODEL / 32);
        transpose_convert_kernel<<<g1, blk, 0, stream>>>(W_in, WtIn, D_MODEL, 2 * D_INNER);
        dim3 g2(D_MODEL / 32, D_INNER / 32);
        transpose_convert_kernel<<<g2, blk, 0, stream>>>(W_out, WtOut, D_INNER, D_MODEL);
        dim3 g3(XDBL_W / 32, D_INNER / 32);
        transpose_convert_kernel<<<g3, blk, 0, stream>>>(W_xp, WtXp, D_INNER, XDBL_W);
        hipMemsetAsync(WtXp + (size_t)XDBL_W * D_INNER, 0,
                       (size_t)(128 - XDBL_W) * D_INNER * sizeof(ushort_t), stream);
    }

    // 1. LayerNorm -> bf16 A operand
    layernorm_kernel<<<NROWS, 256, 0, stream>>>(x, ln_g, ln_b, xnbf);

    // 2. xz = xn @ W_in   [2048 x 4096, K=1024]  (bf16 MFMA)
    {
        dim3 grid((2 * D_INNER) / 128, NROWS / 128);
        gemm_bf16_mfma<false><<<grid, 256, 0, stream>>>(
            xnbf, WtIn, xz, NROWS, 2 * D_INNER, D_MODEL, nullptr, nullptr);
    }

    // 3. u2 = silu(causal_conv(u) + conv_b)   (fp32 + bf16 copies)
    conv_silu_kernel<<<(BATCH * SEQLEN * D_INNER) / 256, 256, 0, stream>>>(
        xz, conv_w, conv_b, u2, u2bf);

    // 4. xdbl = u2 @ W_xp  [2048 x 96, K=2048]  bf16 MFMA split-K + reduce
    {
        dim3 grid(1, NROWS / 128, KSPLIT);
        gemm_bf16_mfma_splitk<<<grid, 256, 0, stream>>>(u2bf, WtXp, parts);
        reduce_partials_kernel<<<(NROWS * XDBL_W + 255) / 256, 256, 0, stream>>>(
            parts, xdbl, NROWS * XDBL_W);
    }

    // 5. dt = softplus(xdbl[:, :64] @ W_dt + b_dt)  [2048 x 2048, K=64]
    {
        dim3 grid(D_INNER / 64, NROWS / 64);
        gemm_tiled<true><<<grid, 256, 0, stream>>>(
            xdbl, W_dt, dtbuf, NROWS, D_INNER, 0, DT_RANK,
            XDBL_W, D_INNER, D_INNER, b_dt);
    }

    // 6. chunked parallel scan (A: partials, B: inter-chunk, C: final+gate)
    scan_partial_kernel<<<NCHUNK * (NCHAN / 16), 256, 0, stream>>>(
        dtbuf, xdbl, u2, A_log, hend, sumdt);
    scan_combine_kernel<<<NCHAN, 1024, 0, stream>>>(A_log, sumdt, hend);
    scan_final_kernel<<<NCHUNK * (NCHAN / 16), 256, 0, stream>>>(
        dtbuf, xdbl, xz, u2, ybf, A_log, D_param, hend);

    // 7. out = x + res_scale * (y @ W_out)  [2048 x 1024, K=2048]  (bf16 MFMA)
    {
        dim3 grid(D_MODEL / 128, NROWS / 128);
        gemm_bf16_mfma<true><<<grid, 256, 0, stream>>>(
            ybf, WtOut, out, NROWS, D_MODEL, D_INNER, x, res_sc);
    }
}

// Round 5
// 221.626 us; speedup vs baseline: 10.0699x; 1.3797x over previous
//
#include <hip/hip_runtime.h>
#include <hip/hip_bf16.h>

// Dims (compile-time constants from the reference)
#define D_MODEL 1024
#define D_STATE 16
#define D_CONV  4
#define D_INNER 2048
#define DT_RANK 64
#define BATCH   2
#define SEQLEN  1024
#define NROWS   (BATCH * SEQLEN)        // 2048
#define XDBL_W  (DT_RANK + 2 * D_STATE) // 96
#define NCHUNK  64                      // chunks per sequence
#define LCHUNK  16                      // steps per chunk
#define NCHAN   (BATCH * D_INNER)       // 4096 (b,e) channels
#define KSPLIT  8                       // split-K factor for W_xp GEMM

typedef unsigned short ushort_t;
typedef __attribute__((ext_vector_type(8))) short bf16x8;
typedef __attribute__((ext_vector_type(4))) float f32x4;

// fp32 -> bf16 (round-to-nearest-even), bit-level (deterministic)
__device__ __forceinline__ ushort_t f2bf(float f) {
    union { float f; unsigned u; } v; v.f = f;
    unsigned r = v.u + 0x7fffu + ((v.u >> 16) & 1u);
    return (ushort_t)(r >> 16);
}

__device__ __forceinline__ float fast_sigmoid(float z) {
    return __builtin_amdgcn_rcpf(1.f + __expf(-z));
}

// ---------------------------------------------------------------------------
// LayerNorm: one block per row of 1024, 256 threads x float4. Emits bf16.
// ---------------------------------------------------------------------------
__global__ __launch_bounds__(256)
void layernorm_kernel(const float* __restrict__ x, const float* __restrict__ g,
                      const float* __restrict__ bb, ushort_t* __restrict__ xnbf)
{
    int row = blockIdx.x;
    const float* xr = x + (size_t)row * D_MODEL;
    int tid = threadIdx.x;
    float4 v = reinterpret_cast<const float4*>(xr)[tid];
    float s  = v.x + v.y + v.z + v.w;
    float ss = v.x * v.x + v.y * v.y + v.z * v.z + v.w * v.w;
    #pragma unroll
    for (int off = 32; off; off >>= 1) {
        s  += __shfl_down(s, off);
        ss += __shfl_down(ss, off);
    }
    __shared__ float sbuf[4], ssbuf[4];
    int wid = tid >> 6, lane = tid & 63;
    if (lane == 0) { sbuf[wid] = s; ssbuf[wid] = ss; }
    __syncthreads();
    if (tid == 0) {
        float st = 0.f, sst = 0.f;
        #pragma unroll
        for (int i = 0; i < 4; ++i) { st += sbuf[i]; sst += ssbuf[i]; }
        sbuf[0] = st; ssbuf[0] = sst;
    }
    __syncthreads();
    float mu  = sbuf[0] * (1.f / D_MODEL);
    float var = ssbuf[0] * (1.f / D_MODEL) - mu * mu;
    float inv = rsqrtf(var + 1e-5f);
    float4 gv = reinterpret_cast<const float4*>(g)[tid];
    float4 bv = reinterpret_cast<const float4*>(bb)[tid];
    ushort4 o;
    o.x = f2bf((v.x - mu) * inv * gv.x + bv.x);
    o.y = f2bf((v.y - mu) * inv * gv.y + bv.y);
    o.z = f2bf((v.z - mu) * inv * gv.z + bv.z);
    o.w = f2bf((v.w - mu) * inv * gv.w + bv.w);
    reinterpret_cast<ushort4*>(xnbf + (size_t)row * D_MODEL)[tid] = o;
}

// ---------------------------------------------------------------------------
// Transpose + fp32->bf16 convert: Wt[c][r] = bf16(W[r][c]).  W is [R][C].
// ---------------------------------------------------------------------------
__global__ __launch_bounds__(256)
void transpose_convert_kernel(const float* __restrict__ W, ushort_t* __restrict__ Wt,
                              int R, int C)
{
    __shared__ float t[32][33];
    int c0 = blockIdx.x * 32, r0 = blockIdx.y * 32;
    int tx = threadIdx.x, ty = threadIdx.y;
    #pragma unroll
    for (int i = 0; i < 32; i += 8)
        t[ty + i][tx] = W[(size_t)(r0 + ty + i) * C + c0 + tx];
    __syncthreads();
    #pragma unroll
    for (int i = 0; i < 32; i += 8)
        Wt[(size_t)(c0 + ty + i) * R + r0 + tx] = f2bf(t[tx][ty + i]);
}

// ---------------------------------------------------------------------------
// bf16 MFMA GEMM (m97 structure): C[M,N] = A[M,K] x Bt[N,K]^T, fp32 out.
// 128x128 tile, BK=32, 256 thr (4 waves, 2x2 of 64x64), 16x16x32 MFMA.
// ---------------------------------------------------------------------------
__device__ __forceinline__ void stage128x32(const ushort_t* __restrict__ gbase,
                                            size_t ld, ushort_t* ldsb, int tid)
{
    int l = tid & 63;
    int w = tid >> 6;
    int row = w * 16 + (l >> 2);     // 0..63 within issue
    int kg  = l & 3;                 // 8-elem group
    char* lb = (char*)ldsb + w * 1024;
    const ushort_t* g0 = gbase + (size_t)row * ld + kg * 8;
    __builtin_amdgcn_global_load_lds(
        (const __attribute__((address_space(1))) unsigned*)g0,
        (__attribute__((address_space(3))) unsigned*)lb, 16, 0, 0);
    const ushort_t* g1 = g0 + (size_t)64 * ld;
    __builtin_amdgcn_global_load_lds(
        (const __attribute__((address_space(1))) unsigned*)g1,
        (__attribute__((address_space(3))) unsigned*)(lb + 4096), 16, 0, 0);
}

template<bool RESIDUAL>
__global__ __launch_bounds__(256)
void gemm_bf16_mfma(const ushort_t* __restrict__ A, const ushort_t* __restrict__ Bt,
                    float* __restrict__ C, int M, int N, int K,
                    const float* __restrict__ xres, const float* __restrict__ res_scale)
{
    __shared__ ushort_t As[128 * 32];
    __shared__ ushort_t Bs[128 * 32];
    int tid = threadIdx.x;
    int l = tid & 63, wid = tid >> 6;
    int wr = wid >> 1, wc = wid & 1;           // wave's 64x64 quadrant
    int row0 = blockIdx.y * 128, col0 = blockIdx.x * 128;

    f32x4 acc[4][4];
    #pragma unroll
    for (int m = 0; m < 4; ++m)
        #pragma unroll
        for (int n = 0; n < 4; ++n)
            acc[m][n] = (f32x4){0.f, 0.f, 0.f, 0.f};

    const ushort_t* Ab = A  + (size_t)row0 * K;
    const ushort_t* Bb = Bt + (size_t)col0 * K;
    int arow = wr * 64 + (l & 15);
    int brow = wc * 64 + (l & 15);
    int kb   = (l >> 4) * 8;

    for (int k0 = 0; k0 < K; k0 += 32) {
        stage128x32(Ab + k0, K, As, tid);
        stage128x32(Bb + k0, K, Bs, tid);
        __syncthreads();
        bf16x8 af[4], bfr[4];
        #pragma unroll
        for (int m = 0; m < 4; ++m)
            af[m] = *reinterpret_cast<const bf16x8*>(&As[(arow + m * 16) * 32 + kb]);
        #pragma unroll
        for (int n = 0; n < 4; ++n)
            bfr[n] = *reinterpret_cast<const bf16x8*>(&Bs[(brow + n * 16) * 32 + kb]);
        #pragma unroll
        for (int m = 0; m < 4; ++m)
            #pragma unroll
            for (int n = 0; n < 4; ++n)
                acc[m][n] = __builtin_amdgcn_mfma_f32_16x16x32_bf16(
                    af[m], bfr[n], acc[m][n], 0, 0, 0);
        __syncthreads();
    }

    float rs = RESIDUAL ? res_scale[0] : 0.f;
    int ro = (l >> 4) * 4, co = l & 15;
    #pragma unroll
    for (int m = 0; m < 4; ++m) {
        #pragma unroll
        for (int n = 0; n < 4; ++n) {
            int c = col0 + wc * 64 + n * 16 + co;
            #pragma unroll
            for (int reg = 0; reg < 4; ++reg) {
                int r = row0 + wr * 64 + m * 16 + ro + reg;
                float v = acc[m][n][reg];
                if (RESIDUAL) v = xres[(size_t)r * N + c] + rs * v;
                C[(size_t)r * N + c] = v;
            }
        }
    }
}

// ---------------------------------------------------------------------------
// Split-K bf16 MFMA GEMM for xdbl: A[2048,2048] x Bt[128(pad),2048]^T.
// ---------------------------------------------------------------------------
__global__ __launch_bounds__(256)
void gemm_bf16_mfma_splitk(const ushort_t* __restrict__ A, const ushort_t* __restrict__ Bt,
                           float* __restrict__ parts)
{
    __shared__ ushort_t As[128 * 32];
    __shared__ ushort_t Bs[128 * 32];
    const int K = D_INNER;
    const int KS = D_INNER / KSPLIT;           // 256
    int tid = threadIdx.x;
    int l = tid & 63, wid = tid >> 6;
    int wr = wid >> 1, wc = wid & 1;
    int row0 = blockIdx.y * 128;
    int kbeg = blockIdx.z * KS;

    f32x4 acc[4][4];
    #pragma unroll
    for (int m = 0; m < 4; ++m)
        #pragma unroll
        for (int n = 0; n < 4; ++n)
            acc[m][n] = (f32x4){0.f, 0.f, 0.f, 0.f};

    const ushort_t* Ab = A  + (size_t)row0 * K + kbeg;
    const ushort_t* Bb = Bt + kbeg;
    int arow = wr * 64 + (l & 15);
    int brow = wc * 64 + (l & 15);
    int kb   = (l >> 4) * 8;

    for (int k0 = 0; k0 < KS; k0 += 32) {
        stage128x32(Ab + k0, K, As, tid);
        stage128x32(Bb + k0, K, Bs, tid);
        __syncthreads();
        bf16x8 af[4], bfr[4];
        #pragma unroll
        for (int m = 0; m < 4; ++m)
            af[m] = *reinterpret_cast<const bf16x8*>(&As[(arow + m * 16) * 32 + kb]);
        #pragma unroll
        for (int n = 0; n < 4; ++n)
            bfr[n] = *reinterpret_cast<const bf16x8*>(&Bs[(brow + n * 16) * 32 + kb]);
        #pragma unroll
        for (int m = 0; m < 4; ++m)
            #pragma unroll
            for (int n = 0; n < 4; ++n)
                acc[m][n] = __builtin_amdgcn_mfma_f32_16x16x32_bf16(
                    af[m], bfr[n], acc[m][n], 0, 0, 0);
        __syncthreads();
    }

    float* Cp = parts + (size_t)blockIdx.z * NROWS * XDBL_W;
    int ro = (l >> 4) * 4, co = l & 15;
    #pragma unroll
    for (int m = 0; m < 4; ++m) {
        #pragma unroll
        for (int n = 0; n < 4; ++n) {
            int c = wc * 64 + n * 16 + co;
            if (c >= XDBL_W) continue;
            #pragma unroll
            for (int reg = 0; reg < 4; ++reg) {
                int r = row0 + wr * 64 + m * 16 + ro + reg;
                Cp[(size_t)r * XDBL_W + c] = acc[m][n][reg];
            }
        }
    }
}

// Split-K reduction: out[i] = sum_s partials[s][i]
__global__ __launch_bounds__(256)
void reduce_partials_kernel(const float* __restrict__ p, float* __restrict__ out, int n)
{
    int i = blockIdx.x * 256 + threadIdx.x;
    if (i >= n) return;
    float s = 0.f;
    #pragma unroll
    for (int k = 0; k < KSPLIT; ++k) s += p[(size_t)k * n + i];
    out[i] = s;
}

// ---------------------------------------------------------------------------
// fp32 tiled GEMM (used for the dt GEMM, K=64). Optional fused
// epilogue: C = softplus(acc + bias[col]).
// ---------------------------------------------------------------------------
template<bool SPBIAS>
__global__ __launch_bounds__(256)
void gemm_tiled(const float* __restrict__ A, const float* __restrict__ B,
                float* __restrict__ C,
                int M, int N, int kbeg, int kend, int lda, int ldb, int ldc,
                const float* __restrict__ bias)
{
    __shared__ float As[16][68];
    __shared__ float Bs[16][64];
    int tid = threadIdx.x;
    int tx = tid & 15, ty = tid >> 4;
    int row0 = blockIdx.y * 64, col0 = blockIdx.x * 64;
    float acc[4][4] = {};

    for (int k0 = kbeg; k0 < kend; k0 += 16) {
        {
            int kk = tid & 15;
            int m0 = tid >> 4;
            #pragma unroll
            for (int r = 0; r < 4; ++r) {
                int mm = m0 + 16 * r;
                int grow = row0 + mm, gk = k0 + kk;
                float v = 0.f;
                if (grow < M && gk < kend) v = A[(size_t)grow * lda + gk];
                As[kk][mm] = v;
            }
        }
        {
            int nn = tid & 63;
            int kbw = tid >> 6;
            #pragma unroll
            for (int r = 0; r < 4; ++r) {
                int kk = kbw + 4 * r;
                int gk = k0 + kk, gcol = col0 + nn;
                float v = 0.f;
                if (gk < kend && gcol < N) v = B[(size_t)gk * ldb + gcol];
                Bs[kk][nn] = v;
            }
        }
        __syncthreads();
        #pragma unroll
        for (int kk = 0; kk < 16; ++kk) {
            float4 a4 = *reinterpret_cast<const float4*>(&As[kk][ty * 4]);
            float4 b4 = *reinterpret_cast<const float4*>(&Bs[kk][tx * 4]);
            float av[4] = {a4.x, a4.y, a4.z, a4.w};
            float bv[4] = {b4.x, b4.y, b4.z, b4.w};
            #pragma unroll
            for (int i = 0; i < 4; ++i)
                #pragma unroll
                for (int j = 0; j < 4; ++j)
                    acc[i][j] += av[i] * bv[j];
        }
        __syncthreads();
    }

    #pragma unroll
    for (int i = 0; i < 4; ++i) {
        int r = row0 + ty * 4 + i;
        if (r >= M) continue;
        #pragma unroll
        for (int j = 0; j < 4; ++j) {
            int c = col0 + tx * 4 + j;
            if (c >= N) continue;
            float v = acc[i][j];
            if (SPBIAS) {
                v += bias[c];
                v = (v > 20.f) ? v : log1pf(expf(v));   // softplus, once per elem
            }
            C[(size_t)r * ldc + c] = v;
        }
    }
}

// ---------------------------------------------------------------------------
// Depthwise causal conv (K=4) + bias + SiLU. Writes u2 (fp32) and u2bf (bf16).
// ---------------------------------------------------------------------------
__global__ __launch_bounds__(256)
void conv_silu_kernel(const float* __restrict__ xz, const float* __restrict__ cw,
                      const float* __restrict__ cb, float* __restrict__ u2,
                      ushort_t* __restrict__ u2bf)
{
    int idx = blockIdx.x * 256 + threadIdx.x;   // < 2*1024*2048
    int e = idx & (D_INNER - 1);
    int l = (idx >> 11) & (SEQLEN - 1);
    int b = idx >> 21;
    const float* base = xz + (size_t)b * SEQLEN * (2 * D_INNER) + e;
    float w0 = cw[e * 4 + 0], w1 = cw[e * 4 + 1];
    float w2 = cw[e * 4 + 2], w3 = cw[e * 4 + 3];
    float acc = cb[e];
    if (l >= 3) acc += base[(size_t)(l - 3) * (2 * D_INNER)] * w0;
    if (l >= 2) acc += base[(size_t)(l - 2) * (2 * D_INNER)] * w1;
    if (l >= 1) acc += base[(size_t)(l - 1) * (2 * D_INNER)] * w2;
    acc += base[(size_t)l * (2 * D_INNER)] * w3;
    float sv = acc * fast_sigmoid(acc);         // SiLU
    u2[idx] = sv;
    u2bf[idx] = f2bf(sv);
}

// ---------------------------------------------------------------------------
// Chunked scan, pass A: ONE THREAD per (channel, chunk); all 16 states in
// registers. dt/u loaded once per step (coalesced: wave = 64 consecutive
// channels, same chunk); B row loads are wave-uniform (L1 broadcast).
// ---------------------------------------------------------------------------
__global__ __launch_bounds__(256)
void scan_partial_kernel(const float* __restrict__ dtbuf, const float* __restrict__ xdbl,
                         const float* __restrict__ u2,
                         const float* __restrict__ A_log,
                         float* __restrict__ hend, float* __restrict__ sumdt_buf)
{
    int idx = blockIdx.x * 256 + threadIdx.x;   // 0 .. NCHAN*NCHUNK-1
    int p = idx & (NCHAN - 1);                  // channel (64 consecutive/wave)
    int c = idx >> 12;                          // chunk
    int b = p >> 11, e = p & (D_INNER - 1);

    float An[D_STATE];
    {
        const float4* ar = reinterpret_cast<const float4*>(A_log + (size_t)e * D_STATE);
        #pragma unroll
        for (int q = 0; q < 4; ++q) {
            float4 a4 = ar[q];
            An[q * 4 + 0] = -__expf(a4.x);
            An[q * 4 + 1] = -__expf(a4.y);
            An[q * 4 + 2] = -__expf(a4.z);
            An[q * 4 + 3] = -__expf(a4.w);
        }
    }
    float h[D_STATE];
    #pragma unroll
    for (int n = 0; n < D_STATE; ++n) h[n] = 0.f;
    float sdt = 0.f;

    size_t rowbase = (size_t)b * SEQLEN + c * LCHUNK;
    #pragma unroll
    for (int j = 0; j < LCHUNK; ++j) {
        size_t row = rowbase + j;
        float dt = dtbuf[row * D_INNER + e];
        float u  = u2[row * D_INNER + e];
        float dtu = dt * u;
        sdt += dt;
        const float4* xr = reinterpret_cast<const float4*>(xdbl + row * XDBL_W + DT_RANK);
        float Bv[D_STATE];
        #pragma unroll
        for (int q = 0; q < 4; ++q) {
            float4 b4 = xr[q];
            Bv[q * 4 + 0] = b4.x; Bv[q * 4 + 1] = b4.y;
            Bv[q * 4 + 2] = b4.z; Bv[q * 4 + 3] = b4.w;
        }
        #pragma unroll
        for (int n = 0; n < D_STATE; ++n)
            h[n] = __expf(dt * An[n]) * h[n] + dtu * Bv[n];
    }

    float4* hp = reinterpret_cast<float4*>(hend + ((size_t)p * NCHUNK + c) * D_STATE);
    #pragma unroll
    for (int q = 0; q < 4; ++q)
        hp[q] = (float4){h[q * 4 + 0], h[q * 4 + 1], h[q * 4 + 2], h[q * 4 + 3]};
    sumdt_buf[p * NCHUNK + c] = sdt;
}

// ---------------------------------------------------------------------------
// Pass B: per-channel inter-chunk Hillis-Steele scan; exclusive carry in place.
// ---------------------------------------------------------------------------
__global__ __launch_bounds__(1024)
void scan_combine_kernel(const float* __restrict__ A_log,
                         const float* __restrict__ sumdt_buf,
                         float* __restrict__ hend /* in: hend, out: hcarry */)
{
    __shared__ float Ps[NCHUNK][D_STATE];
    __shared__ float Hs[NCHUNK][D_STATE];
    int tid = threadIdx.x;
    int c = tid >> 4, n = tid & 15;
    int p = blockIdx.x;
    int e = p & (D_INNER - 1);
    float An = -__expf(A_log[e * D_STATE + n]);
    float P = __expf(An * sumdt_buf[p * NCHUNK + c]);
    float H = hend[(size_t)p * (NCHUNK * D_STATE) + c * D_STATE + n];
    Ps[c][n] = P; Hs[c][n] = H;
    __syncthreads();
    #pragma unroll
    for (int d = 1; d < NCHUNK; d <<= 1) {
        float Pl = 1.f, Hl = 0.f;
        if (c >= d) { Pl = Ps[c - d][n]; Hl = Hs[c - d][n]; }
        __syncthreads();
        H = P * Hl + H;   // (P,H) o (Pl,Hl)
        P = P * Pl;
        Ps[c][n] = P; Hs[c][n] = H;
        __syncthreads();
    }
    float carry = (c == 0) ? 0.f : Hs[c - 1][n];
    hend[(size_t)p * (NCHUNK * D_STATE) + c * D_STATE + n] = carry;
}

// ---------------------------------------------------------------------------
// Pass C: one thread per (channel, chunk), seeded with carry; in-register
// dot with C row; fused D-skip + SiLU(z) gate; writes y as bf16.
// ---------------------------------------------------------------------------
__global__ __launch_bounds__(256)
void scan_final_kernel(const float* __restrict__ dtbuf, const float* __restrict__ xdbl,
                       const float* __restrict__ xz, const float* __restrict__ u2,
                       ushort_t* __restrict__ ybf,
                       const float* __restrict__ A_log,
                       const float* __restrict__ D_param,
                       const float* __restrict__ hcarry)
{
    int idx = blockIdx.x * 256 + threadIdx.x;
    int p = idx & (NCHAN - 1);
    int c = idx >> 12;
    int b = p >> 11, e = p & (D_INNER - 1);
    float De = D_param[e];

    float An[D_STATE];
    {
        const float4* ar = reinterpret_cast<const float4*>(A_log + (size_t)e * D_STATE);
        #pragma unroll
        for (int q = 0; q < 4; ++q) {
            float4 a4 = ar[q];
            An[q * 4 + 0] = -__expf(a4.x);
            An[q * 4 + 1] = -__expf(a4.y);
            An[q * 4 + 2] = -__expf(a4.z);
            An[q * 4 + 3] = -__expf(a4.w);
        }
    }
    float h[D_STATE];
    {
        const float4* hp = reinterpret_cast<const float4*>(
            hcarry + ((size_t)p * NCHUNK + c) * D_STATE);
        #pragma unroll
        for (int q = 0; q < 4; ++q) {
            float4 h4 = hp[q];
            h[q * 4 + 0] = h4.x; h[q * 4 + 1] = h4.y;
            h[q * 4 + 2] = h4.z; h[q * 4 + 3] = h4.w;
        }
    }

    size_t rowbase = (size_t)b * SEQLEN + c * LCHUNK;
    #pragma unroll
    for (int j = 0; j < LCHUNK; ++j) {
        size_t row = rowbase + j;
        float dt = dtbuf[row * D_INNER + e];
        float u  = u2[row * D_INNER + e];
        float dtu = dt * u;
        const float4* xr = reinterpret_cast<const float4*>(xdbl + row * XDBL_W + DT_RANK);
        float Bv[D_STATE], Cv[D_STATE];
        #pragma unroll
        for (int q = 0; q < 4; ++q) {
            float4 b4 = xr[q];
            Bv[q * 4 + 0] = b4.x; Bv[q * 4 + 1] = b4.y;
            Bv[q * 4 + 2] = b4.z; Bv[q * 4 + 3] = b4.w;
            float4 c4 = xr[q + 4];
            Cv[q * 4 + 0] = c4.x; Cv[q * 4 + 1] = c4.y;
            Cv[q * 4 + 2] = c4.z; Cv[q * 4 + 3] = c4.w;
        }
        float y = 0.f;
        #pragma unroll
        for (int n = 0; n < D_STATE; ++n) {
            h[n] = __expf(dt * An[n]) * h[n] + dtu * Bv[n];
            y += h[n] * Cv[n];
        }
        float z  = xz[row * (2 * D_INNER) + D_INNER + e];
        float sz = z * fast_sigmoid(z);
        ybf[row * D_INNER + e] = f2bf((y + u * De) * sz);
    }
}

// ---------------------------------------------------------------------------
extern "C" void kernel_launch(void* const* d_in, const int* in_sizes, int n_in,
                              void* d_out, int out_size, void* d_ws, size_t ws_size,
                              hipStream_t stream)
{
    const float* x       = (const float*)d_in[0];
    const float* ln_g    = (const float*)d_in[1];
    const float* ln_b    = (const float*)d_in[2];
    const float* W_in    = (const float*)d_in[3];
    const float* conv_w  = (const float*)d_in[4];
    const float* conv_b  = (const float*)d_in[5];
    const float* W_xp    = (const float*)d_in[6];
    const float* W_dt    = (const float*)d_in[7];
    const float* b_dt    = (const float*)d_in[8];
    const float* A_log   = (const float*)d_in[9];
    const float* D_param = (const float*)d_in[10];
    const float* W_out   = (const float*)d_in[11];
    const float* res_sc  = (const float*)d_in[12];
    float* out = (float*)d_out;

    char* ws = (char*)d_ws;
    const size_t MB = 1024 * 1024;
    // Workspace (liveness-overlapped):
    //   xz     [0,32M)      2048x4096 fp32
    //   u2     [32M,48M)    2048x2048 fp32
    //   dt     [48M,64M)    2048x2048 fp32 (softplus'd in GEMM epilogue)
    //   xdbl   [64M,65M)    2048x96 fp32
    //   hend   [65M,81M)    4096x64x16 fp32    (written step 6)
    //   u2bf   [65M,73M)    2048x2048 bf16     (dead before hend written)
    //   sumdt  [81M,82M)
    //   xnbf   [82M,86M)    2048x1024 bf16
    //   WtIn   [86M,94M)    4096x1024 bf16
    //   WtOut  [94M,98M)    1024x2048 bf16
    //   ybf    [98M,106M)   2048x2048 bf16     (written step 6c)
    //   parts  [98M,104M)   8x2048x96 fp32     (dead before ybf written)
    //   WtXp   [106M,106.5M) 128x2048 bf16 (rows 96..127 zero)
    float*    xz    = (float*)(ws);
    float*    u2    = (float*)(ws + 32 * MB);
    float*    dtbuf = (float*)(ws + 48 * MB);
    float*    xdbl  = (float*)(ws + 64 * MB);
    float*    hend  = (float*)(ws + 65 * MB);
    ushort_t* u2bf  = (ushort_t*)(ws + 65 * MB);
    float*    sumdt = (float*)(ws + 81 * MB);
    ushort_t* xnbf  = (ushort_t*)(ws + 82 * MB);
    ushort_t* WtIn  = (ushort_t*)(ws + 86 * MB);
    ushort_t* WtOut = (ushort_t*)(ws + 94 * MB);
    ushort_t* ybf   = (ushort_t*)(ws + 98 * MB);
    float*    parts = (float*)(ws + 98 * MB);
    ushort_t* WtXp  = (ushort_t*)(ws + 106 * MB);

    // 0. weight transpose+convert (bf16); zero WtXp pad rows [96,128)
    {
        dim3 blk(32, 8);
        dim3 g1((2 * D_INNER) / 32, D_MODEL / 32);
        transpose_convert_kernel<<<g1, blk, 0, stream>>>(W_in, WtIn, D_MODEL, 2 * D_INNER);
        dim3 g2(D_MODEL / 32, D_INNER / 32);
        transpose_convert_kernel<<<g2, blk, 0, stream>>>(W_out, WtOut, D_INNER, D_MODEL);
        dim3 g3(XDBL_W / 32, D_INNER / 32);
        transpose_convert_kernel<<<g3, blk, 0, stream>>>(W_xp, WtXp, D_INNER, XDBL_W);
        hipMemsetAsync(WtXp + (size_t)XDBL_W * D_INNER, 0,
                       (size_t)(128 - XDBL_W) * D_INNER * sizeof(ushort_t), stream);
    }

    // 1. LayerNorm -> bf16 A operand
    layernorm_kernel<<<NROWS, 256, 0, stream>>>(x, ln_g, ln_b, xnbf);

    // 2. xz = xn @ W_in   [2048 x 4096, K=1024]  (bf16 MFMA)
    {
        dim3 grid((2 * D_INNER) / 128, NROWS / 128);
        gemm_bf16_mfma<false><<<grid, 256, 0, stream>>>(
            xnbf, WtIn, xz, NROWS, 2 * D_INNER, D_MODEL, nullptr, nullptr);
    }

    // 3. u2 = silu(causal_conv(u) + conv_b)   (fp32 + bf16 copies)
    conv_silu_kernel<<<(BATCH * SEQLEN * D_INNER) / 256, 256, 0, stream>>>(
        xz, conv_w, conv_b, u2, u2bf);

    // 4. xdbl = u2 @ W_xp  [2048 x 96, K=2048]  bf16 MFMA split-K + reduce
    {
        dim3 grid(1, NROWS / 128, KSPLIT);
        gemm_bf16_mfma_splitk<<<grid, 256, 0, stream>>>(u2bf, WtXp, parts);
        reduce_partials_kernel<<<(NROWS * XDBL_W + 255) / 256, 256, 0, stream>>>(
            parts, xdbl, NROWS * XDBL_W);
    }

    // 5. dt = softplus(xdbl[:, :64] @ W_dt + b_dt)  [2048 x 2048, K=64]
    {
        dim3 grid(D_INNER / 64, NROWS / 64);
        gemm_tiled<true><<<grid, 256, 0, stream>>>(
            xdbl, W_dt, dtbuf, NROWS, D_INNER, 0, DT_RANK,
            XDBL_W, D_INNER, D_INNER, b_dt);
    }

    // 6. chunked parallel scan (A: partials, B: inter-chunk, C: final+gate)
    scan_partial_kernel<<<(NCHAN * NCHUNK) / 256, 256, 0, stream>>>(
        dtbuf, xdbl, u2, A_log, hend, sumdt);
    scan_combine_kernel<<<NCHAN, 1024, 0, stream>>>(A_log, sumdt, hend);
    scan_final_kernel<<<(NCHAN * NCHUNK) / 256, 256, 0, stream>>>(
        dtbuf, xdbl, xz, u2, ybf, A_log, D_param, hend);

    // 7. out = x + res_scale * (y @ W_out)  [2048 x 1024, K=2048]  (bf16 MFMA)
    {
        dim3 grid(D_MODEL / 128, NROWS / 128);
        gemm_bf16_mfma<true><<<grid, 256, 0, stream>>>(
            ybf, WtOut, out, NROWS, D_MODEL, D_INNER, x, res_sc);
    }
}

// Round 6
// 202.018 us; speedup vs baseline: 11.0473x; 1.0971x over previous
//
#include <hip/hip_runtime.h>
#include <hip/hip_bf16.h>

// Dims (compile-time constants from the reference)
#define D_MODEL 1024
#define D_STATE 16
#define D_CONV  4
#define D_INNER 2048
#define DT_RANK 64
#define BATCH   2
#define SEQLEN  1024
#define NROWS   (BATCH * SEQLEN)        // 2048
#define XDBL_W  (DT_RANK + 2 * D_STATE) // 96
#define NCHUNK  64                      // chunks per sequence
#define LCHUNK  16                      // steps per chunk
#define NCHAN   (BATCH * D_INNER)       // 4096 (b,e) channels
#define KSPLIT_XDBL 8
#define KSPLIT_OUT  4

typedef unsigned short ushort_t;
typedef __attribute__((ext_vector_type(8))) short bf16x8;
typedef __attribute__((ext_vector_type(4))) float f32x4;

// fp32 -> bf16 (round-to-nearest-even), bit-level (deterministic)
__device__ __forceinline__ ushort_t f2bf(float f) {
    union { float f; unsigned u; } v; v.f = f;
    unsigned r = v.u + 0x7fffu + ((v.u >> 16) & 1u);
    return (ushort_t)(r >> 16);
}
__device__ __forceinline__ float bf2f(ushort_t h) {
    union { unsigned u; float f; } v; v.u = (unsigned)h << 16; return v.f;
}
__device__ __forceinline__ float fast_sigmoid(float z) {
    return __builtin_amdgcn_rcpf(1.f + __expf(-z));
}

// ---------------------------------------------------------------------------
// LayerNorm: one block per row of 1024, 256 threads x float4. Emits bf16.
// ---------------------------------------------------------------------------
__global__ __launch_bounds__(256)
void layernorm_kernel(const float* __restrict__ x, const float* __restrict__ g,
                      const float* __restrict__ bb, ushort_t* __restrict__ xnbf)
{
    int row = blockIdx.x;
    const float* xr = x + (size_t)row * D_MODEL;
    int tid = threadIdx.x;
    float4 v = reinterpret_cast<const float4*>(xr)[tid];
    float s  = v.x + v.y + v.z + v.w;
    float ss = v.x * v.x + v.y * v.y + v.z * v.z + v.w * v.w;
    #pragma unroll
    for (int off = 32; off; off >>= 1) {
        s  += __shfl_down(s, off);
        ss += __shfl_down(ss, off);
    }
    __shared__ float sbuf[4], ssbuf[4];
    int wid = tid >> 6, lane = tid & 63;
    if (lane == 0) { sbuf[wid] = s; ssbuf[wid] = ss; }
    __syncthreads();
    if (tid == 0) {
        float st = 0.f, sst = 0.f;
        #pragma unroll
        for (int i = 0; i < 4; ++i) { st += sbuf[i]; sst += ssbuf[i]; }
        sbuf[0] = st; ssbuf[0] = sst;
    }
    __syncthreads();
    float mu  = sbuf[0] * (1.f / D_MODEL);
    float var = ssbuf[0] * (1.f / D_MODEL) - mu * mu;
    float inv = rsqrtf(var + 1e-5f);
    float4 gv = reinterpret_cast<const float4*>(g)[tid];
    float4 bv = reinterpret_cast<const float4*>(bb)[tid];
    ushort4 o;
    o.x = f2bf((v.x - mu) * inv * gv.x + bv.x);
    o.y = f2bf((v.y - mu) * inv * gv.y + bv.y);
    o.z = f2bf((v.z - mu) * inv * gv.z + bv.z);
    o.w = f2bf((v.w - mu) * inv * gv.w + bv.w);
    reinterpret_cast<ushort4*>(xnbf + (size_t)row * D_MODEL)[tid] = o;
}

// ---------------------------------------------------------------------------
// Transpose + fp32->bf16 convert: Wt[c][r] = bf16(W[r][c]).  W is [R][C].
// ---------------------------------------------------------------------------
__global__ __launch_bounds__(256)
void transpose_convert_kernel(const float* __restrict__ W, ushort_t* __restrict__ Wt,
                              int R, int C)
{
    __shared__ float t[32][33];
    int c0 = blockIdx.x * 32, r0 = blockIdx.y * 32;
    int tx = threadIdx.x, ty = threadIdx.y;
    #pragma unroll
    for (int i = 0; i < 32; i += 8)
        t[ty + i][tx] = W[(size_t)(r0 + ty + i) * C + c0 + tx];
    __syncthreads();
    #pragma unroll
    for (int i = 0; i < 32; i += 8)
        Wt[(size_t)(c0 + ty + i) * R + r0 + tx] = f2bf(t[tx][ty + i]);
}

// ---------------------------------------------------------------------------
// Global->LDS staging for a 128x32 bf16 tile (linear LDS), width-16 async.
// ---------------------------------------------------------------------------
__device__ __forceinline__ void stage128x32(const ushort_t* __restrict__ gbase,
                                            size_t ld, ushort_t* ldsb, int tid)
{
    int l = tid & 63;
    int w = tid >> 6;
    int row = w * 16 + (l >> 2);
    int kg  = l & 3;
    char* lb = (char*)ldsb + w * 1024;
    const ushort_t* g0 = gbase + (size_t)row * ld + kg * 8;
    __builtin_amdgcn_global_load_lds(
        (const __attribute__((address_space(1))) unsigned*)g0,
        (__attribute__((address_space(3))) unsigned*)lb, 16, 0, 0);
    const ushort_t* g1 = g0 + (size_t)64 * ld;
    __builtin_amdgcn_global_load_lds(
        (const __attribute__((address_space(1))) unsigned*)g1,
        (__attribute__((address_space(3))) unsigned*)(lb + 4096), 16, 0, 0);
}

// ---------------------------------------------------------------------------
// bf16 MFMA GEMM, bf16 output: C[M,N] = A[M,K] x Bt[N,K]^T.
// 128x128 tile, BK=32, 256 thr (4 waves, 2x2 of 64x64), 16x16x32 MFMA.
// ---------------------------------------------------------------------------
__global__ __launch_bounds__(256)
void gemm_bf16_mfma_bfout(const ushort_t* __restrict__ A, const ushort_t* __restrict__ Bt,
                          ushort_t* __restrict__ C, int M, int N, int K)
{
    __shared__ ushort_t As[128 * 32];
    __shared__ ushort_t Bs[128 * 32];
    int tid = threadIdx.x;
    int l = tid & 63, wid = tid >> 6;
    int wr = wid >> 1, wc = wid & 1;
    int row0 = blockIdx.y * 128, col0 = blockIdx.x * 128;

    f32x4 acc[4][4];
    #pragma unroll
    for (int m = 0; m < 4; ++m)
        #pragma unroll
        for (int n = 0; n < 4; ++n)
            acc[m][n] = (f32x4){0.f, 0.f, 0.f, 0.f};

    const ushort_t* Ab = A  + (size_t)row0 * K;
    const ushort_t* Bb = Bt + (size_t)col0 * K;
    int arow = wr * 64 + (l & 15);
    int brow = wc * 64 + (l & 15);
    int kb   = (l >> 4) * 8;

    for (int k0 = 0; k0 < K; k0 += 32) {
        stage128x32(Ab + k0, K, As, tid);
        stage128x32(Bb + k0, K, Bs, tid);
        __syncthreads();
        bf16x8 af[4], bfr[4];
        #pragma unroll
        for (int m = 0; m < 4; ++m)
            af[m] = *reinterpret_cast<const bf16x8*>(&As[(arow + m * 16) * 32 + kb]);
        #pragma unroll
        for (int n = 0; n < 4; ++n)
            bfr[n] = *reinterpret_cast<const bf16x8*>(&Bs[(brow + n * 16) * 32 + kb]);
        #pragma unroll
        for (int m = 0; m < 4; ++m)
            #pragma unroll
            for (int n = 0; n < 4; ++n)
                acc[m][n] = __builtin_amdgcn_mfma_f32_16x16x32_bf16(
                    af[m], bfr[n], acc[m][n], 0, 0, 0);
        __syncthreads();
    }

    int ro = (l >> 4) * 4, co = l & 15;
    #pragma unroll
    for (int m = 0; m < 4; ++m) {
        #pragma unroll
        for (int n = 0; n < 4; ++n) {
            int c = col0 + wc * 64 + n * 16 + co;
            #pragma unroll
            for (int reg = 0; reg < 4; ++reg) {
                int r = row0 + wr * 64 + m * 16 + ro + reg;
                C[(size_t)r * N + c] = f2bf(acc[m][n][reg]);
            }
        }
    }
}

// ---------------------------------------------------------------------------
// Unified split-K bf16 MFMA GEMM: parts[z][M][Nreal] = A x Bt^T over K-range.
// Grid (ceil(Nreal/128), M/128, nsplit). Bt rows padded to >= grid.x*128.
// ---------------------------------------------------------------------------
__global__ __launch_bounds__(256)
void gemm_bf16_splitk(const ushort_t* __restrict__ A, const ushort_t* __restrict__ Bt,
                      float* __restrict__ parts, int Nreal, int K)
{
    __shared__ ushort_t As[128 * 32];
    __shared__ ushort_t Bs[128 * 32];
    int M = gridDim.y * 128;
    int KS = K / gridDim.z;
    int kbeg = blockIdx.z * KS;
    int tid = threadIdx.x;
    int l = tid & 63, wid = tid >> 6;
    int wr = wid >> 1, wc = wid & 1;
    int row0 = blockIdx.y * 128, col0 = blockIdx.x * 128;

    f32x4 acc[4][4];
    #pragma unroll
    for (int m = 0; m < 4; ++m)
        #pragma unroll
        for (int n = 0; n < 4; ++n)
            acc[m][n] = (f32x4){0.f, 0.f, 0.f, 0.f};

    const ushort_t* Ab = A  + (size_t)row0 * K + kbeg;
    const ushort_t* Bb = Bt + (size_t)col0 * K + kbeg;
    int arow = wr * 64 + (l & 15);
    int brow = wc * 64 + (l & 15);
    int kb   = (l >> 4) * 8;

    for (int k0 = 0; k0 < KS; k0 += 32) {
        stage128x32(Ab + k0, K, As, tid);
        stage128x32(Bb + k0, K, Bs, tid);
        __syncthreads();
        bf16x8 af[4], bfr[4];
        #pragma unroll
        for (int m = 0; m < 4; ++m)
            af[m] = *reinterpret_cast<const bf16x8*>(&As[(arow + m * 16) * 32 + kb]);
        #pragma unroll
        for (int n = 0; n < 4; ++n)
            bfr[n] = *reinterpret_cast<const bf16x8*>(&Bs[(brow + n * 16) * 32 + kb]);
        #pragma unroll
        for (int m = 0; m < 4; ++m)
            #pragma unroll
            for (int n = 0; n < 4; ++n)
                acc[m][n] = __builtin_amdgcn_mfma_f32_16x16x32_bf16(
                    af[m], bfr[n], acc[m][n], 0, 0, 0);
        __syncthreads();
    }

    float* Cp = parts + (size_t)blockIdx.z * M * Nreal;
    int ro = (l >> 4) * 4, co = l & 15;
    #pragma unroll
    for (int m = 0; m < 4; ++m) {
        #pragma unroll
        for (int n = 0; n < 4; ++n) {
            int c = col0 + wc * 64 + n * 16 + co;
            if (c >= Nreal) continue;
            #pragma unroll
            for (int reg = 0; reg < 4; ++reg) {
                int r = row0 + wr * 64 + m * 16 + ro + reg;
                Cp[(size_t)r * Nreal + c] = acc[m][n][reg];
            }
        }
    }
}

// Split-K reduction (xdbl): out[i] = sum_s parts[s][i]
__global__ __launch_bounds__(256)
void reduce_partials_kernel(const float* __restrict__ p, float* __restrict__ out, int n)
{
    int i = blockIdx.x * 256 + threadIdx.x;
    if (i >= n) return;
    float s = 0.f;
    #pragma unroll
    for (int k = 0; k < KSPLIT_XDBL; ++k) s += p[(size_t)k * n + i];
    out[i] = s;
}

// Split-K reduction with residual (out GEMM): out = x + rs * sum(parts), float4
__global__ __launch_bounds__(256)
void reduce_out_kernel(const float* __restrict__ p, const float* __restrict__ x,
                       const float* __restrict__ res_scale, float* __restrict__ out,
                       int n4 /* = n/4 */)
{
    int i = blockIdx.x * 256 + threadIdx.x;
    if (i >= n4) return;
    float rs = res_scale[0];
    size_t n = (size_t)n4 * 4;
    float4 s = reinterpret_cast<const float4*>(p)[i];
    #pragma unroll
    for (int k = 1; k < KSPLIT_OUT; ++k) {
        float4 v = reinterpret_cast<const float4*>(p + k * n)[i];
        s.x += v.x; s.y += v.y; s.z += v.z; s.w += v.w;
    }
    float4 xv = reinterpret_cast<const float4*>(x)[i];
    float4 o;
    o.x = xv.x + rs * s.x; o.y = xv.y + rs * s.y;
    o.z = xv.z + rs * s.z; o.w = xv.w + rs * s.w;
    reinterpret_cast<float4*>(out)[i] = o;
}

// ---------------------------------------------------------------------------
// fp32 tiled GEMM (dt GEMM, K=64) with fused softplus+bias epilogue.
// ---------------------------------------------------------------------------
__global__ __launch_bounds__(256)
void gemm_tiled_sp(const float* __restrict__ A, const float* __restrict__ B,
                   float* __restrict__ C,
                   int M, int N, int kend, int lda, int ldb, int ldc,
                   const float* __restrict__ bias)
{
    __shared__ float As[16][68];
    __shared__ float Bs[16][64];
    int tid = threadIdx.x;
    int tx = tid & 15, ty = tid >> 4;
    int row0 = blockIdx.y * 64, col0 = blockIdx.x * 64;
    float acc[4][4] = {};

    for (int k0 = 0; k0 < kend; k0 += 16) {
        {
            int kk = tid & 15;
            int m0 = tid >> 4;
            #pragma unroll
            for (int r = 0; r < 4; ++r) {
                int mm = m0 + 16 * r;
                int grow = row0 + mm, gk = k0 + kk;
                float v = 0.f;
                if (grow < M && gk < kend) v = A[(size_t)grow * lda + gk];
                As[kk][mm] = v;
            }
        }
        {
            int nn = tid & 63;
            int kbw = tid >> 6;
            #pragma unroll
            for (int r = 0; r < 4; ++r) {
                int kk = kbw + 4 * r;
                int gk = k0 + kk, gcol = col0 + nn;
                float v = 0.f;
                if (gk < kend && gcol < N) v = B[(size_t)gk * ldb + gcol];
                Bs[kk][nn] = v;
            }
        }
        __syncthreads();
        #pragma unroll
        for (int kk = 0; kk < 16; ++kk) {
            float4 a4 = *reinterpret_cast<const float4*>(&As[kk][ty * 4]);
            float4 b4 = *reinterpret_cast<const float4*>(&Bs[kk][tx * 4]);
            float av[4] = {a4.x, a4.y, a4.z, a4.w};
            float bv[4] = {b4.x, b4.y, b4.z, b4.w};
            #pragma unroll
            for (int i = 0; i < 4; ++i)
                #pragma unroll
                for (int j = 0; j < 4; ++j)
                    acc[i][j] += av[i] * bv[j];
        }
        __syncthreads();
    }

    #pragma unroll
    for (int i = 0; i < 4; ++i) {
        int r = row0 + ty * 4 + i;
        if (r >= M) continue;
        #pragma unroll
        for (int j = 0; j < 4; ++j) {
            int c = col0 + tx * 4 + j;
            if (c >= N) continue;
            float v = acc[i][j] + bias[c];
            v = (v > 20.f) ? v : log1pf(expf(v));   // softplus, once per elem
            C[(size_t)r * ldc + c] = v;
        }
    }
}

// ---------------------------------------------------------------------------
// Depthwise causal conv (K=4) + bias + SiLU. bf16 in (u half of xz), bf16 out.
// ---------------------------------------------------------------------------
__global__ __launch_bounds__(256)
void conv_silu_kernel(const ushort_t* __restrict__ xzbf, const float* __restrict__ cw,
                      const float* __restrict__ cb, ushort_t* __restrict__ u2bf)
{
    int idx = blockIdx.x * 256 + threadIdx.x;   // < 2*1024*2048
    int e = idx & (D_INNER - 1);
    int l = (idx >> 11) & (SEQLEN - 1);
    int b = idx >> 21;
    const ushort_t* base = xzbf + (size_t)b * SEQLEN * (2 * D_INNER) + e;
    float w0 = cw[e * 4 + 0], w1 = cw[e * 4 + 1];
    float w2 = cw[e * 4 + 2], w3 = cw[e * 4 + 3];
    float acc = cb[e];
    if (l >= 3) acc += bf2f(base[(size_t)(l - 3) * (2 * D_INNER)]) * w0;
    if (l >= 2) acc += bf2f(base[(size_t)(l - 2) * (2 * D_INNER)]) * w1;
    if (l >= 1) acc += bf2f(base[(size_t)(l - 1) * (2 * D_INNER)]) * w2;
    acc += bf2f(base[(size_t)l * (2 * D_INNER)]) * w3;
    float sv = acc * fast_sigmoid(acc);         // SiLU
    u2bf[idx] = f2bf(sv);
}

// ---------------------------------------------------------------------------
// Chunked scan, pass A: one thread per (channel, chunk); 16 states in regs.
// ---------------------------------------------------------------------------
__global__ __launch_bounds__(256)
void scan_partial_kernel(const float* __restrict__ dtbuf, const float* __restrict__ xdbl,
                         const ushort_t* __restrict__ u2bf,
                         const float* __restrict__ A_log,
                         float* __restrict__ hend, float* __restrict__ sumdt_buf)
{
    int idx = blockIdx.x * 256 + threadIdx.x;   // 0 .. NCHAN*NCHUNK-1
    int p = idx & (NCHAN - 1);                  // channel (64 consecutive/wave)
    int c = idx >> 12;                          // chunk
    int b = p >> 11, e = p & (D_INNER - 1);

    float An[D_STATE];
    {
        const float4* ar = reinterpret_cast<const float4*>(A_log + (size_t)e * D_STATE);
        #pragma unroll
        for (int q = 0; q < 4; ++q) {
            float4 a4 = ar[q];
            An[q * 4 + 0] = -__expf(a4.x);
            An[q * 4 + 1] = -__expf(a4.y);
            An[q * 4 + 2] = -__expf(a4.z);
            An[q * 4 + 3] = -__expf(a4.w);
        }
    }
    float h[D_STATE];
    #pragma unroll
    for (int n = 0; n < D_STATE; ++n) h[n] = 0.f;
    float sdt = 0.f;

    size_t rowbase = (size_t)b * SEQLEN + c * LCHUNK;
    #pragma unroll
    for (int j = 0; j < LCHUNK; ++j) {
        size_t row = rowbase + j;
        float dt = dtbuf[row * D_INNER + e];
        float u  = bf2f(u2bf[row * D_INNER + e]);
        float dtu = dt * u;
        sdt += dt;
        const float4* xr = reinterpret_cast<const float4*>(xdbl + row * XDBL_W + DT_RANK);
        float Bv[D_STATE];
        #pragma unroll
        for (int q = 0; q < 4; ++q) {
            float4 b4 = xr[q];
            Bv[q * 4 + 0] = b4.x; Bv[q * 4 + 1] = b4.y;
            Bv[q * 4 + 2] = b4.z; Bv[q * 4 + 3] = b4.w;
        }
        #pragma unroll
        for (int n = 0; n < D_STATE; ++n)
            h[n] = __expf(dt * An[n]) * h[n] + dtu * Bv[n];
    }

    float4* hp = reinterpret_cast<float4*>(hend + ((size_t)p * NCHUNK + c) * D_STATE);
    #pragma unroll
    for (int q = 0; q < 4; ++q)
        hp[q] = (float4){h[q * 4 + 0], h[q * 4 + 1], h[q * 4 + 2], h[q * 4 + 3]};
    sumdt_buf[p * NCHUNK + c] = sdt;
}

// ---------------------------------------------------------------------------
// Pass B: per-channel inter-chunk Hillis-Steele scan; exclusive carry in place.
// ---------------------------------------------------------------------------
__global__ __launch_bounds__(1024)
void scan_combine_kernel(const float* __restrict__ A_log,
                         const float* __restrict__ sumdt_buf,
                         float* __restrict__ hend /* in: hend, out: hcarry */)
{
    __shared__ float Ps[NCHUNK][D_STATE];
    __shared__ float Hs[NCHUNK][D_STATE];
    int tid = threadIdx.x;
    int c = tid >> 4, n = tid & 15;
    int p = blockIdx.x;
    int e = p & (D_INNER - 1);
    float An = -__expf(A_log[e * D_STATE + n]);
    float P = __expf(An * sumdt_buf[p * NCHUNK + c]);
    float H = hend[(size_t)p * (NCHUNK * D_STATE) + c * D_STATE + n];
    Ps[c][n] = P; Hs[c][n] = H;
    __syncthreads();
    #pragma unroll
    for (int d = 1; d < NCHUNK; d <<= 1) {
        float Pl = 1.f, Hl = 0.f;
        if (c >= d) { Pl = Ps[c - d][n]; Hl = Hs[c - d][n]; }
        __syncthreads();
        H = P * Hl + H;   // (P,H) o (Pl,Hl)
        P = P * Pl;
        Ps[c][n] = P; Hs[c][n] = H;
        __syncthreads();
    }
    float carry = (c == 0) ? 0.f : Hs[c - 1][n];
    hend[(size_t)p * (NCHUNK * D_STATE) + c * D_STATE + n] = carry;
}

// ---------------------------------------------------------------------------
// Pass C: one thread per (channel, chunk), seeded with carry; in-register
// dot with C row; fused D-skip + SiLU(z) gate; writes y as bf16.
// ---------------------------------------------------------------------------
__global__ __launch_bounds__(256)
void scan_final_kernel(const float* __restrict__ dtbuf, const float* __restrict__ xdbl,
                       const ushort_t* __restrict__ xzbf, const ushort_t* __restrict__ u2bf,
                       ushort_t* __restrict__ ybf,
                       const float* __restrict__ A_log,
                       const float* __restrict__ D_param,
                       const float* __restrict__ hcarry)
{
    int idx = blockIdx.x * 256 + threadIdx.x;
    int p = idx & (NCHAN - 1);
    int c = idx >> 12;
    int b = p >> 11, e = p & (D_INNER - 1);
    float De = D_param[e];

    float An[D_STATE];
    {
        const float4* ar = reinterpret_cast<const float4*>(A_log + (size_t)e * D_STATE);
        #pragma unroll
        for (int q = 0; q < 4; ++q) {
            float4 a4 = ar[q];
            An[q * 4 + 0] = -__expf(a4.x);
            An[q * 4 + 1] = -__expf(a4.y);
            An[q * 4 + 2] = -__expf(a4.z);
            An[q * 4 + 3] = -__expf(a4.w);
        }
    }
    float h[D_STATE];
    {
        const float4* hp = reinterpret_cast<const float4*>(
            hcarry + ((size_t)p * NCHUNK + c) * D_STATE);
        #pragma unroll
        for (int q = 0; q < 4; ++q) {
            float4 h4 = hp[q];
            h[q * 4 + 0] = h4.x; h[q * 4 + 1] = h4.y;
            h[q * 4 + 2] = h4.z; h[q * 4 + 3] = h4.w;
        }
    }

    size_t rowbase = (size_t)b * SEQLEN + c * LCHUNK;
    #pragma unroll
    for (int j = 0; j < LCHUNK; ++j) {
        size_t row = rowbase + j;
        float dt = dtbuf[row * D_INNER + e];
        float u  = bf2f(u2bf[row * D_INNER + e]);
        float dtu = dt * u;
        const float4* xr = reinterpret_cast<const float4*>(xdbl + row * XDBL_W + DT_RANK);
        float Bv[D_STATE], Cv[D_STATE];
        #pragma unroll
        for (int q = 0; q < 4; ++q) {
            float4 b4 = xr[q];
            Bv[q * 4 + 0] = b4.x; Bv[q * 4 + 1] = b4.y;
            Bv[q * 4 + 2] = b4.z; Bv[q * 4 + 3] = b4.w;
            float4 c4 = xr[q + 4];
            Cv[q * 4 + 0] = c4.x; Cv[q * 4 + 1] = c4.y;
            Cv[q * 4 + 2] = c4.z; Cv[q * 4 + 3] = c4.w;
        }
        float y = 0.f;
        #pragma unroll
        for (int n = 0; n < D_STATE; ++n) {
            h[n] = __expf(dt * An[n]) * h[n] + dtu * Bv[n];
            y += h[n] * Cv[n];
        }
        float z  = bf2f(xzbf[row * (2 * D_INNER) + D_INNER + e]);
        float sz = z * fast_sigmoid(z);
        ybf[row * D_INNER + e] = f2bf((y + u * De) * sz);
    }
}

// ---------------------------------------------------------------------------
extern "C" void kernel_launch(void* const* d_in, const int* in_sizes, int n_in,
                              void* d_out, int out_size, void* d_ws, size_t ws_size,
                              hipStream_t stream)
{
    const float* x       = (const float*)d_in[0];
    const float* ln_g    = (const float*)d_in[1];
    const float* ln_b    = (const float*)d_in[2];
    const float* W_in    = (const float*)d_in[3];
    const float* conv_w  = (const float*)d_in[4];
    const float* conv_b  = (const float*)d_in[5];
    const float* W_xp    = (const float*)d_in[6];
    const float* W_dt    = (const float*)d_in[7];
    const float* b_dt    = (const float*)d_in[8];
    const float* A_log   = (const float*)d_in[9];
    const float* D_param = (const float*)d_in[10];
    const float* W_out   = (const float*)d_in[11];
    const float* res_sc  = (const float*)d_in[12];
    float* out = (float*)d_out;

    char* ws = (char*)d_ws;
    const size_t MB = 1024 * 1024;
    // Workspace (liveness-overlapped; peak 89 MB):
    //   xzbf    [0,16M)     2048x4096 bf16 (u cols 0-2047, z cols 2048-4095)
    //   u2bf    [16M,24M)   2048x2048 bf16
    //   dtbuf   [24M,40M)   2048x2048 fp32
    //   xdbl    [40M,41M)   2048x96 fp32
    //   hend    [41M,57M)   4096x64x16 fp32 (carry in place)
    //   sumdt   [57M,58M)
    //   xnbf    [58M,62M)   2048x1024 bf16
    //   WtIn    [62M,70M)   4096x1024 bf16
    //   WtOut   [70M,74M)   1024x2048 bf16
    //   WtXp    [74M,74.5M) 128x2048 bf16 (rows 96..127 zero)
    //   ybf     [75M,83M)   2048x2048 bf16
    //   partsX  [83M,89M)   8x2048x96 fp32
    //   partsO  [24M,56M)   4x2048x1024 fp32 (overlaps dtbuf/xdbl/hend — dead at step 7)
    ushort_t* xzbf   = (ushort_t*)(ws);
    ushort_t* u2bf   = (ushort_t*)(ws + 16 * MB);
    float*    dtbuf  = (float*)(ws + 24 * MB);
    float*    xdbl   = (float*)(ws + 40 * MB);
    float*    hend   = (float*)(ws + 41 * MB);
    float*    sumdt  = (float*)(ws + 57 * MB);
    ushort_t* xnbf   = (ushort_t*)(ws + 58 * MB);
    ushort_t* WtIn   = (ushort_t*)(ws + 62 * MB);
    ushort_t* WtOut  = (ushort_t*)(ws + 70 * MB);
    ushort_t* WtXp   = (ushort_t*)(ws + 74 * MB);
    ushort_t* ybf    = (ushort_t*)(ws + 75 * MB);
    float*    partsX = (float*)(ws + 83 * MB);
    float*    partsO = (float*)(ws + 24 * MB);

    // 0. weight transpose+convert (bf16); zero WtXp pad rows [96,128)
    {
        dim3 blk(32, 8);
        dim3 g1((2 * D_INNER) / 32, D_MODEL / 32);
        transpose_convert_kernel<<<g1, blk, 0, stream>>>(W_in, WtIn, D_MODEL, 2 * D_INNER);
        dim3 g2(D_MODEL / 32, D_INNER / 32);
        transpose_convert_kernel<<<g2, blk, 0, stream>>>(W_out, WtOut, D_INNER, D_MODEL);
        dim3 g3(XDBL_W / 32, D_INNER / 32);
        transpose_convert_kernel<<<g3, blk, 0, stream>>>(W_xp, WtXp, D_INNER, XDBL_W);
        hipMemsetAsync(WtXp + (size_t)XDBL_W * D_INNER, 0,
                       (size_t)(128 - XDBL_W) * D_INNER * sizeof(ushort_t), stream);
    }

    // 1. LayerNorm -> bf16 A operand
    layernorm_kernel<<<NROWS, 256, 0, stream>>>(x, ln_g, ln_b, xnbf);

    // 2. xz = xn @ W_in   [2048 x 4096, K=1024]  (bf16 MFMA, bf16 out)
    {
        dim3 grid((2 * D_INNER) / 128, NROWS / 128);
        gemm_bf16_mfma_bfout<<<grid, 256, 0, stream>>>(
            xnbf, WtIn, xzbf, NROWS, 2 * D_INNER, D_MODEL);
    }

    // 3. u2 = silu(causal_conv(u) + conv_b)   (bf16 in/out)
    conv_silu_kernel<<<(BATCH * SEQLEN * D_INNER) / 256, 256, 0, stream>>>(
        xzbf, conv_w, conv_b, u2bf);

    // 4. xdbl = u2 @ W_xp  [2048 x 96, K=2048]  bf16 MFMA split-K x8 + reduce
    {
        dim3 grid(1, NROWS / 128, KSPLIT_XDBL);
        gemm_bf16_splitk<<<grid, 256, 0, stream>>>(u2bf, WtXp, partsX, XDBL_W, D_INNER);
        reduce_partials_kernel<<<(NROWS * XDBL_W + 255) / 256, 256, 0, stream>>>(
            partsX, xdbl, NROWS * XDBL_W);
    }

    // 5. dt = softplus(xdbl[:, :64] @ W_dt + b_dt)  [2048 x 2048, K=64]
    {
        dim3 grid(D_INNER / 64, NROWS / 64);
        gemm_tiled_sp<<<grid, 256, 0, stream>>>(
            xdbl, W_dt, dtbuf, NROWS, D_INNER, DT_RANK,
            XDBL_W, D_INNER, D_INNER, b_dt);
    }

    // 6. chunked parallel scan (A: partials, B: inter-chunk, C: final+gate)
    scan_partial_kernel<<<(NCHAN * NCHUNK) / 256, 256, 0, stream>>>(
        dtbuf, xdbl, u2bf, A_log, hend, sumdt);
    scan_combine_kernel<<<NCHAN, 1024, 0, stream>>>(A_log, sumdt, hend);
    scan_final_kernel<<<(NCHAN * NCHUNK) / 256, 256, 0, stream>>>(
        dtbuf, xdbl, xzbf, u2bf, ybf, A_log, D_param, hend);

    // 7. out = x + res_scale * (y @ W_out)  split-K x4 MFMA + residual reduce
    {
        dim3 grid(D_MODEL / 128, NROWS / 128, KSPLIT_OUT);
        gemm_bf16_splitk<<<grid, 256, 0, stream>>>(ybf, WtOut, partsO, D_MODEL, D_INNER);
        reduce_out_kernel<<<(NROWS * D_MODEL / 4 + 255) / 256, 256, 0, stream>>>(
            partsO, x, res_sc, out, NROWS * D_MODEL / 4);
    }
}

// Round 7
// 181.344 us; speedup vs baseline: 12.3067x; 1.1140x over previous
//
#include <hip/hip_runtime.h>
#include <hip/hip_bf16.h>

// Dims (compile-time constants from the reference)
#define D_MODEL 1024
#define D_STATE 16
#define D_CONV  4
#define D_INNER 2048
#define DT_RANK 64
#define BATCH   2
#define SEQLEN  1024
#define NROWS   (BATCH * SEQLEN)        // 2048
#define XDBL_W  (DT_RANK + 2 * D_STATE) // 96
#define NCHUNK  64                      // chunks per sequence
#define LCHUNK  16                      // steps per chunk
#define NCHAN   (BATCH * D_INNER)       // 4096 (b,e) channels
#define KSPLIT_XDBL 8
#define KSPLIT_OUT  4

typedef unsigned short ushort_t;
typedef __attribute__((ext_vector_type(8))) short bf16x8;
typedef __attribute__((ext_vector_type(4))) float f32x4;

// fp32 -> bf16 (round-to-nearest-even), bit-level (deterministic)
__device__ __forceinline__ ushort_t f2bf(float f) {
    union { float f; unsigned u; } v; v.f = f;
    unsigned r = v.u + 0x7fffu + ((v.u >> 16) & 1u);
    return (ushort_t)(r >> 16);
}
__device__ __forceinline__ float bf2f(ushort_t h) {
    union { unsigned u; float f; } v; v.u = (unsigned)h << 16; return v.f;
}
__device__ __forceinline__ float fast_sigmoid(float z) {
    return __builtin_amdgcn_rcpf(1.f + __expf(-z));
}

// ---------------------------------------------------------------------------
// LayerNorm: one block per row of 1024, 256 threads x float4. Emits bf16.
// ---------------------------------------------------------------------------
__global__ __launch_bounds__(256)
void layernorm_kernel(const float* __restrict__ x, const float* __restrict__ g,
                      const float* __restrict__ bb, ushort_t* __restrict__ xnbf)
{
    int row = blockIdx.x;
    const float* xr = x + (size_t)row * D_MODEL;
    int tid = threadIdx.x;
    float4 v = reinterpret_cast<const float4*>(xr)[tid];
    float s  = v.x + v.y + v.z + v.w;
    float ss = v.x * v.x + v.y * v.y + v.z * v.z + v.w * v.w;
    #pragma unroll
    for (int off = 32; off; off >>= 1) {
        s  += __shfl_down(s, off);
        ss += __shfl_down(ss, off);
    }
    __shared__ float sbuf[4], ssbuf[4];
    int wid = tid >> 6, lane = tid & 63;
    if (lane == 0) { sbuf[wid] = s; ssbuf[wid] = ss; }
    __syncthreads();
    if (tid == 0) {
        float st = 0.f, sst = 0.f;
        #pragma unroll
        for (int i = 0; i < 4; ++i) { st += sbuf[i]; sst += ssbuf[i]; }
        sbuf[0] = st; ssbuf[0] = sst;
    }
    __syncthreads();
    float mu  = sbuf[0] * (1.f / D_MODEL);
    float var = ssbuf[0] * (1.f / D_MODEL) - mu * mu;
    float inv = rsqrtf(var + 1e-5f);
    float4 gv = reinterpret_cast<const float4*>(g)[tid];
    float4 bv = reinterpret_cast<const float4*>(bb)[tid];
    ushort4 o;
    o.x = f2bf((v.x - mu) * inv * gv.x + bv.x);
    o.y = f2bf((v.y - mu) * inv * gv.y + bv.y);
    o.z = f2bf((v.z - mu) * inv * gv.z + bv.z);
    o.w = f2bf((v.w - mu) * inv * gv.w + bv.w);
    reinterpret_cast<ushort4*>(xnbf + (size_t)row * D_MODEL)[tid] = o;
}

// ---------------------------------------------------------------------------
// Transpose + fp32->bf16 convert: Wt[c][r] = bf16(W[r][c]).  W is [R][C].
// ---------------------------------------------------------------------------
__global__ __launch_bounds__(256)
void transpose_convert_kernel(const float* __restrict__ W, ushort_t* __restrict__ Wt,
                              int R, int C)
{
    __shared__ float t[32][33];
    int c0 = blockIdx.x * 32, r0 = blockIdx.y * 32;
    int tx = threadIdx.x, ty = threadIdx.y;
    #pragma unroll
    for (int i = 0; i < 32; i += 8)
        t[ty + i][tx] = W[(size_t)(r0 + ty + i) * C + c0 + tx];
    __syncthreads();
    #pragma unroll
    for (int i = 0; i < 32; i += 8)
        Wt[(size_t)(c0 + ty + i) * R + r0 + tx] = f2bf(t[tx][ty + i]);
}

// Zero the WtXp pad rows [96,128): 32*2048 bf16 = 64K elems, ushort4 stores.
__global__ __launch_bounds__(256)
void pad_zero_kernel(ushort_t* __restrict__ dst)
{
    int i = blockIdx.x * 256 + threadIdx.x;   // 16384 threads x 4 elems
    reinterpret_cast<ushort4*>(dst)[i] = (ushort4){0, 0, 0, 0};
}

// ---------------------------------------------------------------------------
// Global->LDS staging for a 128x32 bf16 tile (linear LDS), width-16 async.
// ---------------------------------------------------------------------------
__device__ __forceinline__ void stage128x32(const ushort_t* __restrict__ gbase,
                                            size_t ld, ushort_t* ldsb, int tid)
{
    int l = tid & 63;
    int w = tid >> 6;
    int row = w * 16 + (l >> 2);
    int kg  = l & 3;
    char* lb = (char*)ldsb + w * 1024;
    const ushort_t* g0 = gbase + (size_t)row * ld + kg * 8;
    __builtin_amdgcn_global_load_lds(
        (const __attribute__((address_space(1))) unsigned*)g0,
        (__attribute__((address_space(3))) unsigned*)lb, 16, 0, 0);
    const ushort_t* g1 = g0 + (size_t)64 * ld;
    __builtin_amdgcn_global_load_lds(
        (const __attribute__((address_space(1))) unsigned*)g1,
        (__attribute__((address_space(3))) unsigned*)(lb + 4096), 16, 0, 0);
}

// ---------------------------------------------------------------------------
// bf16 MFMA GEMM, bf16 output: C[M,N] = A[M,K] x Bt[N,K]^T.
// 128x128 tile, BK=32, 256 thr (4 waves, 2x2 of 64x64), 16x16x32 MFMA.
// ---------------------------------------------------------------------------
__global__ __launch_bounds__(256)
void gemm_bf16_mfma_bfout(const ushort_t* __restrict__ A, const ushort_t* __restrict__ Bt,
                          ushort_t* __restrict__ C, int M, int N, int K)
{
    __shared__ ushort_t As[128 * 32];
    __shared__ ushort_t Bs[128 * 32];
    int tid = threadIdx.x;
    int l = tid & 63, wid = tid >> 6;
    int wr = wid >> 1, wc = wid & 1;
    int row0 = blockIdx.y * 128, col0 = blockIdx.x * 128;

    f32x4 acc[4][4];
    #pragma unroll
    for (int m = 0; m < 4; ++m)
        #pragma unroll
        for (int n = 0; n < 4; ++n)
            acc[m][n] = (f32x4){0.f, 0.f, 0.f, 0.f};

    const ushort_t* Ab = A  + (size_t)row0 * K;
    const ushort_t* Bb = Bt + (size_t)col0 * K;
    int arow = wr * 64 + (l & 15);
    int brow = wc * 64 + (l & 15);
    int kb   = (l >> 4) * 8;

    for (int k0 = 0; k0 < K; k0 += 32) {
        stage128x32(Ab + k0, K, As, tid);
        stage128x32(Bb + k0, K, Bs, tid);
        __syncthreads();
        bf16x8 af[4], bfr[4];
        #pragma unroll
        for (int m = 0; m < 4; ++m)
            af[m] = *reinterpret_cast<const bf16x8*>(&As[(arow + m * 16) * 32 + kb]);
        #pragma unroll
        for (int n = 0; n < 4; ++n)
            bfr[n] = *reinterpret_cast<const bf16x8*>(&Bs[(brow + n * 16) * 32 + kb]);
        #pragma unroll
        for (int m = 0; m < 4; ++m)
            #pragma unroll
            for (int n = 0; n < 4; ++n)
                acc[m][n] = __builtin_amdgcn_mfma_f32_16x16x32_bf16(
                    af[m], bfr[n], acc[m][n], 0, 0, 0);
        __syncthreads();
    }

    int ro = (l >> 4) * 4, co = l & 15;
    #pragma unroll
    for (int m = 0; m < 4; ++m) {
        #pragma unroll
        for (int n = 0; n < 4; ++n) {
            int c = col0 + wc * 64 + n * 16 + co;
            #pragma unroll
            for (int reg = 0; reg < 4; ++reg) {
                int r = row0 + wr * 64 + m * 16 + ro + reg;
                C[(size_t)r * N + c] = f2bf(acc[m][n][reg]);
            }
        }
    }
}

// ---------------------------------------------------------------------------
// bf16 MFMA GEMM for dt: A[2048][64] x WtDt[2048][64]^T, K=64.
// Epilogue: dt = softplus(acc + b_dt[col]), written as bf16.
// ---------------------------------------------------------------------------
__global__ __launch_bounds__(256)
void gemm_bf16_dt(const ushort_t* __restrict__ A, const ushort_t* __restrict__ Bt,
                  ushort_t* __restrict__ dtb, const float* __restrict__ bias)
{
    __shared__ ushort_t As[128 * 32];
    __shared__ ushort_t Bs[128 * 32];
    const int K = DT_RANK;   // 64
    int tid = threadIdx.x;
    int l = tid & 63, wid = tid >> 6;
    int wr = wid >> 1, wc = wid & 1;
    int row0 = blockIdx.y * 128, col0 = blockIdx.x * 128;

    f32x4 acc[4][4];
    #pragma unroll
    for (int m = 0; m < 4; ++m)
        #pragma unroll
        for (int n = 0; n < 4; ++n)
            acc[m][n] = (f32x4){0.f, 0.f, 0.f, 0.f};

    const ushort_t* Ab = A  + (size_t)row0 * K;
    const ushort_t* Bb = Bt + (size_t)col0 * K;
    int arow = wr * 64 + (l & 15);
    int brow = wc * 64 + (l & 15);
    int kb   = (l >> 4) * 8;

    #pragma unroll
    for (int k0 = 0; k0 < K; k0 += 32) {
        stage128x32(Ab + k0, K, As, tid);
        stage128x32(Bb + k0, K, Bs, tid);
        __syncthreads();
        bf16x8 af[4], bfr[4];
        #pragma unroll
        for (int m = 0; m < 4; ++m)
            af[m] = *reinterpret_cast<const bf16x8*>(&As[(arow + m * 16) * 32 + kb]);
        #pragma unroll
        for (int n = 0; n < 4; ++n)
            bfr[n] = *reinterpret_cast<const bf16x8*>(&Bs[(brow + n * 16) * 32 + kb]);
        #pragma unroll
        for (int m = 0; m < 4; ++m)
            #pragma unroll
            for (int n = 0; n < 4; ++n)
                acc[m][n] = __builtin_amdgcn_mfma_f32_16x16x32_bf16(
                    af[m], bfr[n], acc[m][n], 0, 0, 0);
        __syncthreads();
    }

    int ro = (l >> 4) * 4, co = l & 15;
    #pragma unroll
    for (int m = 0; m < 4; ++m) {
        #pragma unroll
        for (int n = 0; n < 4; ++n) {
            int c = col0 + wc * 64 + n * 16 + co;
            float bdt = bias[c];
            #pragma unroll
            for (int reg = 0; reg < 4; ++reg) {
                int r = row0 + wr * 64 + m * 16 + ro + reg;
                float v = acc[m][n][reg] + bdt;
                v = (v > 20.f) ? v : __logf(1.f + __expf(v));   // softplus
                dtb[(size_t)r * D_INNER + c] = f2bf(v);
            }
        }
    }
}

// ---------------------------------------------------------------------------
// Unified split-K bf16 MFMA GEMM: parts[z][M][Nreal] = A x Bt^T over K-range.
// Grid (ceil(Nreal/128), M/128, nsplit). Bt rows padded to >= grid.x*128.
// ---------------------------------------------------------------------------
__global__ __launch_bounds__(256)
void gemm_bf16_splitk(const ushort_t* __restrict__ A, const ushort_t* __restrict__ Bt,
                      float* __restrict__ parts, int Nreal, int K)
{
    __shared__ ushort_t As[128 * 32];
    __shared__ ushort_t Bs[128 * 32];
    int M = gridDim.y * 128;
    int KS = K / gridDim.z;
    int kbeg = blockIdx.z * KS;
    int tid = threadIdx.x;
    int l = tid & 63, wid = tid >> 6;
    int wr = wid >> 1, wc = wid & 1;
    int row0 = blockIdx.y * 128, col0 = blockIdx.x * 128;

    f32x4 acc[4][4];
    #pragma unroll
    for (int m = 0; m < 4; ++m)
        #pragma unroll
        for (int n = 0; n < 4; ++n)
            acc[m][n] = (f32x4){0.f, 0.f, 0.f, 0.f};

    const ushort_t* Ab = A  + (size_t)row0 * K + kbeg;
    const ushort_t* Bb = Bt + (size_t)col0 * K + kbeg;
    int arow = wr * 64 + (l & 15);
    int brow = wc * 64 + (l & 15);
    int kb   = (l >> 4) * 8;

    for (int k0 = 0; k0 < KS; k0 += 32) {
        stage128x32(Ab + k0, K, As, tid);
        stage128x32(Bb + k0, K, Bs, tid);
        __syncthreads();
        bf16x8 af[4], bfr[4];
        #pragma unroll
        for (int m = 0; m < 4; ++m)
            af[m] = *reinterpret_cast<const bf16x8*>(&As[(arow + m * 16) * 32 + kb]);
        #pragma unroll
        for (int n = 0; n < 4; ++n)
            bfr[n] = *reinterpret_cast<const bf16x8*>(&Bs[(brow + n * 16) * 32 + kb]);
        #pragma unroll
        for (int m = 0; m < 4; ++m)
            #pragma unroll
            for (int n = 0; n < 4; ++n)
                acc[m][n] = __builtin_amdgcn_mfma_f32_16x16x32_bf16(
                    af[m], bfr[n], acc[m][n], 0, 0, 0);
        __syncthreads();
    }

    float* Cp = parts + (size_t)blockIdx.z * M * Nreal;
    int ro = (l >> 4) * 4, co = l & 15;
    #pragma unroll
    for (int m = 0; m < 4; ++m) {
        #pragma unroll
        for (int n = 0; n < 4; ++n) {
            int c = col0 + wc * 64 + n * 16 + co;
            if (c >= Nreal) continue;
            #pragma unroll
            for (int reg = 0; reg < 4; ++reg) {
                int r = row0 + wr * 64 + m * 16 + ro + reg;
                Cp[(size_t)r * Nreal + c] = acc[m][n][reg];
            }
        }
    }
}

// Split-K reduction (xdbl): out fp32 [2048][96]; also emit bf16 copy of the
// dt_lo columns (c<64) as the A-operand for the dt GEMM.
__global__ __launch_bounds__(256)
void reduce_partials_kernel(const float* __restrict__ p, float* __restrict__ out,
                            ushort_t* __restrict__ out64bf, int n)
{
    int i = blockIdx.x * 256 + threadIdx.x;
    if (i >= n) return;
    float s = 0.f;
    #pragma unroll
    for (int k = 0; k < KSPLIT_XDBL; ++k) s += p[(size_t)k * n + i];
    out[i] = s;
    int r = i / XDBL_W, c = i - r * XDBL_W;
    if (c < DT_RANK) out64bf[r * DT_RANK + c] = f2bf(s);
}

// Split-K reduction with residual (out GEMM): out = x + rs * sum(parts), float4
__global__ __launch_bounds__(256)
void reduce_out_kernel(const float* __restrict__ p, const float* __restrict__ x,
                       const float* __restrict__ res_scale, float* __restrict__ out,
                       int n4 /* = n/4 */)
{
    int i = blockIdx.x * 256 + threadIdx.x;
    if (i >= n4) return;
    float rs = res_scale[0];
    size_t n = (size_t)n4 * 4;
    float4 s = reinterpret_cast<const float4*>(p)[i];
    #pragma unroll
    for (int k = 1; k < KSPLIT_OUT; ++k) {
        float4 v = reinterpret_cast<const float4*>(p + k * n)[i];
        s.x += v.x; s.y += v.y; s.z += v.z; s.w += v.w;
    }
    float4 xv = reinterpret_cast<const float4*>(x)[i];
    float4 o;
    o.x = xv.x + rs * s.x; o.y = xv.y + rs * s.y;
    o.z = xv.z + rs * s.z; o.w = xv.w + rs * s.w;
    reinterpret_cast<float4*>(out)[i] = o;
}

// ---------------------------------------------------------------------------
// Depthwise causal conv (K=4) + bias + SiLU. bf16 in (u half of xz), bf16 out.
// ---------------------------------------------------------------------------
__global__ __launch_bounds__(256)
void conv_silu_kernel(const ushort_t* __restrict__ xzbf, const float* __restrict__ cw,
                      const float* __restrict__ cb, ushort_t* __restrict__ u2bf)
{
    int idx = blockIdx.x * 256 + threadIdx.x;   // < 2*1024*2048
    int e = idx & (D_INNER - 1);
    int l = (idx >> 11) & (SEQLEN - 1);
    int b = idx >> 21;
    const ushort_t* base = xzbf + (size_t)b * SEQLEN * (2 * D_INNER) + e;
    float w0 = cw[e * 4 + 0], w1 = cw[e * 4 + 1];
    float w2 = cw[e * 4 + 2], w3 = cw[e * 4 + 3];
    float acc = cb[e];
    if (l >= 3) acc += bf2f(base[(size_t)(l - 3) * (2 * D_INNER)]) * w0;
    if (l >= 2) acc += bf2f(base[(size_t)(l - 2) * (2 * D_INNER)]) * w1;
    if (l >= 1) acc += bf2f(base[(size_t)(l - 1) * (2 * D_INNER)]) * w2;
    acc += bf2f(base[(size_t)l * (2 * D_INNER)]) * w3;
    float sv = acc * fast_sigmoid(acc);         // SiLU
    u2bf[idx] = f2bf(sv);
}

// ---------------------------------------------------------------------------
// Chunked scan, pass A: one thread per (channel, chunk); 16 states in regs.
// ---------------------------------------------------------------------------
__global__ __launch_bounds__(256)
void scan_partial_kernel(const ushort_t* __restrict__ dtb, const float* __restrict__ xdbl,
                         const ushort_t* __restrict__ u2bf,
                         const float* __restrict__ A_log,
                         float* __restrict__ hend, float* __restrict__ sumdt_buf)
{
    int idx = blockIdx.x * 256 + threadIdx.x;   // 0 .. NCHAN*NCHUNK-1
    int p = idx & (NCHAN - 1);                  // channel (64 consecutive/wave)
    int c = idx >> 12;                          // chunk
    int b = p >> 11, e = p & (D_INNER - 1);

    float An[D_STATE];
    {
        const float4* ar = reinterpret_cast<const float4*>(A_log + (size_t)e * D_STATE);
        #pragma unroll
        for (int q = 0; q < 4; ++q) {
            float4 a4 = ar[q];
            An[q * 4 + 0] = -__expf(a4.x);
            An[q * 4 + 1] = -__expf(a4.y);
            An[q * 4 + 2] = -__expf(a4.z);
            An[q * 4 + 3] = -__expf(a4.w);
        }
    }
    float h[D_STATE];
    #pragma unroll
    for (int n = 0; n < D_STATE; ++n) h[n] = 0.f;
    float sdt = 0.f;

    size_t rowbase = (size_t)b * SEQLEN + c * LCHUNK;
    #pragma unroll
    for (int j = 0; j < LCHUNK; ++j) {
        size_t row = rowbase + j;
        float dt = bf2f(dtb[row * D_INNER + e]);
        float u  = bf2f(u2bf[row * D_INNER + e]);
        float dtu = dt * u;
        sdt += dt;
        const float4* xr = reinterpret_cast<const float4*>(xdbl + row * XDBL_W + DT_RANK);
        float Bv[D_STATE];
        #pragma unroll
        for (int q = 0; q < 4; ++q) {
            float4 b4 = xr[q];
            Bv[q * 4 + 0] = b4.x; Bv[q * 4 + 1] = b4.y;
            Bv[q * 4 + 2] = b4.z; Bv[q * 4 + 3] = b4.w;
        }
        #pragma unroll
        for (int n = 0; n < D_STATE; ++n)
            h[n] = __expf(dt * An[n]) * h[n] + dtu * Bv[n];
    }

    float4* hp = reinterpret_cast<float4*>(hend + ((size_t)p * NCHUNK + c) * D_STATE);
    #pragma unroll
    for (int q = 0; q < 4; ++q)
        hp[q] = (float4){h[q * 4 + 0], h[q * 4 + 1], h[q * 4 + 2], h[q * 4 + 3]};
    sumdt_buf[p * NCHUNK + c] = sdt;
}

// ---------------------------------------------------------------------------
// Pass B: per-channel inter-chunk Hillis-Steele scan; exclusive carry in place.
// ---------------------------------------------------------------------------
__global__ __launch_bounds__(1024)
void scan_combine_kernel(const float* __restrict__ A_log,
                         const float* __restrict__ sumdt_buf,
                         float* __restrict__ hend /* in: hend, out: hcarry */)
{
    __shared__ float Ps[NCHUNK][D_STATE];
    __shared__ float Hs[NCHUNK][D_STATE];
    int tid = threadIdx.x;
    int c = tid >> 4, n = tid & 15;
    int p = blockIdx.x;
    int e = p & (D_INNER - 1);
    float An = -__expf(A_log[e * D_STATE + n]);
    float P = __expf(An * sumdt_buf[p * NCHUNK + c]);
    float H = hend[(size_t)p * (NCHUNK * D_STATE) + c * D_STATE + n];
    Ps[c][n] = P; Hs[c][n] = H;
    __syncthreads();
    #pragma unroll
    for (int d = 1; d < NCHUNK; d <<= 1) {
        float Pl = 1.f, Hl = 0.f;
        if (c >= d) { Pl = Ps[c - d][n]; Hl = Hs[c - d][n]; }
        __syncthreads();
        H = P * Hl + H;   // (P,H) o (Pl,Hl)
        P = P * Pl;
        Ps[c][n] = P; Hs[c][n] = H;
        __syncthreads();
    }
    float carry = (c == 0) ? 0.f : Hs[c - 1][n];
    hend[(size_t)p * (NCHUNK * D_STATE) + c * D_STATE + n] = carry;
}

// ---------------------------------------------------------------------------
// Pass C: one thread per (channel, chunk), seeded with carry; in-register
// dot with C row; fused D-skip + SiLU(z) gate; writes y as bf16.
// ---------------------------------------------------------------------------
__global__ __launch_bounds__(256)
void scan_final_kernel(const ushort_t* __restrict__ dtb, const float* __restrict__ xdbl,
                       const ushort_t* __restrict__ xzbf, const ushort_t* __restrict__ u2bf,
                       ushort_t* __restrict__ ybf,
                       const float* __restrict__ A_log,
                       const float* __restrict__ D_param,
                       const float* __restrict__ hcarry)
{
    int idx = blockIdx.x * 256 + threadIdx.x;
    int p = idx & (NCHAN - 1);
    int c = idx >> 12;
    int b = p >> 11, e = p & (D_INNER - 1);
    float De = D_param[e];

    float An[D_STATE];
    {
        const float4* ar = reinterpret_cast<const float4*>(A_log + (size_t)e * D_STATE);
        #pragma unroll
        for (int q = 0; q < 4; ++q) {
            float4 a4 = ar[q];
            An[q * 4 + 0] = -__expf(a4.x);
            An[q * 4 + 1] = -__expf(a4.y);
            An[q * 4 + 2] = -__expf(a4.z);
            An[q * 4 + 3] = -__expf(a4.w);
        }
    }
    float h[D_STATE];
    {
        const float4* hp = reinterpret_cast<const float4*>(
            hcarry + ((size_t)p * NCHUNK + c) * D_STATE);
        #pragma unroll
        for (int q = 0; q < 4; ++q) {
            float4 h4 = hp[q];
            h[q * 4 + 0] = h4.x; h[q * 4 + 1] = h4.y;
            h[q * 4 + 2] = h4.z; h[q * 4 + 3] = h4.w;
        }
    }

    size_t rowbase = (size_t)b * SEQLEN + c * LCHUNK;
    #pragma unroll
    for (int j = 0; j < LCHUNK; ++j) {
        size_t row = rowbase + j;
        float dt = bf2f(dtb[row * D_INNER + e]);
        float u  = bf2f(u2bf[row * D_INNER + e]);
        float dtu = dt * u;
        const float4* xr = reinterpret_cast<const float4*>(xdbl + row * XDBL_W + DT_RANK);
        float Bv[D_STATE], Cv[D_STATE];
        #pragma unroll
        for (int q = 0; q < 4; ++q) {
            float4 b4 = xr[q];
            Bv[q * 4 + 0] = b4.x; Bv[q * 4 + 1] = b4.y;
            Bv[q * 4 + 2] = b4.z; Bv[q * 4 + 3] = b4.w;
            float4 c4 = xr[q + 4];
            Cv[q * 4 + 0] = c4.x; Cv[q * 4 + 1] = c4.y;
            Cv[q * 4 + 2] = c4.z; Cv[q * 4 + 3] = c4.w;
        }
        float y = 0.f;
        #pragma unroll
        for (int n = 0; n < D_STATE; ++n) {
            h[n] = __expf(dt * An[n]) * h[n] + dtu * Bv[n];
            y += h[n] * Cv[n];
        }
        float z  = bf2f(xzbf[row * (2 * D_INNER) + D_INNER + e]);
        float sz = z * fast_sigmoid(z);
        ybf[row * D_INNER + e] = f2bf((y + u * De) * sz);
    }
}

// ---------------------------------------------------------------------------
extern "C" void kernel_launch(void* const* d_in, const int* in_sizes, int n_in,
                              void* d_out, int out_size, void* d_ws, size_t ws_size,
                              hipStream_t stream)
{
    const float* x       = (const float*)d_in[0];
    const float* ln_g    = (const float*)d_in[1];
    const float* ln_b    = (const float*)d_in[2];
    const float* W_in    = (const float*)d_in[3];
    const float* conv_w  = (const float*)d_in[4];
    const float* conv_b  = (const float*)d_in[5];
    const float* W_xp    = (const float*)d_in[6];
    const float* W_dt    = (const float*)d_in[7];
    const float* b_dt    = (const float*)d_in[8];
    const float* A_log   = (const float*)d_in[9];
    const float* D_param = (const float*)d_in[10];
    const float* W_out   = (const float*)d_in[11];
    const float* res_sc  = (const float*)d_in[12];
    float* out = (float*)d_out;

    char* ws = (char*)d_ws;
    const size_t MB = 1024 * 1024;
    // Workspace (liveness-overlapped; peak 82 MB):
    //   xzbf    [0,16M)      2048x4096 bf16 (u cols 0-2047, z cols 2048-4095)
    //   u2bf    [16M,24M)    2048x2048 bf16
    //   dtb16   [24M,32M)    2048x2048 bf16 (softplus'd dt)
    //   xdbl    [32M,33M)    2048x96 fp32
    //   xdbl64  [33M,34M)    2048x64 bf16 (dt_lo, A-operand for dt GEMM)
    //   hend    [34M,50M)    4096x64x16 fp32 (carry in place)
    //   sumdt   [50M,51M)    4096x64 fp32
    //   xnbf    [51M,55M)    2048x1024 bf16
    //   WtIn    [55M,63M)    4096x1024 bf16
    //   WtOut   [63M,67M)    1024x2048 bf16
    //   WtXp    [67M,67.5M)  128x2048 bf16 (rows 96..127 zeroed by pad kernel)
    //   WtDt    [67.5M,68M)  2048x64 bf16
    //   ybf     [68M,76M)    2048x2048 bf16
    //   partsX  [76M,82M)    8x2048x96 fp32
    //   partsO  [24M,56M)    4x2048x1024 fp32 (overlaps dt/xdbl/hend/sumdt/xnbf
    //                        — all dead at step 7)
    ushort_t* xzbf   = (ushort_t*)(ws);
    ushort_t* u2bf   = (ushort_t*)(ws + 16 * MB);
    ushort_t* dtb16  = (ushort_t*)(ws + 24 * MB);
    float*    xdbl   = (float*)(ws + 32 * MB);
    ushort_t* xdbl64 = (ushort_t*)(ws + 33 * MB);
    float*    hend   = (float*)(ws + 34 * MB);
    float*    sumdt  = (float*)(ws + 50 * MB);
    ushort_t* xnbf   = (ushort_t*)(ws + 51 * MB);
    ushort_t* WtIn   = (ushort_t*)(ws + 55 * MB);
    ushort_t* WtOut  = (ushort_t*)(ws + 63 * MB);
    ushort_t* WtXp   = (ushort_t*)(ws + 67 * MB);
    ushort_t* WtDt   = (ushort_t*)(ws + 67 * MB + 512 * 1024);
    ushort_t* ybf    = (ushort_t*)(ws + 68 * MB);
    float*    partsX = (float*)(ws + 76 * MB);
    float*    partsO = (float*)(ws + 24 * MB);

    // 0. weight transpose+convert (bf16); zero WtXp pad rows [96,128)
    {
        dim3 blk(32, 8);
        dim3 g1((2 * D_INNER) / 32, D_MODEL / 32);
        transpose_convert_kernel<<<g1, blk, 0, stream>>>(W_in, WtIn, D_MODEL, 2 * D_INNER);
        dim3 g2(D_MODEL / 32, D_INNER / 32);
        transpose_convert_kernel<<<g2, blk, 0, stream>>>(W_out, WtOut, D_INNER, D_MODEL);
        dim3 g3(XDBL_W / 32, D_INNER / 32);
        transpose_convert_kernel<<<g3, blk, 0, stream>>>(W_xp, WtXp, D_INNER, XDBL_W);
        dim3 g4(D_INNER / 32, DT_RANK / 32);
        transpose_convert_kernel<<<g4, blk, 0, stream>>>(W_dt, WtDt, DT_RANK, D_INNER);
        pad_zero_kernel<<<64, 256, 0, stream>>>(WtXp + (size_t)XDBL_W * D_INNER);
    }

    // 1. LayerNorm -> bf16 A operand
    layernorm_kernel<<<NROWS, 256, 0, stream>>>(x, ln_g, ln_b, xnbf);

    // 2. xz = xn @ W_in   [2048 x 4096, K=1024]  (bf16 MFMA, bf16 out)
    {
        dim3 grid((2 * D_INNER) / 128, NROWS / 128);
        gemm_bf16_mfma_bfout<<<grid, 256, 0, stream>>>(
            xnbf, WtIn, xzbf, NROWS, 2 * D_INNER, D_MODEL);
    }

    // 3. u2 = silu(causal_conv(u) + conv_b)   (bf16 in/out)
    conv_silu_kernel<<<(BATCH * SEQLEN * D_INNER) / 256, 256, 0, stream>>>(
        xzbf, conv_w, conv_b, u2bf);

    // 4. xdbl = u2 @ W_xp  [2048 x 96, K=2048]  bf16 MFMA split-K x8 + reduce
    {
        dim3 grid(1, NROWS / 128, KSPLIT_XDBL);
        gemm_bf16_splitk<<<grid, 256, 0, stream>>>(u2bf, WtXp, partsX, XDBL_W, D_INNER);
        reduce_partials_kernel<<<(NROWS * XDBL_W + 255) / 256, 256, 0, stream>>>(
            partsX, xdbl, xdbl64, NROWS * XDBL_W);
    }

    // 5. dt = softplus(dt_lo @ W_dt + b_dt)  [2048 x 2048, K=64]  (bf16 MFMA)
    {
        dim3 grid(D_INNER / 128, NROWS / 128);
        gemm_bf16_dt<<<grid, 256, 0, stream>>>(xdbl64, WtDt, dtb16, b_dt);
    }

    // 6. chunked parallel scan (A: partials, B: inter-chunk, C: final+gate)
    scan_partial_kernel<<<(NCHAN * NCHUNK) / 256, 256, 0, stream>>>(
        dtb16, xdbl, u2bf, A_log, hend, sumdt);
    scan_combine_kernel<<<NCHAN, 1024, 0, stream>>>(A_log, sumdt, hend);
    scan_final_kernel<<<(NCHAN * NCHUNK) / 256, 256, 0, stream>>>(
        dtb16, xdbl, xzbf, u2bf, ybf, A_log, D_param, hend);

    // 7. out = x + res_scale * (y @ W_out)  split-K x4 MFMA + residual reduce
    {
        dim3 grid(D_MODEL / 128, NROWS / 128, KSPLIT_OUT);
        gemm_bf16_splitk<<<grid, 256, 0, stream>>>(ybf, WtOut, partsO, D_MODEL, D_INNER);
        reduce_out_kernel<<<(NROWS * D_MODEL / 4 + 255) / 256, 256, 0, stream>>>(
            partsO, x, res_sc, out, NROWS * D_MODEL / 4);
    }
}

// Round 8
// 175.018 us; speedup vs baseline: 12.7515x; 1.0361x over previous
//
#include <hip/hip_runtime.h>
#include <hip/hip_bf16.h>

// Dims (compile-time constants from the reference)
#define D_MODEL 1024
#define D_STATE 16
#define D_CONV  4
#define D_INNER 2048
#define DT_RANK 64
#define BATCH   2
#define SEQLEN  1024
#define NROWS   (BATCH * SEQLEN)        // 2048
#define XDBL_W  (DT_RANK + 2 * D_STATE) // 96
#define NCHUNK  64                      // chunks per sequence
#define LCHUNK  16                      // steps per chunk
#define NCHAN   (BATCH * D_INNER)       // 4096 (b,e) channels
#define KSPLIT_XDBL 8

typedef unsigned short ushort_t;
typedef __attribute__((ext_vector_type(8))) short bf16x8;
typedef __attribute__((ext_vector_type(4))) float f32x4;

// fp32 -> bf16 (round-to-nearest-even), bit-level (deterministic)
__device__ __forceinline__ ushort_t f2bf(float f) {
    union { float f; unsigned u; } v; v.f = f;
    unsigned r = v.u + 0x7fffu + ((v.u >> 16) & 1u);
    return (ushort_t)(r >> 16);
}
__device__ __forceinline__ float bf2f(ushort_t h) {
    union { unsigned u; float f; } v; v.u = (unsigned)h << 16; return v.f;
}
__device__ __forceinline__ float fast_sigmoid(float z) {
    return __builtin_amdgcn_rcpf(1.f + __expf(-z));
}

// ---------------------------------------------------------------------------
// LayerNorm: one block per row of 1024, 256 threads x float4. Emits bf16.
// ---------------------------------------------------------------------------
__global__ __launch_bounds__(256)
void layernorm_kernel(const float* __restrict__ x, const float* __restrict__ g,
                      const float* __restrict__ bb, ushort_t* __restrict__ xnbf)
{
    int row = blockIdx.x;
    const float* xr = x + (size_t)row * D_MODEL;
    int tid = threadIdx.x;
    float4 v = reinterpret_cast<const float4*>(xr)[tid];
    float s  = v.x + v.y + v.z + v.w;
    float ss = v.x * v.x + v.y * v.y + v.z * v.z + v.w * v.w;
    #pragma unroll
    for (int off = 32; off; off >>= 1) {
        s  += __shfl_down(s, off);
        ss += __shfl_down(ss, off);
    }
    __shared__ float sbuf[4], ssbuf[4];
    int wid = tid >> 6, lane = tid & 63;
    if (lane == 0) { sbuf[wid] = s; ssbuf[wid] = ss; }
    __syncthreads();
    if (tid == 0) {
        float st = 0.f, sst = 0.f;
        #pragma unroll
        for (int i = 0; i < 4; ++i) { st += sbuf[i]; sst += ssbuf[i]; }
        sbuf[0] = st; ssbuf[0] = sst;
    }
    __syncthreads();
    float mu  = sbuf[0] * (1.f / D_MODEL);
    float var = ssbuf[0] * (1.f / D_MODEL) - mu * mu;
    float inv = rsqrtf(var + 1e-5f);
    float4 gv = reinterpret_cast<const float4*>(g)[tid];
    float4 bv = reinterpret_cast<const float4*>(bb)[tid];
    ushort4 o;
    o.x = f2bf((v.x - mu) * inv * gv.x + bv.x);
    o.y = f2bf((v.y - mu) * inv * gv.y + bv.y);
    o.z = f2bf((v.z - mu) * inv * gv.z + bv.z);
    o.w = f2bf((v.w - mu) * inv * gv.w + bv.w);
    reinterpret_cast<ushort4*>(xnbf + (size_t)row * D_MODEL)[tid] = o;
}

// ---------------------------------------------------------------------------
// Transpose + fp32->bf16 convert: Wt[c][r] = bf16(W[r][c]).  W is [R][C].
// ---------------------------------------------------------------------------
__global__ __launch_bounds__(256)
void transpose_convert_kernel(const float* __restrict__ W, ushort_t* __restrict__ Wt,
                              int R, int C)
{
    __shared__ float t[32][33];
    int c0 = blockIdx.x * 32, r0 = blockIdx.y * 32;
    int tx = threadIdx.x, ty = threadIdx.y;
    #pragma unroll
    for (int i = 0; i < 32; i += 8)
        t[ty + i][tx] = W[(size_t)(r0 + ty + i) * C + c0 + tx];
    __syncthreads();
    #pragma unroll
    for (int i = 0; i < 32; i += 8)
        Wt[(size_t)(c0 + ty + i) * R + r0 + tx] = f2bf(t[tx][ty + i]);
}

// Zero the WtXp pad rows [96,128): 32*2048 bf16 = 64K elems, ushort4 stores.
__global__ __launch_bounds__(256)
void pad_zero_kernel(ushort_t* __restrict__ dst)
{
    int i = blockIdx.x * 256 + threadIdx.x;   // 16384 threads x 4 elems
    reinterpret_cast<ushort4*>(dst)[i] = (ushort4){0, 0, 0, 0};
}

// ---------------------------------------------------------------------------
// Global->LDS staging, width-16 async. 128x32 tile (2 issues) / 64x32 (1).
// ---------------------------------------------------------------------------
__device__ __forceinline__ void stage128x32(const ushort_t* __restrict__ gbase,
                                            size_t ld, ushort_t* ldsb, int tid)
{
    int l = tid & 63;
    int w = tid >> 6;
    int row = w * 16 + (l >> 2);
    int kg  = l & 3;
    char* lb = (char*)ldsb + w * 1024;
    const ushort_t* g0 = gbase + (size_t)row * ld + kg * 8;
    __builtin_amdgcn_global_load_lds(
        (const __attribute__((address_space(1))) unsigned*)g0,
        (__attribute__((address_space(3))) unsigned*)lb, 16, 0, 0);
    const ushort_t* g1 = g0 + (size_t)64 * ld;
    __builtin_amdgcn_global_load_lds(
        (const __attribute__((address_space(1))) unsigned*)g1,
        (__attribute__((address_space(3))) unsigned*)(lb + 4096), 16, 0, 0);
}

__device__ __forceinline__ void stage64x32(const ushort_t* __restrict__ gbase,
                                           size_t ld, ushort_t* ldsb, int tid)
{
    int l = tid & 63;
    int w = tid >> 6;
    int row = w * 16 + (l >> 2);     // 0..63
    int kg  = l & 3;
    char* lb = (char*)ldsb + w * 1024;
    const ushort_t* g0 = gbase + (size_t)row * ld + kg * 8;
    __builtin_amdgcn_global_load_lds(
        (const __attribute__((address_space(1))) unsigned*)g0,
        (__attribute__((address_space(3))) unsigned*)lb, 16, 0, 0);
}

// ---------------------------------------------------------------------------
// bf16 MFMA GEMM, bf16 output: C[M,N] = A[M,K] x Bt[N,K]^T.
// 128x128 tile, BK=32, 256 thr (4 waves, 2x2 of 64x64), 16x16x32 MFMA.
// ---------------------------------------------------------------------------
__global__ __launch_bounds__(256)
void gemm_bf16_mfma_bfout(const ushort_t* __restrict__ A, const ushort_t* __restrict__ Bt,
                          ushort_t* __restrict__ C, int M, int N, int K)
{
    __shared__ ushort_t As[128 * 32];
    __shared__ ushort_t Bs[128 * 32];
    int tid = threadIdx.x;
    int l = tid & 63, wid = tid >> 6;
    int wr = wid >> 1, wc = wid & 1;
    int row0 = blockIdx.y * 128, col0 = blockIdx.x * 128;

    f32x4 acc[4][4];
    #pragma unroll
    for (int m = 0; m < 4; ++m)
        #pragma unroll
        for (int n = 0; n < 4; ++n)
            acc[m][n] = (f32x4){0.f, 0.f, 0.f, 0.f};

    const ushort_t* Ab = A  + (size_t)row0 * K;
    const ushort_t* Bb = Bt + (size_t)col0 * K;
    int arow = wr * 64 + (l & 15);
    int brow = wc * 64 + (l & 15);
    int kb   = (l >> 4) * 8;

    for (int k0 = 0; k0 < K; k0 += 32) {
        stage128x32(Ab + k0, K, As, tid);
        stage128x32(Bb + k0, K, Bs, tid);
        __syncthreads();
        bf16x8 af[4], bfr[4];
        #pragma unroll
        for (int m = 0; m < 4; ++m)
            af[m] = *reinterpret_cast<const bf16x8*>(&As[(arow + m * 16) * 32 + kb]);
        #pragma unroll
        for (int n = 0; n < 4; ++n)
            bfr[n] = *reinterpret_cast<const bf16x8*>(&Bs[(brow + n * 16) * 32 + kb]);
        #pragma unroll
        for (int m = 0; m < 4; ++m)
            #pragma unroll
            for (int n = 0; n < 4; ++n)
                acc[m][n] = __builtin_amdgcn_mfma_f32_16x16x32_bf16(
                    af[m], bfr[n], acc[m][n], 0, 0, 0);
        __syncthreads();
    }

    int ro = (l >> 4) * 4, co = l & 15;
    #pragma unroll
    for (int m = 0; m < 4; ++m) {
        #pragma unroll
        for (int n = 0; n < 4; ++n) {
            int c = col0 + wc * 64 + n * 16 + co;
            #pragma unroll
            for (int reg = 0; reg < 4; ++reg) {
                int r = row0 + wr * 64 + m * 16 + ro + reg;
                C[(size_t)r * N + c] = f2bf(acc[m][n][reg]);
            }
        }
    }
}

// ---------------------------------------------------------------------------
// bf16 MFMA GEMM for dt: A[2048][64] x WtDt[2048][64]^T, K=64.
// Epilogue: dt = softplus(acc + b_dt[col]), written as bf16.
// ---------------------------------------------------------------------------
__global__ __launch_bounds__(256)
void gemm_bf16_dt(const ushort_t* __restrict__ A, const ushort_t* __restrict__ Bt,
                  ushort_t* __restrict__ dtb, const float* __restrict__ bias)
{
    __shared__ ushort_t As[128 * 32];
    __shared__ ushort_t Bs[128 * 32];
    const int K = DT_RANK;   // 64
    int tid = threadIdx.x;
    int l = tid & 63, wid = tid >> 6;
    int wr = wid >> 1, wc = wid & 1;
    int row0 = blockIdx.y * 128, col0 = blockIdx.x * 128;

    f32x4 acc[4][4];
    #pragma unroll
    for (int m = 0; m < 4; ++m)
        #pragma unroll
        for (int n = 0; n < 4; ++n)
            acc[m][n] = (f32x4){0.f, 0.f, 0.f, 0.f};

    const ushort_t* Ab = A  + (size_t)row0 * K;
    const ushort_t* Bb = Bt + (size_t)col0 * K;
    int arow = wr * 64 + (l & 15);
    int brow = wc * 64 + (l & 15);
    int kb   = (l >> 4) * 8;

    #pragma unroll
    for (int k0 = 0; k0 < K; k0 += 32) {
        stage128x32(Ab + k0, K, As, tid);
        stage128x32(Bb + k0, K, Bs, tid);
        __syncthreads();
        bf16x8 af[4], bfr[4];
        #pragma unroll
        for (int m = 0; m < 4; ++m)
            af[m] = *reinterpret_cast<const bf16x8*>(&As[(arow + m * 16) * 32 + kb]);
        #pragma unroll
        for (int n = 0; n < 4; ++n)
            bfr[n] = *reinterpret_cast<const bf16x8*>(&Bs[(brow + n * 16) * 32 + kb]);
        #pragma unroll
        for (int m = 0; m < 4; ++m)
            #pragma unroll
            for (int n = 0; n < 4; ++n)
                acc[m][n] = __builtin_amdgcn_mfma_f32_16x16x32_bf16(
                    af[m], bfr[n], acc[m][n], 0, 0, 0);
        __syncthreads();
    }

    int ro = (l >> 4) * 4, co = l & 15;
    #pragma unroll
    for (int m = 0; m < 4; ++m) {
        #pragma unroll
        for (int n = 0; n < 4; ++n) {
            int c = col0 + wc * 64 + n * 16 + co;
            float bdt = bias[c];
            #pragma unroll
            for (int reg = 0; reg < 4; ++reg) {
                int r = row0 + wr * 64 + m * 16 + ro + reg;
                float v = acc[m][n][reg] + bdt;
                v = (v > 20.f) ? v : __logf(1.f + __expf(v));   // softplus
                dtb[(size_t)r * D_INNER + c] = f2bf(v);
            }
        }
    }
}

// ---------------------------------------------------------------------------
// xdbl split-K GEMM, 64x128 tile: parts[z][64-row-block][96] = u2 x WtXp^T.
// Grid (1, M/64, KSPLIT_XDBL). 4 waves 2x2, each 32x64. KS = K/splits = 256.
// ---------------------------------------------------------------------------
__global__ __launch_bounds__(256)
void gemm_xdbl64(const ushort_t* __restrict__ A, const ushort_t* __restrict__ Bt,
                 float* __restrict__ parts)
{
    __shared__ ushort_t As[64 * 32];
    __shared__ ushort_t Bs[128 * 32];
    const int K = D_INNER;
    const int KS = D_INNER / KSPLIT_XDBL;      // 256
    int tid = threadIdx.x;
    int l = tid & 63, wid = tid >> 6;
    int wr = wid >> 1, wc = wid & 1;
    int row0 = blockIdx.y * 64;
    int kbeg = blockIdx.z * KS;

    f32x4 acc[2][4];
    #pragma unroll
    for (int m = 0; m < 2; ++m)
        #pragma unroll
        for (int n = 0; n < 4; ++n)
            acc[m][n] = (f32x4){0.f, 0.f, 0.f, 0.f};

    const ushort_t* Ab = A  + (size_t)row0 * K + kbeg;
    const ushort_t* Bb = Bt + kbeg;
    int arow = wr * 32 + (l & 15);
    int brow = wc * 64 + (l & 15);
    int kb   = (l >> 4) * 8;

    #pragma unroll
    for (int k0 = 0; k0 < KS; k0 += 32) {
        stage64x32(Ab + k0, K, As, tid);
        stage128x32(Bb + k0, K, Bs, tid);
        __syncthreads();
        bf16x8 af[2], bfr[4];
        #pragma unroll
        for (int m = 0; m < 2; ++m)
            af[m] = *reinterpret_cast<const bf16x8*>(&As[(arow + m * 16) * 32 + kb]);
        #pragma unroll
        for (int n = 0; n < 4; ++n)
            bfr[n] = *reinterpret_cast<const bf16x8*>(&Bs[(brow + n * 16) * 32 + kb]);
        #pragma unroll
        for (int m = 0; m < 2; ++m)
            #pragma unroll
            for (int n = 0; n < 4; ++n)
                acc[m][n] = __builtin_amdgcn_mfma_f32_16x16x32_bf16(
                    af[m], bfr[n], acc[m][n], 0, 0, 0);
        __syncthreads();
    }

    float* Cp = parts + (size_t)blockIdx.z * NROWS * XDBL_W;
    int ro = (l >> 4) * 4, co = l & 15;
    #pragma unroll
    for (int m = 0; m < 2; ++m) {
        #pragma unroll
        for (int n = 0; n < 4; ++n) {
            int c = wc * 64 + n * 16 + co;
            if (c >= XDBL_W) continue;
            #pragma unroll
            for (int reg = 0; reg < 4; ++reg) {
                int r = row0 + wr * 32 + m * 16 + ro + reg;
                Cp[(size_t)r * XDBL_W + c] = acc[m][n][reg];
            }
        }
    }
}

// ---------------------------------------------------------------------------
// out GEMM, 64x64 tile direct (no split-K): out = x + rs * (ybf x WtOut^T).
// Grid (N/64, M/64) = (16, 32) = 512 blocks. 4 waves 2x2, each 32x32.
// ---------------------------------------------------------------------------
__global__ __launch_bounds__(256)
void gemm_out64(const ushort_t* __restrict__ A, const ushort_t* __restrict__ Bt,
                const float* __restrict__ x, const float* __restrict__ res_scale,
                float* __restrict__ out)
{
    __shared__ ushort_t As[64 * 32];
    __shared__ ushort_t Bs[64 * 32];
    const int K = D_INNER, N = D_MODEL;
    int tid = threadIdx.x;
    int l = tid & 63, wid = tid >> 6;
    int wr = wid >> 1, wc = wid & 1;
    int row0 = blockIdx.y * 64, col0 = blockIdx.x * 64;

    f32x4 acc[2][2];
    #pragma unroll
    for (int m = 0; m < 2; ++m)
        #pragma unroll
        for (int n = 0; n < 2; ++n)
            acc[m][n] = (f32x4){0.f, 0.f, 0.f, 0.f};

    const ushort_t* Ab = A  + (size_t)row0 * K;
    const ushort_t* Bb = Bt + (size_t)col0 * K;
    int arow = wr * 32 + (l & 15);
    int brow = wc * 32 + (l & 15);
    int kb   = (l >> 4) * 8;

    for (int k0 = 0; k0 < K; k0 += 32) {
        stage64x32(Ab + k0, K, As, tid);
        stage64x32(Bb + k0, K, Bs, tid);
        __syncthreads();
        bf16x8 af[2], bfr[2];
        #pragma unroll
        for (int m = 0; m < 2; ++m)
            af[m] = *reinterpret_cast<const bf16x8*>(&As[(arow + m * 16) * 32 + kb]);
        #pragma unroll
        for (int n = 0; n < 2; ++n)
            bfr[n] = *reinterpret_cast<const bf16x8*>(&Bs[(brow + n * 16) * 32 + kb]);
        #pragma unroll
        for (int m = 0; m < 2; ++m)
            #pragma unroll
            for (int n = 0; n < 2; ++n)
                acc[m][n] = __builtin_amdgcn_mfma_f32_16x16x32_bf16(
                    af[m], bfr[n], acc[m][n], 0, 0, 0);
        __syncthreads();
    }

    float rs = res_scale[0];
    int ro = (l >> 4) * 4, co = l & 15;
    #pragma unroll
    for (int m = 0; m < 2; ++m) {
        #pragma unroll
        for (int n = 0; n < 2; ++n) {
            int c = col0 + wc * 32 + n * 16 + co;
            #pragma unroll
            for (int reg = 0; reg < 4; ++reg) {
                int r = row0 + wr * 32 + m * 16 + ro + reg;
                out[(size_t)r * N + c] = x[(size_t)r * N + c] + rs * acc[m][n][reg];
            }
        }
    }
}

// Split-K reduction (xdbl): out fp32 [2048][96]; also emit bf16 copy of the
// dt_lo columns (c<64) as the A-operand for the dt GEMM.
__global__ __launch_bounds__(256)
void reduce_partials_kernel(const float* __restrict__ p, float* __restrict__ out,
                            ushort_t* __restrict__ out64bf, int n)
{
    int i = blockIdx.x * 256 + threadIdx.x;
    if (i >= n) return;
    float s = 0.f;
    #pragma unroll
    for (int k = 0; k < KSPLIT_XDBL; ++k) s += p[(size_t)k * n + i];
    out[i] = s;
    int r = i / XDBL_W, c = i - r * XDBL_W;
    if (c < DT_RANK) out64bf[r * DT_RANK + c] = f2bf(s);
}

// ---------------------------------------------------------------------------
// Depthwise causal conv (K=4) + bias + SiLU. bf16 in (u half of xz), bf16 out.
// ---------------------------------------------------------------------------
__global__ __launch_bounds__(256)
void conv_silu_kernel(const ushort_t* __restrict__ xzbf, const float* __restrict__ cw,
                      const float* __restrict__ cb, ushort_t* __restrict__ u2bf)
{
    int idx = blockIdx.x * 256 + threadIdx.x;   // < 2*1024*2048
    int e = idx & (D_INNER - 1);
    int l = (idx >> 11) & (SEQLEN - 1);
    int b = idx >> 21;
    const ushort_t* base = xzbf + (size_t)b * SEQLEN * (2 * D_INNER) + e;
    float w0 = cw[e * 4 + 0], w1 = cw[e * 4 + 1];
    float w2 = cw[e * 4 + 2], w3 = cw[e * 4 + 3];
    float acc = cb[e];
    if (l >= 3) acc += bf2f(base[(size_t)(l - 3) * (2 * D_INNER)]) * w0;
    if (l >= 2) acc += bf2f(base[(size_t)(l - 2) * (2 * D_INNER)]) * w1;
    if (l >= 1) acc += bf2f(base[(size_t)(l - 1) * (2 * D_INNER)]) * w2;
    acc += bf2f(base[(size_t)l * (2 * D_INNER)]) * w3;
    float sv = acc * fast_sigmoid(acc);         // SiLU
    u2bf[idx] = f2bf(sv);
}

// ---------------------------------------------------------------------------
// Chunked scan, pass A: one thread per (channel, chunk); 16 states in regs.
// ---------------------------------------------------------------------------
__global__ __launch_bounds__(256)
void scan_partial_kernel(const ushort_t* __restrict__ dtb, const float* __restrict__ xdbl,
                         const ushort_t* __restrict__ u2bf,
                         const float* __restrict__ A_log,
                         float* __restrict__ hend, float* __restrict__ sumdt_buf)
{
    int idx = blockIdx.x * 256 + threadIdx.x;   // 0 .. NCHAN*NCHUNK-1
    int p = idx & (NCHAN - 1);                  // channel (64 consecutive/wave)
    int c = idx >> 12;                          // chunk
    int b = p >> 11, e = p & (D_INNER - 1);

    float An[D_STATE];
    {
        const float4* ar = reinterpret_cast<const float4*>(A_log + (size_t)e * D_STATE);
        #pragma unroll
        for (int q = 0; q < 4; ++q) {
            float4 a4 = ar[q];
            An[q * 4 + 0] = -__expf(a4.x);
            An[q * 4 + 1] = -__expf(a4.y);
            An[q * 4 + 2] = -__expf(a4.z);
            An[q * 4 + 3] = -__expf(a4.w);
        }
    }
    float h[D_STATE];
    #pragma unroll
    for (int n = 0; n < D_STATE; ++n) h[n] = 0.f;
    float sdt = 0.f;

    size_t rowbase = (size_t)b * SEQLEN + c * LCHUNK;
    #pragma unroll
    for (int j = 0; j < LCHUNK; ++j) {
        size_t row = rowbase + j;
        float dt = bf2f(dtb[row * D_INNER + e]);
        float u  = bf2f(u2bf[row * D_INNER + e]);
        float dtu = dt * u;
        sdt += dt;
        const float4* xr = reinterpret_cast<const float4*>(xdbl + row * XDBL_W + DT_RANK);
        float Bv[D_STATE];
        #pragma unroll
        for (int q = 0; q < 4; ++q) {
            float4 b4 = xr[q];
            Bv[q * 4 + 0] = b4.x; Bv[q * 4 + 1] = b4.y;
            Bv[q * 4 + 2] = b4.z; Bv[q * 4 + 3] = b4.w;
        }
        #pragma unroll
        for (int n = 0; n < D_STATE; ++n)
            h[n] = __expf(dt * An[n]) * h[n] + dtu * Bv[n];
    }

    float4* hp = reinterpret_cast<float4*>(hend + ((size_t)p * NCHUNK + c) * D_STATE);
    #pragma unroll
    for (int q = 0; q < 4; ++q)
        hp[q] = (float4){h[q * 4 + 0], h[q * 4 + 1], h[q * 4 + 2], h[q * 4 + 3]};
    sumdt_buf[p * NCHUNK + c] = sdt;
}

// ---------------------------------------------------------------------------
// Pass B: per-channel inter-chunk Hillis-Steele scan; exclusive carry in place.
// ---------------------------------------------------------------------------
__global__ __launch_bounds__(1024)
void scan_combine_kernel(const float* __restrict__ A_log,
                         const float* __restrict__ sumdt_buf,
                         float* __restrict__ hend /* in: hend, out: hcarry */)
{
    __shared__ float Ps[NCHUNK][D_STATE];
    __shared__ float Hs[NCHUNK][D_STATE];
    int tid = threadIdx.x;
    int c = tid >> 4, n = tid & 15;
    int p = blockIdx.x;
    int e = p & (D_INNER - 1);
    float An = -__expf(A_log[e * D_STATE + n]);
    float P = __expf(An * sumdt_buf[p * NCHUNK + c]);
    float H = hend[(size_t)p * (NCHUNK * D_STATE) + c * D_STATE + n];
    Ps[c][n] = P; Hs[c][n] = H;
    __syncthreads();
    #pragma unroll
    for (int d = 1; d < NCHUNK; d <<= 1) {
        float Pl = 1.f, Hl = 0.f;
        if (c >= d) { Pl = Ps[c - d][n]; Hl = Hs[c - d][n]; }
        __syncthreads();
        H = P * Hl + H;   // (P,H) o (Pl,Hl)
        P = P * Pl;
        Ps[c][n] = P; Hs[c][n] = H;
        __syncthreads();
    }
    float carry = (c == 0) ? 0.f : Hs[c - 1][n];
    hend[(size_t)p * (NCHUNK * D_STATE) + c * D_STATE + n] = carry;
}

// ---------------------------------------------------------------------------
// Pass C: one thread per (channel, chunk), seeded with carry; in-register
// dot with C row; fused D-skip + SiLU(z) gate; writes y as bf16.
// ---------------------------------------------------------------------------
__global__ __launch_bounds__(256)
void scan_final_kernel(const ushort_t* __restrict__ dtb, const float* __restrict__ xdbl,
                       const ushort_t* __restrict__ xzbf, const ushort_t* __restrict__ u2bf,
                       ushort_t* __restrict__ ybf,
                       const float* __restrict__ A_log,
                       const float* __restrict__ D_param,
                       const float* __restrict__ hcarry)
{
    int idx = blockIdx.x * 256 + threadIdx.x;
    int p = idx & (NCHAN - 1);
    int c = idx >> 12;
    int b = p >> 11, e = p & (D_INNER - 1);
    float De = D_param[e];

    float An[D_STATE];
    {
        const float4* ar = reinterpret_cast<const float4*>(A_log + (size_t)e * D_STATE);
        #pragma unroll
        for (int q = 0; q < 4; ++q) {
            float4 a4 = ar[q];
            An[q * 4 + 0] = -__expf(a4.x);
            An[q * 4 + 1] = -__expf(a4.y);
            An[q * 4 + 2] = -__expf(a4.z);
            An[q * 4 + 3] = -__expf(a4.w);
        }
    }
    float h[D_STATE];
    {
        const float4* hp = reinterpret_cast<const float4*>(
            hcarry + ((size_t)p * NCHUNK + c) * D_STATE);
        #pragma unroll
        for (int q = 0; q < 4; ++q) {
            float4 h4 = hp[q];
            h[q * 4 + 0] = h4.x; h[q * 4 + 1] = h4.y;
            h[q * 4 + 2] = h4.z; h[q * 4 + 3] = h4.w;
        }
    }

    size_t rowbase = (size_t)b * SEQLEN + c * LCHUNK;
    #pragma unroll
    for (int j = 0; j < LCHUNK; ++j) {
        size_t row = rowbase + j;
        float dt = bf2f(dtb[row * D_INNER + e]);
        float u  = bf2f(u2bf[row * D_INNER + e]);
        float dtu = dt * u;
        const float4* xr = reinterpret_cast<const float4*>(xdbl + row * XDBL_W + DT_RANK);
        float Bv[D_STATE], Cv[D_STATE];
        #pragma unroll
        for (int q = 0; q < 4; ++q) {
            float4 b4 = xr[q];
            Bv[q * 4 + 0] = b4.x; Bv[q * 4 + 1] = b4.y;
            Bv[q * 4 + 2] = b4.z; Bv[q * 4 + 3] = b4.w;
            float4 c4 = xr[q + 4];
            Cv[q * 4 + 0] = c4.x; Cv[q * 4 + 1] = c4.y;
            Cv[q * 4 + 2] = c4.z; Cv[q * 4 + 3] = c4.w;
        }
        float y = 0.f;
        #pragma unroll
        for (int n = 0; n < D_STATE; ++n) {
            h[n] = __expf(dt * An[n]) * h[n] + dtu * Bv[n];
            y += h[n] * Cv[n];
        }
        float z  = bf2f(xzbf[row * (2 * D_INNER) + D_INNER + e]);
        float sz = z * fast_sigmoid(z);
        ybf[row * D_INNER + e] = f2bf((y + u * De) * sz);
    }
}

// ---------------------------------------------------------------------------
extern "C" void kernel_launch(void* const* d_in, const int* in_sizes, int n_in,
                              void* d_out, int out_size, void* d_ws, size_t ws_size,
                              hipStream_t stream)
{
    const float* x       = (const float*)d_in[0];
    const float* ln_g    = (const float*)d_in[1];
    const float* ln_b    = (const float*)d_in[2];
    const float* W_in    = (const float*)d_in[3];
    const float* conv_w  = (const float*)d_in[4];
    const float* conv_b  = (const float*)d_in[5];
    const float* W_xp    = (const float*)d_in[6];
    const float* W_dt    = (const float*)d_in[7];
    const float* b_dt    = (const float*)d_in[8];
    const float* A_log   = (const float*)d_in[9];
    const float* D_param = (const float*)d_in[10];
    const float* W_out   = (const float*)d_in[11];
    const float* res_sc  = (const float*)d_in[12];
    float* out = (float*)d_out;

    char* ws = (char*)d_ws;
    const size_t MB = 1024 * 1024;
    // Workspace (peak 82 MB):
    //   xzbf    [0,16M)      2048x4096 bf16 (u cols 0-2047, z cols 2048-4095)
    //   u2bf    [16M,24M)    2048x2048 bf16
    //   dtb16   [24M,32M)    2048x2048 bf16 (softplus'd dt)
    //   xdbl    [32M,33M)    2048x96 fp32
    //   xdbl64  [33M,34M)    2048x64 bf16 (dt_lo, A-operand for dt GEMM)
    //   hend    [34M,50M)    4096x64x16 fp32 (carry in place)
    //   sumdt   [50M,51M)    4096x64 fp32
    //   xnbf    [51M,55M)    2048x1024 bf16
    //   WtIn    [55M,63M)    4096x1024 bf16
    //   WtOut   [63M,67M)    1024x2048 bf16
    //   WtXp    [67M,67.5M)  128x2048 bf16 (rows 96..127 zeroed by pad kernel)
    //   WtDt    [67.5M,68M)  2048x64 bf16
    //   ybf     [68M,76M)    2048x2048 bf16
    //   partsX  [76M,82M)    8x2048x96 fp32
    ushort_t* xzbf   = (ushort_t*)(ws);
    ushort_t* u2bf   = (ushort_t*)(ws + 16 * MB);
    ushort_t* dtb16  = (ushort_t*)(ws + 24 * MB);
    float*    xdbl   = (float*)(ws + 32 * MB);
    ushort_t* xdbl64 = (ushort_t*)(ws + 33 * MB);
    float*    hend   = (float*)(ws + 34 * MB);
    float*    sumdt  = (float*)(ws + 50 * MB);
    ushort_t* xnbf   = (ushort_t*)(ws + 51 * MB);
    ushort_t* WtIn   = (ushort_t*)(ws + 55 * MB);
    ushort_t* WtOut  = (ushort_t*)(ws + 63 * MB);
    ushort_t* WtXp   = (ushort_t*)(ws + 67 * MB);
    ushort_t* WtDt   = (ushort_t*)(ws + 67 * MB + 512 * 1024);
    ushort_t* ybf    = (ushort_t*)(ws + 68 * MB);
    float*    partsX = (float*)(ws + 76 * MB);

    // 0. weight transpose+convert (bf16); zero WtXp pad rows [96,128)
    {
        dim3 blk(32, 8);
        dim3 g1((2 * D_INNER) / 32, D_MODEL / 32);
        transpose_convert_kernel<<<g1, blk, 0, stream>>>(W_in, WtIn, D_MODEL, 2 * D_INNER);
        dim3 g2(D_MODEL / 32, D_INNER / 32);
        transpose_convert_kernel<<<g2, blk, 0, stream>>>(W_out, WtOut, D_INNER, D_MODEL);
        dim3 g3(XDBL_W / 32, D_INNER / 32);
        transpose_convert_kernel<<<g3, blk, 0, stream>>>(W_xp, WtXp, D_INNER, XDBL_W);
        dim3 g4(D_INNER / 32, DT_RANK / 32);
        transpose_convert_kernel<<<g4, blk, 0, stream>>>(W_dt, WtDt, DT_RANK, D_INNER);
        pad_zero_kernel<<<64, 256, 0, stream>>>(WtXp + (size_t)XDBL_W * D_INNER);
    }

    // 1. LayerNorm -> bf16 A operand
    layernorm_kernel<<<NROWS, 256, 0, stream>>>(x, ln_g, ln_b, xnbf);

    // 2. xz = xn @ W_in   [2048 x 4096, K=1024]  (bf16 MFMA, bf16 out)
    {
        dim3 grid((2 * D_INNER) / 128, NROWS / 128);
        gemm_bf16_mfma_bfout<<<grid, 256, 0, stream>>>(
            xnbf, WtIn, xzbf, NROWS, 2 * D_INNER, D_MODEL);
    }

    // 3. u2 = silu(causal_conv(u) + conv_b)   (bf16 in/out)
    conv_silu_kernel<<<(BATCH * SEQLEN * D_INNER) / 256, 256, 0, stream>>>(
        xzbf, conv_w, conv_b, u2bf);

    // 4. xdbl = u2 @ W_xp  [2048 x 96, K=2048]  64-row-tile split-K x8 + reduce
    {
        dim3 grid(1, NROWS / 64, KSPLIT_XDBL);
        gemm_xdbl64<<<grid, 256, 0, stream>>>(u2bf, WtXp, partsX);
        reduce_partials_kernel<<<(NROWS * XDBL_W + 255) / 256, 256, 0, stream>>>(
            partsX, xdbl, xdbl64, NROWS * XDBL_W);
    }

    // 5. dt = softplus(dt_lo @ W_dt + b_dt)  [2048 x 2048, K=64]  (bf16 MFMA)
    {
        dim3 grid(D_INNER / 128, NROWS / 128);
        gemm_bf16_dt<<<grid, 256, 0, stream>>>(xdbl64, WtDt, dtb16, b_dt);
    }

    // 6. chunked parallel scan (A: partials, B: inter-chunk, C: final+gate)
    scan_partial_kernel<<<(NCHAN * NCHUNK) / 256, 256, 0, stream>>>(
        dtb16, xdbl, u2bf, A_log, hend, sumdt);
    scan_combine_kernel<<<NCHAN, 1024, 0, stream>>>(A_log, sumdt, hend);
    scan_final_kernel<<<(NCHAN * NCHUNK) / 256, 256, 0, stream>>>(
        dtb16, xdbl, xzbf, u2bf, ybf, A_log, D_param, hend);

    // 7. out = x + res_scale * (y @ W_out)  [2048 x 1024, K=2048]  direct 64x64
    {
        dim3 grid(D_MODEL / 64, NROWS / 64);
        gemm_out64<<<grid, 256, 0, stream>>>(ybf, WtOut, x, res_sc, out);
    }
}

// Round 9
// 163.633 us; speedup vs baseline: 13.6388x; 1.0696x over previous
//
#include <hip/hip_runtime.h>
#include <hip/hip_bf16.h>

// Dims (compile-time constants from the reference)
#define D_MODEL 1024
#define D_STATE 16
#define D_CONV  4
#define D_INNER 2048
#define DT_RANK 64
#define BATCH   2
#define SEQLEN  1024
#define NROWS   (BATCH * SEQLEN)        // 2048
#define XDBL_W  (DT_RANK + 2 * D_STATE) // 96
#define NCHUNK  64                      // chunks per sequence
#define LCHUNK  16                      // steps per chunk
#define NCHAN   (BATCH * D_INNER)       // 4096 (b,e) channels
#define KSPLIT_XDBL 8

typedef unsigned short ushort_t;
typedef __attribute__((ext_vector_type(8))) short bf16x8;
typedef __attribute__((ext_vector_type(4))) float f32x4;

// fp32 -> bf16 (round-to-nearest-even), bit-level (deterministic)
__device__ __forceinline__ ushort_t f2bf(float f) {
    union { float f; unsigned u; } v; v.f = f;
    unsigned r = v.u + 0x7fffu + ((v.u >> 16) & 1u);
    return (ushort_t)(r >> 16);
}
__device__ __forceinline__ float bf2f(ushort_t h) {
    union { unsigned u; float f; } v; v.u = (unsigned)h << 16; return v.f;
}
__device__ __forceinline__ float fast_sigmoid(float z) {
    return __builtin_amdgcn_rcpf(1.f + __expf(-z));
}

// ---------------------------------------------------------------------------
// Mega-prologue: one kernel does LayerNorm (2048 blocks) + 4 weight
// transpose-converts + WtXp pad (job selected by blockIdx range).
//   [0,2048)      LN row
//   [2048,6144)   W_in  [1024][4096] -> WtIn  [4096][1024]   (128 x 32)
//   [6144,8192)   W_out [2048][1024] -> WtOut [1024][2048]   (32 x 64)
//   [8192,8448)   W_xp  [2048][96]   -> WtXp  [128][2048]    (4 x 64, col<96)
//   [8448,8576)   W_dt  [64][2048]   -> WtDt  [2048][64]     (64 x 2)
// ---------------------------------------------------------------------------
#define PRO_LN1   2048
#define PRO_TIN1  6144
#define PRO_TOUT1 8192
#define PRO_TXP1  8448
#define PRO_TOTAL 8576

__device__ __forceinline__ void transpose_job(const float* __restrict__ W,
                                              ushort_t* __restrict__ Wt,
                                              int R, int Creal,
                                              int cx, int ry, int tid,
                                              float t[32][33])
{
    int c0 = cx * 32, r0 = ry * 32;
    int tx = tid & 31, ty = tid >> 5;
    int col = c0 + tx;
    #pragma unroll
    for (int i = 0; i < 32; i += 8) {
        float v = (col < Creal) ? W[(size_t)(r0 + ty + i) * Creal + col] : 0.f;
        t[ty + i][tx] = v;
    }
    __syncthreads();
    #pragma unroll
    for (int i = 0; i < 32; i += 8)
        Wt[(size_t)(c0 + ty + i) * R + r0 + tx] = f2bf(t[tx][ty + i]);
}

__global__ __launch_bounds__(256)
void prologue_kernel(const float* __restrict__ x, const float* __restrict__ g,
                     const float* __restrict__ bb, ushort_t* __restrict__ xnbf,
                     const float* __restrict__ W_in, ushort_t* __restrict__ WtIn,
                     const float* __restrict__ W_out, ushort_t* __restrict__ WtOut,
                     const float* __restrict__ W_xp, ushort_t* __restrict__ WtXp,
                     const float* __restrict__ W_dt, ushort_t* __restrict__ WtDt)
{
    __shared__ float t[32][33];
    __shared__ float red[8];
    int bid = blockIdx.x;
    int tid = threadIdx.x;

    if (bid < PRO_LN1) {
        // -------- LayerNorm row --------
        const float* xr = x + (size_t)bid * D_MODEL;
        float4 v = reinterpret_cast<const float4*>(xr)[tid];
        float s  = v.x + v.y + v.z + v.w;
        float ss = v.x * v.x + v.y * v.y + v.z * v.z + v.w * v.w;
        #pragma unroll
        for (int off = 32; off; off >>= 1) {
            s  += __shfl_down(s, off);
            ss += __shfl_down(ss, off);
        }
        int wid = tid >> 6, lane = tid & 63;
        if (lane == 0) { red[wid] = s; red[4 + wid] = ss; }
        __syncthreads();
        if (tid == 0) {
            float st = 0.f, sst = 0.f;
            #pragma unroll
            for (int i = 0; i < 4; ++i) { st += red[i]; sst += red[4 + i]; }
            red[0] = st; red[4] = sst;
        }
        __syncthreads();
        float mu  = red[0] * (1.f / D_MODEL);
        float var = red[4] * (1.f / D_MODEL) - mu * mu;
        float inv = rsqrtf(var + 1e-5f);
        float4 gv = reinterpret_cast<const float4*>(g)[tid];
        float4 bv = reinterpret_cast<const float4*>(bb)[tid];
        ushort4 o;
        o.x = f2bf((v.x - mu) * inv * gv.x + bv.x);
        o.y = f2bf((v.y - mu) * inv * gv.y + bv.y);
        o.z = f2bf((v.z - mu) * inv * gv.z + bv.z);
        o.w = f2bf((v.w - mu) * inv * gv.w + bv.w);
        reinterpret_cast<ushort4*>(xnbf + (size_t)bid * D_MODEL)[tid] = o;
    } else if (bid < PRO_TIN1) {
        int j = bid - PRO_LN1;
        transpose_job(W_in, WtIn, D_MODEL, 2 * D_INNER, j & 127, j >> 7, tid, t);
    } else if (bid < PRO_TOUT1) {
        int j = bid - PRO_TIN1;
        transpose_job(W_out, WtOut, D_INNER, D_MODEL, j & 31, j >> 5, tid, t);
    } else if (bid < PRO_TXP1) {
        int j = bid - PRO_TOUT1;
        transpose_job(W_xp, WtXp, D_INNER, XDBL_W, j & 3, j >> 2, tid, t);
    } else {
        int j = bid - PRO_TXP1;
        transpose_job(W_dt, WtDt, DT_RANK, D_INNER, j & 63, j >> 6, tid, t);
    }
}

// ---------------------------------------------------------------------------
// Global->LDS staging, width-16 async.
// ---------------------------------------------------------------------------
__device__ __forceinline__ void stage128x32(const ushort_t* __restrict__ gbase,
                                            size_t ld, ushort_t* ldsb, int tid)
{
    int l = tid & 63;
    int w = tid >> 6;
    int row = w * 16 + (l >> 2);
    int kg  = l & 3;
    char* lb = (char*)ldsb + w * 1024;
    const ushort_t* g0 = gbase + (size_t)row * ld + kg * 8;
    __builtin_amdgcn_global_load_lds(
        (const __attribute__((address_space(1))) unsigned*)g0,
        (__attribute__((address_space(3))) unsigned*)lb, 16, 0, 0);
    const ushort_t* g1 = g0 + (size_t)64 * ld;
    __builtin_amdgcn_global_load_lds(
        (const __attribute__((address_space(1))) unsigned*)g1,
        (__attribute__((address_space(3))) unsigned*)(lb + 4096), 16, 0, 0);
}

__device__ __forceinline__ void stage64x32(const ushort_t* __restrict__ gbase,
                                           size_t ld, ushort_t* ldsb, int tid)
{
    int l = tid & 63;
    int w = tid >> 6;
    int row = w * 16 + (l >> 2);
    int kg  = l & 3;
    char* lb = (char*)ldsb + w * 1024;
    const ushort_t* g0 = gbase + (size_t)row * ld + kg * 8;
    __builtin_amdgcn_global_load_lds(
        (const __attribute__((address_space(1))) unsigned*)g0,
        (__attribute__((address_space(3))) unsigned*)lb, 16, 0, 0);
}

// 64 rows x 64 k bf16 (8KB), linear [64][64]: 2 issues/wave, 8 rows per
// wave-issue (row = i*32 + w*8 + (l>>3), 16B at col (l&7)*8).
__device__ __forceinline__ void stage64x64(const ushort_t* __restrict__ gbase,
                                           size_t ld, ushort_t* ldsb, int tid)
{
    int l = tid & 63;
    int w = tid >> 6;
    #pragma unroll
    for (int i = 0; i < 2; ++i) {
        int row = i * 32 + w * 8 + (l >> 3);
        const ushort_t* src = gbase + (size_t)row * ld + (l & 7) * 8;
        char* dst = (char*)ldsb + (i * 32 + w * 8) * 128;
        __builtin_amdgcn_global_load_lds(
            (const __attribute__((address_space(1))) unsigned*)src,
            (__attribute__((address_space(3))) unsigned*)dst, 16, 0, 0);
    }
}

// ---------------------------------------------------------------------------
// xz GEMM: xzbf[2048][4096] = xnbf[2048][1024] x WtIn[4096][1024]^T, bf16 out.
// 128x128 tile, BK=32, 512 blocks (1D grid), XCD-swizzled (64 blocks/XCD).
// ---------------------------------------------------------------------------
__global__ __launch_bounds__(256)
void gemm_xz(const ushort_t* __restrict__ A, const ushort_t* __restrict__ Bt,
             ushort_t* __restrict__ C)
{
    __shared__ ushort_t As[128 * 32];
    __shared__ ushort_t Bs[128 * 32];
    const int K = D_MODEL, N = 2 * D_INNER;
    int bid = blockIdx.x;                       // 512
    int swz = ((bid & 7) << 6) + (bid >> 3);    // XCD k -> contiguous 64 tiles
    int bx = swz & 31, by = swz >> 5;
    int tid = threadIdx.x;
    int l = tid & 63, wid = tid >> 6;
    int wr = wid >> 1, wc = wid & 1;
    int row0 = by * 128, col0 = bx * 128;

    f32x4 acc[4][4];
    #pragma unroll
    for (int m = 0; m < 4; ++m)
        #pragma unroll
        for (int n = 0; n < 4; ++n)
            acc[m][n] = (f32x4){0.f, 0.f, 0.f, 0.f};

    const ushort_t* Ab = A  + (size_t)row0 * K;
    const ushort_t* Bb = Bt + (size_t)col0 * K;
    int arow = wr * 64 + (l & 15);
    int brow = wc * 64 + (l & 15);
    int kb   = (l >> 4) * 8;

    for (int k0 = 0; k0 < K; k0 += 32) {
        stage128x32(Ab + k0, K, As, tid);
        stage128x32(Bb + k0, K, Bs, tid);
        __syncthreads();
        bf16x8 af[4], bfr[4];
        #pragma unroll
        for (int m = 0; m < 4; ++m)
            af[m] = *reinterpret_cast<const bf16x8*>(&As[(arow + m * 16) * 32 + kb]);
        #pragma unroll
        for (int n = 0; n < 4; ++n)
            bfr[n] = *reinterpret_cast<const bf16x8*>(&Bs[(brow + n * 16) * 32 + kb]);
        #pragma unroll
        for (int m = 0; m < 4; ++m)
            #pragma unroll
            for (int n = 0; n < 4; ++n)
                acc[m][n] = __builtin_amdgcn_mfma_f32_16x16x32_bf16(
                    af[m], bfr[n], acc[m][n], 0, 0, 0);
        __syncthreads();
    }

    int ro = (l >> 4) * 4, co = l & 15;
    #pragma unroll
    for (int m = 0; m < 4; ++m) {
        #pragma unroll
        for (int n = 0; n < 4; ++n) {
            int c = col0 + wc * 64 + n * 16 + co;
            #pragma unroll
            for (int reg = 0; reg < 4; ++reg) {
                int r = row0 + wr * 64 + m * 16 + ro + reg;
                C[(size_t)r * N + c] = f2bf(acc[m][n][reg]);
            }
        }
    }
}

// ---------------------------------------------------------------------------
// bf16 MFMA GEMM for dt: A[2048][64] x WtDt[2048][64]^T, K=64.
// Epilogue: dt = softplus(acc + b_dt[col]), written as bf16.
// ---------------------------------------------------------------------------
__global__ __launch_bounds__(256)
void gemm_bf16_dt(const ushort_t* __restrict__ A, const ushort_t* __restrict__ Bt,
                  ushort_t* __restrict__ dtb, const float* __restrict__ bias)
{
    __shared__ ushort_t As[128 * 32];
    __shared__ ushort_t Bs[128 * 32];
    const int K = DT_RANK;   // 64
    int tid = threadIdx.x;
    int l = tid & 63, wid = tid >> 6;
    int wr = wid >> 1, wc = wid & 1;
    int row0 = blockIdx.y * 128, col0 = blockIdx.x * 128;

    f32x4 acc[4][4];
    #pragma unroll
    for (int m = 0; m < 4; ++m)
        #pragma unroll
        for (int n = 0; n < 4; ++n)
            acc[m][n] = (f32x4){0.f, 0.f, 0.f, 0.f};

    const ushort_t* Ab = A  + (size_t)row0 * K;
    const ushort_t* Bb = Bt + (size_t)col0 * K;
    int arow = wr * 64 + (l & 15);
    int brow = wc * 64 + (l & 15);
    int kb   = (l >> 4) * 8;

    #pragma unroll
    for (int k0 = 0; k0 < K; k0 += 32) {
        stage128x32(Ab + k0, K, As, tid);
        stage128x32(Bb + k0, K, Bs, tid);
        __syncthreads();
        bf16x8 af[4], bfr[4];
        #pragma unroll
        for (int m = 0; m < 4; ++m)
            af[m] = *reinterpret_cast<const bf16x8*>(&As[(arow + m * 16) * 32 + kb]);
        #pragma unroll
        for (int n = 0; n < 4; ++n)
            bfr[n] = *reinterpret_cast<const bf16x8*>(&Bs[(brow + n * 16) * 32 + kb]);
        #pragma unroll
        for (int m = 0; m < 4; ++m)
            #pragma unroll
            for (int n = 0; n < 4; ++n)
                acc[m][n] = __builtin_amdgcn_mfma_f32_16x16x32_bf16(
                    af[m], bfr[n], acc[m][n], 0, 0, 0);
        __syncthreads();
    }

    int ro = (l >> 4) * 4, co = l & 15;
    #pragma unroll
    for (int m = 0; m < 4; ++m) {
        #pragma unroll
        for (int n = 0; n < 4; ++n) {
            int c = col0 + wc * 64 + n * 16 + co;
            float bdt = bias[c];
            #pragma unroll
            for (int reg = 0; reg < 4; ++reg) {
                int r = row0 + wr * 64 + m * 16 + ro + reg;
                float v = acc[m][n][reg] + bdt;
                v = (v > 20.f) ? v : __logf(1.f + __expf(v));   // softplus
                dtb[(size_t)r * D_INNER + c] = f2bf(v);
            }
        }
    }
}

// ---------------------------------------------------------------------------
// xdbl split-K GEMM, 64x128 tile: parts[z][64-row-block][96] = u2 x WtXp^T.
// Grid (1, M/64, KSPLIT_XDBL). 4 waves 2x2, each 32x64. KS = 256.
// ---------------------------------------------------------------------------
__global__ __launch_bounds__(256)
void gemm_xdbl64(const ushort_t* __restrict__ A, const ushort_t* __restrict__ Bt,
                 float* __restrict__ parts)
{
    __shared__ ushort_t As[64 * 32];
    __shared__ ushort_t Bs[128 * 32];
    const int K = D_INNER;
    const int KS = D_INNER / KSPLIT_XDBL;      // 256
    int tid = threadIdx.x;
    int l = tid & 63, wid = tid >> 6;
    int wr = wid >> 1, wc = wid & 1;
    int row0 = blockIdx.y * 64;
    int kbeg = blockIdx.z * KS;

    f32x4 acc[2][4];
    #pragma unroll
    for (int m = 0; m < 2; ++m)
        #pragma unroll
        for (int n = 0; n < 4; ++n)
            acc[m][n] = (f32x4){0.f, 0.f, 0.f, 0.f};

    const ushort_t* Ab = A  + (size_t)row0 * K + kbeg;
    const ushort_t* Bb = Bt + kbeg;
    int arow = wr * 32 + (l & 15);
    int brow = wc * 64 + (l & 15);
    int kb   = (l >> 4) * 8;

    #pragma unroll
    for (int k0 = 0; k0 < KS; k0 += 32) {
        stage64x32(Ab + k0, K, As, tid);
        stage128x32(Bb + k0, K, Bs, tid);
        __syncthreads();
        bf16x8 af[2], bfr[4];
        #pragma unroll
        for (int m = 0; m < 2; ++m)
            af[m] = *reinterpret_cast<const bf16x8*>(&As[(arow + m * 16) * 32 + kb]);
        #pragma unroll
        for (int n = 0; n < 4; ++n)
            bfr[n] = *reinterpret_cast<const bf16x8*>(&Bs[(brow + n * 16) * 32 + kb]);
        #pragma unroll
        for (int m = 0; m < 2; ++m)
            #pragma unroll
            for (int n = 0; n < 4; ++n)
                acc[m][n] = __builtin_amdgcn_mfma_f32_16x16x32_bf16(
                    af[m], bfr[n], acc[m][n], 0, 0, 0);
        __syncthreads();
    }

    float* Cp = parts + (size_t)blockIdx.z * NROWS * XDBL_W;
    int ro = (l >> 4) * 4, co = l & 15;
    #pragma unroll
    for (int m = 0; m < 2; ++m) {
        #pragma unroll
        for (int n = 0; n < 4; ++n) {
            int c = wc * 64 + n * 16 + co;
            if (c >= XDBL_W) continue;
            #pragma unroll
            for (int reg = 0; reg < 4; ++reg) {
                int r = row0 + wr * 32 + m * 16 + ro + reg;
                Cp[(size_t)r * XDBL_W + c] = acc[m][n][reg];
            }
        }
    }
}

// ---------------------------------------------------------------------------
// out GEMM, 64x64 tile, BK=64 (32 K-iters): out = x + rs * (ybf x WtOut^T).
// 1D grid 512, XCD-swizzled. 4 waves 2x2, each 32x32.
// ---------------------------------------------------------------------------
__global__ __launch_bounds__(256)
void gemm_out64(const ushort_t* __restrict__ A, const ushort_t* __restrict__ Bt,
                const float* __restrict__ x, const float* __restrict__ res_scale,
                float* __restrict__ out)
{
    __shared__ ushort_t As[64 * 64];
    __shared__ ushort_t Bs[64 * 64];
    const int K = D_INNER, N = D_MODEL;
    int bid = blockIdx.x;                       // 512
    int swz = ((bid & 7) << 6) + (bid >> 3);
    int bx = swz & 15, by = swz >> 4;
    int tid = threadIdx.x;
    int l = tid & 63, wid = tid >> 6;
    int wr = wid >> 1, wc = wid & 1;
    int row0 = by * 64, col0 = bx * 64;

    f32x4 acc[2][2];
    #pragma unroll
    for (int m = 0; m < 2; ++m)
        #pragma unroll
        for (int n = 0; n < 2; ++n)
            acc[m][n] = (f32x4){0.f, 0.f, 0.f, 0.f};

    const ushort_t* Ab = A  + (size_t)row0 * K;
    const ushort_t* Bb = Bt + (size_t)col0 * K;
    int arow = wr * 32 + (l & 15);
    int brow = wc * 32 + (l & 15);
    int kb   = (l >> 4) * 8;

    for (int k0 = 0; k0 < K; k0 += 64) {
        stage64x64(Ab + k0, K, As, tid);
        stage64x64(Bb + k0, K, Bs, tid);
        __syncthreads();
        #pragma unroll
        for (int ks = 0; ks < 2; ++ks) {
            bf16x8 af[2], bfr[2];
            #pragma unroll
            for (int m = 0; m < 2; ++m)
                af[m] = *reinterpret_cast<const bf16x8*>(
                    &As[(arow + m * 16) * 64 + ks * 32 + kb]);
            #pragma unroll
            for (int n = 0; n < 2; ++n)
                bfr[n] = *reinterpret_cast<const bf16x8*>(
                    &Bs[(brow + n * 16) * 64 + ks * 32 + kb]);
            #pragma unroll
            for (int m = 0; m < 2; ++m)
                #pragma unroll
                for (int n = 0; n < 2; ++n)
                    acc[m][n] = __builtin_amdgcn_mfma_f32_16x16x32_bf16(
                        af[m], bfr[n], acc[m][n], 0, 0, 0);
        }
        __syncthreads();
    }

    float rs = res_scale[0];
    int ro = (l >> 4) * 4, co = l & 15;
    #pragma unroll
    for (int m = 0; m < 2; ++m) {
        #pragma unroll
        for (int n = 0; n < 2; ++n) {
            int c = col0 + wc * 32 + n * 16 + co;
            #pragma unroll
            for (int reg = 0; reg < 4; ++reg) {
                int r = row0 + wr * 32 + m * 16 + ro + reg;
                out[(size_t)r * N + c] = x[(size_t)r * N + c] + rs * acc[m][n][reg];
            }
        }
    }
}

// Split-K reduction (xdbl): out fp32 [2048][96]; also emit bf16 copy of the
// dt_lo columns (c<64) as the A-operand for the dt GEMM.
__global__ __launch_bounds__(256)
void reduce_partials_kernel(const float* __restrict__ p, float* __restrict__ out,
                            ushort_t* __restrict__ out64bf, int n)
{
    int i = blockIdx.x * 256 + threadIdx.x;
    if (i >= n) return;
    float s = 0.f;
    #pragma unroll
    for (int k = 0; k < KSPLIT_XDBL; ++k) s += p[(size_t)k * n + i];
    out[i] = s;
    int r = i / XDBL_W, c = i - r * XDBL_W;
    if (c < DT_RANK) out64bf[r * DT_RANK + c] = f2bf(s);
}

// ---------------------------------------------------------------------------
// Depthwise causal conv (K=4) + bias + SiLU, vectorized x4 (ushort4).
// ---------------------------------------------------------------------------
__global__ __launch_bounds__(256)
void conv_silu_kernel(const ushort_t* __restrict__ xzbf, const float* __restrict__ cw,
                      const float* __restrict__ cb, ushort_t* __restrict__ u2bf)
{
    int idx4 = blockIdx.x * 256 + threadIdx.x;    // 0 .. 1048575
    int e0 = (idx4 & 511) * 4;
    int l  = (idx4 >> 9) & (SEQLEN - 1);
    int b  = idx4 >> 19;
    size_t row = (size_t)b * SEQLEN + l;
    const ushort_t* base = xzbf + row * (2 * D_INNER) + e0;
    ushort4 r0 = {0,0,0,0}, r1 = {0,0,0,0}, r2 = {0,0,0,0}, r3;
    if (l >= 3) r0 = *reinterpret_cast<const ushort4*>(base - 3 * (size_t)(2 * D_INNER));
    if (l >= 2) r1 = *reinterpret_cast<const ushort4*>(base - 2 * (size_t)(2 * D_INNER));
    if (l >= 1) r2 = *reinterpret_cast<const ushort4*>(base - 1 * (size_t)(2 * D_INNER));
    r3 = *reinterpret_cast<const ushort4*>(base);
    const float4* cwv = reinterpret_cast<const float4*>(cw + (size_t)e0 * 4);
    float4 cb4 = *reinterpret_cast<const float4*>(cb + e0);
    const ushort_t* p0 = (const ushort_t*)&r0;
    const ushort_t* p1 = (const ushort_t*)&r1;
    const ushort_t* p2 = (const ushort_t*)&r2;
    const ushort_t* p3 = (const ushort_t*)&r3;
    const float* cbp = (const float*)&cb4;
    ushort4 o;
    ushort_t* op = (ushort_t*)&o;
    #pragma unroll
    for (int j = 0; j < 4; ++j) {
        float4 w = cwv[j];
        float a = cbp[j] + bf2f(p0[j]) * w.x + bf2f(p1[j]) * w.y
                         + bf2f(p2[j]) * w.z + bf2f(p3[j]) * w.w;
        op[j] = f2bf(a * fast_sigmoid(a));
    }
    reinterpret_cast<ushort4*>(u2bf)[idx4] = o;
}

// ---------------------------------------------------------------------------
// Chunked scan, pass A: one thread per (channel, chunk); 16 states in regs.
// ---------------------------------------------------------------------------
__global__ __launch_bounds__(256)
void scan_partial_kernel(const ushort_t* __restrict__ dtb, const float* __restrict__ xdbl,
                         const ushort_t* __restrict__ u2bf,
                         const float* __restrict__ A_log,
                         float* __restrict__ hend, float* __restrict__ sumdt_buf)
{
    int idx = blockIdx.x * 256 + threadIdx.x;   // 0 .. NCHAN*NCHUNK-1
    int p = idx & (NCHAN - 1);                  // channel (64 consecutive/wave)
    int c = idx >> 12;                          // chunk
    int b = p >> 11, e = p & (D_INNER - 1);

    float An[D_STATE];
    {
        const float4* ar = reinterpret_cast<const float4*>(A_log + (size_t)e * D_STATE);
        #pragma unroll
        for (int q = 0; q < 4; ++q) {
            float4 a4 = ar[q];
            An[q * 4 + 0] = -__expf(a4.x);
            An[q * 4 + 1] = -__expf(a4.y);
            An[q * 4 + 2] = -__expf(a4.z);
            An[q * 4 + 3] = -__expf(a4.w);
        }
    }
    float h[D_STATE];
    #pragma unroll
    for (int n = 0; n < D_STATE; ++n) h[n] = 0.f;
    float sdt = 0.f;

    size_t rowbase = (size_t)b * SEQLEN + c * LCHUNK;
    #pragma unroll
    for (int j = 0; j < LCHUNK; ++j) {
        size_t row = rowbase + j;
        float dt = bf2f(dtb[row * D_INNER + e]);
        float u  = bf2f(u2bf[row * D_INNER + e]);
        float dtu = dt * u;
        sdt += dt;
        const float4* xr = reinterpret_cast<const float4*>(xdbl + row * XDBL_W + DT_RANK);
        float Bv[D_STATE];
        #pragma unroll
        for (int q = 0; q < 4; ++q) {
            float4 b4 = xr[q];
            Bv[q * 4 + 0] = b4.x; Bv[q * 4 + 1] = b4.y;
            Bv[q * 4 + 2] = b4.z; Bv[q * 4 + 3] = b4.w;
        }
        #pragma unroll
        for (int n = 0; n < D_STATE; ++n)
            h[n] = __expf(dt * An[n]) * h[n] + dtu * Bv[n];
    }

    float4* hp = reinterpret_cast<float4*>(hend + ((size_t)p * NCHUNK + c) * D_STATE);
    #pragma unroll
    for (int q = 0; q < 4; ++q)
        hp[q] = (float4){h[q * 4 + 0], h[q * 4 + 1], h[q * 4 + 2], h[q * 4 + 3]};
    sumdt_buf[p * NCHUNK + c] = sdt;
}

// ---------------------------------------------------------------------------
// Pass B: per-channel inter-chunk Hillis-Steele scan; exclusive carry in place.
// ---------------------------------------------------------------------------
__global__ __launch_bounds__(1024)
void scan_combine_kernel(const float* __restrict__ A_log,
                         const float* __restrict__ sumdt_buf,
                         float* __restrict__ hend /* in: hend, out: hcarry */)
{
    __shared__ float Ps[NCHUNK][D_STATE];
    __shared__ float Hs[NCHUNK][D_STATE];
    int tid = threadIdx.x;
    int c = tid >> 4, n = tid & 15;
    int p = blockIdx.x;
    int e = p & (D_INNER - 1);
    float An = -__expf(A_log[e * D_STATE + n]);
    float P = __expf(An * sumdt_buf[p * NCHUNK + c]);
    float H = hend[(size_t)p * (NCHUNK * D_STATE) + c * D_STATE + n];
    Ps[c][n] = P; Hs[c][n] = H;
    __syncthreads();
    #pragma unroll
    for (int d = 1; d < NCHUNK; d <<= 1) {
        float Pl = 1.f, Hl = 0.f;
        if (c >= d) { Pl = Ps[c - d][n]; Hl = Hs[c - d][n]; }
        __syncthreads();
        H = P * Hl + H;   // (P,H) o (Pl,Hl)
        P = P * Pl;
        Ps[c][n] = P; Hs[c][n] = H;
        __syncthreads();
    }
    float carry = (c == 0) ? 0.f : Hs[c - 1][n];
    hend[(size_t)p * (NCHUNK * D_STATE) + c * D_STATE + n] = carry;
}

// ---------------------------------------------------------------------------
// Pass C: one thread per (channel, chunk), seeded with carry; in-register
// dot with C row; fused D-skip + SiLU(z) gate; writes y as bf16.
// ---------------------------------------------------------------------------
__global__ __launch_bounds__(256)
void scan_final_kernel(const ushort_t* __restrict__ dtb, const float* __restrict__ xdbl,
                       const ushort_t* __restrict__ xzbf, const ushort_t* __restrict__ u2bf,
                       ushort_t* __restrict__ ybf,
                       const float* __restrict__ A_log,
                       const float* __restrict__ D_param,
                       const float* __restrict__ hcarry)
{
    int idx = blockIdx.x * 256 + threadIdx.x;
    int p = idx & (NCHAN - 1);
    int c = idx >> 12;
    int b = p >> 11, e = p & (D_INNER - 1);
    float De = D_param[e];

    float An[D_STATE];
    {
        const float4* ar = reinterpret_cast<const float4*>(A_log + (size_t)e * D_STATE);
        #pragma unroll
        for (int q = 0; q < 4; ++q) {
            float4 a4 = ar[q];
            An[q * 4 + 0] = -__expf(a4.x);
            An[q * 4 + 1] = -__expf(a4.y);
            An[q * 4 + 2] = -__expf(a4.z);
            An[q * 4 + 3] = -__expf(a4.w);
        }
    }
    float h[D_STATE];
    {
        const float4* hp = reinterpret_cast<const float4*>(
            hcarry + ((size_t)p * NCHUNK + c) * D_STATE);
        #pragma unroll
        for (int q = 0; q < 4; ++q) {
            float4 h4 = hp[q];
            h[q * 4 + 0] = h4.x; h[q * 4 + 1] = h4.y;
            h[q * 4 + 2] = h4.z; h[q * 4 + 3] = h4.w;
        }
    }

    size_t rowbase = (size_t)b * SEQLEN + c * LCHUNK;
    #pragma unroll
    for (int j = 0; j < LCHUNK; ++j) {
        size_t row = rowbase + j;
        float dt = bf2f(dtb[row * D_INNER + e]);
        float u  = bf2f(u2bf[row * D_INNER + e]);
        float dtu = dt * u;
        const float4* xr = reinterpret_cast<const float4*>(xdbl + row * XDBL_W + DT_RANK);
        float Bv[D_STATE], Cv[D_STATE];
        #pragma unroll
        for (int q = 0; q < 4; ++q) {
            float4 b4 = xr[q];
            Bv[q * 4 + 0] = b4.x; Bv[q * 4 + 1] = b4.y;
            Bv[q * 4 + 2] = b4.z; Bv[q * 4 + 3] = b4.w;
            float4 c4 = xr[q + 4];
            Cv[q * 4 + 0] = c4.x; Cv[q * 4 + 1] = c4.y;
            Cv[q * 4 + 2] = c4.z; Cv[q * 4 + 3] = c4.w;
        }
        float y = 0.f;
        #pragma unroll
        for (int n = 0; n < D_STATE; ++n) {
            h[n] = __expf(dt * An[n]) * h[n] + dtu * Bv[n];
            y += h[n] * Cv[n];
        }
        float z  = bf2f(xzbf[row * (2 * D_INNER) + D_INNER + e]);
        float sz = z * fast_sigmoid(z);
        ybf[row * D_INNER + e] = f2bf((y + u * De) * sz);
    }
}

// ---------------------------------------------------------------------------
extern "C" void kernel_launch(void* const* d_in, const int* in_sizes, int n_in,
                              void* d_out, int out_size, void* d_ws, size_t ws_size,
                              hipStream_t stream)
{
    const float* x       = (const float*)d_in[0];
    const float* ln_g    = (const float*)d_in[1];
    const float* ln_b    = (const float*)d_in[2];
    const float* W_in    = (const float*)d_in[3];
    const float* conv_w  = (const float*)d_in[4];
    const float* conv_b  = (const float*)d_in[5];
    const float* W_xp    = (const float*)d_in[6];
    const float* W_dt    = (const float*)d_in[7];
    const float* b_dt    = (const float*)d_in[8];
    const float* A_log   = (const float*)d_in[9];
    const float* D_param = (const float*)d_in[10];
    const float* W_out   = (const float*)d_in[11];
    const float* res_sc  = (const float*)d_in[12];
    float* out = (float*)d_out;

    char* ws = (char*)d_ws;
    const size_t MB = 1024 * 1024;
    // Workspace (peak 82 MB):
    //   xzbf    [0,16M)      2048x4096 bf16 (u cols 0-2047, z cols 2048-4095)
    //   u2bf    [16M,24M)    2048x2048 bf16
    //   dtb16   [24M,32M)    2048x2048 bf16 (softplus'd dt)
    //   xdbl    [32M,33M)    2048x96 fp32
    //   xdbl64  [33M,34M)    2048x64 bf16 (dt_lo, A-operand for dt GEMM)
    //   hend    [34M,50M)    4096x64x16 fp32 (carry in place)
    //   sumdt   [50M,51M)    4096x64 fp32
    //   xnbf    [51M,55M)    2048x1024 bf16
    //   WtIn    [55M,63M)    4096x1024 bf16
    //   WtOut   [63M,67M)    1024x2048 bf16
    //   WtXp    [67M,67.5M)  128x2048 bf16 (rows 96..127 zeroed via col guard)
    //   WtDt    [67.5M,68M)  2048x64 bf16
    //   ybf     [68M,76M)    2048x2048 bf16
    //   partsX  [76M,82M)    8x2048x96 fp32
    ushort_t* xzbf   = (ushort_t*)(ws);
    ushort_t* u2bf   = (ushort_t*)(ws + 16 * MB);
    ushort_t* dtb16  = (ushort_t*)(ws + 24 * MB);
    float*    xdbl   = (float*)(ws + 32 * MB);
    ushort_t* xdbl64 = (ushort_t*)(ws + 33 * MB);
    float*    hend   = (float*)(ws + 34 * MB);
    float*    sumdt  = (float*)(ws + 50 * MB);
    ushort_t* xnbf   = (ushort_t*)(ws + 51 * MB);
    ushort_t* WtIn   = (ushort_t*)(ws + 55 * MB);
    ushort_t* WtOut  = (ushort_t*)(ws + 63 * MB);
    ushort_t* WtXp   = (ushort_t*)(ws + 67 * MB);
    ushort_t* WtDt   = (ushort_t*)(ws + 67 * MB + 512 * 1024);
    ushort_t* ybf    = (ushort_t*)(ws + 68 * MB);
    float*    partsX = (float*)(ws + 76 * MB);

    // 0+1. mega-prologue: LayerNorm + all weight transposes (+WtXp pad)
    prologue_kernel<<<PRO_TOTAL, 256, 0, stream>>>(
        x, ln_g, ln_b, xnbf, W_in, WtIn, W_out, WtOut, W_xp, WtXp, W_dt, WtDt);

    // 2. xz = xn @ W_in   [2048 x 4096, K=1024]  (bf16 MFMA, XCD-swizzled)
    gemm_xz<<<512, 256, 0, stream>>>(xnbf, WtIn, xzbf);

    // 3. u2 = silu(causal_conv(u) + conv_b)   (bf16, x4 vectorized)
    conv_silu_kernel<<<(BATCH * SEQLEN * D_INNER) / 1024, 256, 0, stream>>>(
        xzbf, conv_w, conv_b, u2bf);

    // 4. xdbl = u2 @ W_xp  [2048 x 96, K=2048]  64-row-tile split-K x8 + reduce
    {
        dim3 grid(1, NROWS / 64, KSPLIT_XDBL);
        gemm_xdbl64<<<grid, 256, 0, stream>>>(u2bf, WtXp, partsX);
        reduce_partials_kernel<<<(NROWS * XDBL_W + 255) / 256, 256, 0, stream>>>(
            partsX, xdbl, xdbl64, NROWS * XDBL_W);
    }

    // 5. dt = softplus(dt_lo @ W_dt + b_dt)  [2048 x 2048, K=64]  (bf16 MFMA)
    {
        dim3 grid(D_INNER / 128, NROWS / 128);
        gemm_bf16_dt<<<grid, 256, 0, stream>>>(xdbl64, WtDt, dtb16, b_dt);
    }

    // 6. chunked parallel scan (A: partials, B: inter-chunk, C: final+gate)
    scan_partial_kernel<<<(NCHAN * NCHUNK) / 256, 256, 0, stream>>>(
        dtb16, xdbl, u2bf, A_log, hend, sumdt);
    scan_combine_kernel<<<NCHAN, 1024, 0, stream>>>(A_log, sumdt, hend);
    scan_final_kernel<<<(NCHAN * NCHUNK) / 256, 256, 0, stream>>>(
        dtb16, xdbl, xzbf, u2bf, ybf, A_log, D_param, hend);

    // 7. out = x + rs * (y @ W_out)  [2048 x 1024, K=2048]  64x64 BK=64 direct
    gemm_out64<<<512, 256, 0, stream>>>(ybf, WtOut, x, res_sc, out);
}

// Round 10
// 162.864 us; speedup vs baseline: 13.7032x; 1.0047x over previous
//
#include <hip/hip_runtime.h>
#include <hip/hip_bf16.h>

// Dims (compile-time constants from the reference)
#define D_MODEL 1024
#define D_STATE 16
#define D_CONV  4
#define D_INNER 2048
#define DT_RANK 64
#define BATCH   2
#define SEQLEN  1024
#define NROWS   (BATCH * SEQLEN)        // 2048
#define XDBL_W  (DT_RANK + 2 * D_STATE) // 96
#define NCHUNK  64                      // chunks per sequence
#define LCHUNK  16                      // steps per chunk
#define NCHAN   (BATCH * D_INNER)       // 4096 (b,e) channels
#define KSPLIT_XDBL 8

typedef unsigned short ushort_t;
typedef __attribute__((ext_vector_type(8))) short bf16x8;
typedef __attribute__((ext_vector_type(8))) unsigned short ushort8v;
typedef __attribute__((ext_vector_type(4))) float f32x4;

// fp32 -> bf16 (round-to-nearest-even), bit-level (deterministic)
__device__ __forceinline__ ushort_t f2bf(float f) {
    union { float f; unsigned u; } v; v.f = f;
    unsigned r = v.u + 0x7fffu + ((v.u >> 16) & 1u);
    return (ushort_t)(r >> 16);
}
__device__ __forceinline__ float bf2f(ushort_t h) {
    union { unsigned u; float f; } v; v.u = (unsigned)h << 16; return v.f;
}
__device__ __forceinline__ float fast_sigmoid(float z) {
    return __builtin_amdgcn_rcpf(1.f + __expf(-z));
}

// ---------------------------------------------------------------------------
// Mega-prologue: LayerNorm (2048 blocks) + 4 weight transpose-converts
// (job selected by blockIdx range).
// ---------------------------------------------------------------------------
#define PRO_LN1   2048
#define PRO_TIN1  6144
#define PRO_TOUT1 8192
#define PRO_TXP1  8448
#define PRO_TOTAL 8576

__device__ __forceinline__ void transpose_job(const float* __restrict__ W,
                                              ushort_t* __restrict__ Wt,
                                              int R, int Creal,
                                              int cx, int ry, int tid,
                                              float t[32][33])
{
    int c0 = cx * 32, r0 = ry * 32;
    int tx = tid & 31, ty = tid >> 5;
    int col = c0 + tx;
    #pragma unroll
    for (int i = 0; i < 32; i += 8) {
        float v = (col < Creal) ? W[(size_t)(r0 + ty + i) * Creal + col] : 0.f;
        t[ty + i][tx] = v;
    }
    __syncthreads();
    #pragma unroll
    for (int i = 0; i < 32; i += 8)
        Wt[(size_t)(c0 + ty + i) * R + r0 + tx] = f2bf(t[tx][ty + i]);
}

__global__ __launch_bounds__(256)
void prologue_kernel(const float* __restrict__ x, const float* __restrict__ g,
                     const float* __restrict__ bb, ushort_t* __restrict__ xnbf,
                     const float* __restrict__ W_in, ushort_t* __restrict__ WtIn,
                     const float* __restrict__ W_out, ushort_t* __restrict__ WtOut,
                     const float* __restrict__ W_xp, ushort_t* __restrict__ WtXp,
                     const float* __restrict__ W_dt, ushort_t* __restrict__ WtDt)
{
    __shared__ float t[32][33];
    __shared__ float red[8];
    int bid = blockIdx.x;
    int tid = threadIdx.x;

    if (bid < PRO_LN1) {
        const float* xr = x + (size_t)bid * D_MODEL;
        float4 v = reinterpret_cast<const float4*>(xr)[tid];
        float s  = v.x + v.y + v.z + v.w;
        float ss = v.x * v.x + v.y * v.y + v.z * v.z + v.w * v.w;
        #pragma unroll
        for (int off = 32; off; off >>= 1) {
            s  += __shfl_down(s, off);
            ss += __shfl_down(ss, off);
        }
        int wid = tid >> 6, lane = tid & 63;
        if (lane == 0) { red[wid] = s; red[4 + wid] = ss; }
        __syncthreads();
        if (tid == 0) {
            float st = 0.f, sst = 0.f;
            #pragma unroll
            for (int i = 0; i < 4; ++i) { st += red[i]; sst += red[4 + i]; }
            red[0] = st; red[4] = sst;
        }
        __syncthreads();
        float mu  = red[0] * (1.f / D_MODEL);
        float var = red[4] * (1.f / D_MODEL) - mu * mu;
        float inv = rsqrtf(var + 1e-5f);
        float4 gv = reinterpret_cast<const float4*>(g)[tid];
        float4 bv = reinterpret_cast<const float4*>(bb)[tid];
        ushort4 o;
        o.x = f2bf((v.x - mu) * inv * gv.x + bv.x);
        o.y = f2bf((v.y - mu) * inv * gv.y + bv.y);
        o.z = f2bf((v.z - mu) * inv * gv.z + bv.z);
        o.w = f2bf((v.w - mu) * inv * gv.w + bv.w);
        reinterpret_cast<ushort4*>(xnbf + (size_t)bid * D_MODEL)[tid] = o;
    } else if (bid < PRO_TIN1) {
        int j = bid - PRO_LN1;
        transpose_job(W_in, WtIn, D_MODEL, 2 * D_INNER, j & 127, j >> 7, tid, t);
    } else if (bid < PRO_TOUT1) {
        int j = bid - PRO_TIN1;
        transpose_job(W_out, WtOut, D_INNER, D_MODEL, j & 31, j >> 5, tid, t);
    } else if (bid < PRO_TXP1) {
        int j = bid - PRO_TOUT1;
        transpose_job(W_xp, WtXp, D_INNER, XDBL_W, j & 3, j >> 2, tid, t);
    } else {
        int j = bid - PRO_TXP1;
        transpose_job(W_dt, WtDt, DT_RANK, D_INNER, j & 63, j >> 6, tid, t);
    }
}

// ---------------------------------------------------------------------------
// Global->LDS staging, width-16 async.
// ---------------------------------------------------------------------------
__device__ __forceinline__ void stage128x32(const ushort_t* __restrict__ gbase,
                                            size_t ld, ushort_t* ldsb, int tid)
{
    int l = tid & 63;
    int w = tid >> 6;
    int row = w * 16 + (l >> 2);
    int kg  = l & 3;
    char* lb = (char*)ldsb + w * 1024;
    const ushort_t* g0 = gbase + (size_t)row * ld + kg * 8;
    __builtin_amdgcn_global_load_lds(
        (const __attribute__((address_space(1))) unsigned*)g0,
        (__attribute__((address_space(3))) unsigned*)lb, 16, 0, 0);
    const ushort_t* g1 = g0 + (size_t)64 * ld;
    __builtin_amdgcn_global_load_lds(
        (const __attribute__((address_space(1))) unsigned*)g1,
        (__attribute__((address_space(3))) unsigned*)(lb + 4096), 16, 0, 0);
}

__device__ __forceinline__ void stage64x32(const ushort_t* __restrict__ gbase,
                                           size_t ld, ushort_t* ldsb, int tid)
{
    int l = tid & 63;
    int w = tid >> 6;
    int row = w * 16 + (l >> 2);
    int kg  = l & 3;
    char* lb = (char*)ldsb + w * 1024;
    const ushort_t* g0 = gbase + (size_t)row * ld + kg * 8;
    __builtin_amdgcn_global_load_lds(
        (const __attribute__((address_space(1))) unsigned*)g0,
        (__attribute__((address_space(3))) unsigned*)lb, 16, 0, 0);
}

// 64 rows x 64 k bf16 (8KB), linear [64][64].
__device__ __forceinline__ void stage64x64(const ushort_t* __restrict__ gbase,
                                           size_t ld, ushort_t* ldsb, int tid)
{
    int l = tid & 63;
    int w = tid >> 6;
    #pragma unroll
    for (int i = 0; i < 2; ++i) {
        int row = i * 32 + w * 8 + (l >> 3);
        const ushort_t* src = gbase + (size_t)row * ld + (l & 7) * 8;
        char* dst = (char*)ldsb + (i * 32 + w * 8) * 128;
        __builtin_amdgcn_global_load_lds(
            (const __attribute__((address_space(1))) unsigned*)src,
            (__attribute__((address_space(3))) unsigned*)dst, 16, 0, 0);
    }
}

// 128 rows x 64 k bf16 (16KB), linear [128][64].
__device__ __forceinline__ void stage128x64(const ushort_t* __restrict__ gbase,
                                            size_t ld, ushort_t* ldsb, int tid)
{
    int l = tid & 63;
    int w = tid >> 6;
    #pragma unroll
    for (int i = 0; i < 4; ++i) {
        int row = i * 32 + w * 8 + (l >> 3);
        const ushort_t* src = gbase + (size_t)row * ld + (l & 7) * 8;
        char* dst = (char*)ldsb + (i * 32 + w * 8) * 128;
        __builtin_amdgcn_global_load_lds(
            (const __attribute__((address_space(1))) unsigned*)src,
            (__attribute__((address_space(3))) unsigned*)dst, 16, 0, 0);
    }
}

// ---------------------------------------------------------------------------
// xz GEMM: xzbf[2048][4096] = xnbf[2048][1024] x WtIn[4096][1024]^T, bf16 out.
// 128x128 tile, BK=64 (16 K-iters), 512 blocks 1D, XCD-swizzled.
// ---------------------------------------------------------------------------
__global__ __launch_bounds__(256)
void gemm_xz(const ushort_t* __restrict__ A, const ushort_t* __restrict__ Bt,
             ushort_t* __restrict__ C)
{
    __shared__ ushort_t As[128 * 64];
    __shared__ ushort_t Bs[128 * 64];
    const int K = D_MODEL, N = 2 * D_INNER;
    int bid = blockIdx.x;                       // 512
    int swz = ((bid & 7) << 6) + (bid >> 3);    // XCD k -> contiguous 64 tiles
    int bx = swz & 31, by = swz >> 5;
    int tid = threadIdx.x;
    int l = tid & 63, wid = tid >> 6;
    int wr = wid >> 1, wc = wid & 1;
    int row0 = by * 128, col0 = bx * 128;

    f32x4 acc[4][4];
    #pragma unroll
    for (int m = 0; m < 4; ++m)
        #pragma unroll
        for (int n = 0; n < 4; ++n)
            acc[m][n] = (f32x4){0.f, 0.f, 0.f, 0.f};

    const ushort_t* Ab = A  + (size_t)row0 * K;
    const ushort_t* Bb = Bt + (size_t)col0 * K;
    int arow = wr * 64 + (l & 15);
    int brow = wc * 64 + (l & 15);
    int kb   = (l >> 4) * 8;

    for (int k0 = 0; k0 < K; k0 += 64) {
        stage128x64(Ab + k0, K, As, tid);
        stage128x64(Bb + k0, K, Bs, tid);
        __syncthreads();
        #pragma unroll
        for (int ks = 0; ks < 2; ++ks) {
            bf16x8 af[4], bfr[4];
            #pragma unroll
            for (int m = 0; m < 4; ++m)
                af[m] = *reinterpret_cast<const bf16x8*>(
                    &As[(arow + m * 16) * 64 + ks * 32 + kb]);
            #pragma unroll
            for (int n = 0; n < 4; ++n)
                bfr[n] = *reinterpret_cast<const bf16x8*>(
                    &Bs[(brow + n * 16) * 64 + ks * 32 + kb]);
            #pragma unroll
            for (int m = 0; m < 4; ++m)
                #pragma unroll
                for (int n = 0; n < 4; ++n)
                    acc[m][n] = __builtin_amdgcn_mfma_f32_16x16x32_bf16(
                        af[m], bfr[n], acc[m][n], 0, 0, 0);
        }
        __syncthreads();
    }

    int ro = (l >> 4) * 4, co = l & 15;
    #pragma unroll
    for (int m = 0; m < 4; ++m) {
        #pragma unroll
        for (int n = 0; n < 4; ++n) {
            int c = col0 + wc * 64 + n * 16 + co;
            #pragma unroll
            for (int reg = 0; reg < 4; ++reg) {
                int r = row0 + wr * 64 + m * 16 + ro + reg;
                C[(size_t)r * N + c] = f2bf(acc[m][n][reg]);
            }
        }
    }
}

// ---------------------------------------------------------------------------
// bf16 MFMA GEMM for dt: A[2048][64] x WtDt[2048][64]^T, K=64.
// Epilogue: dt = softplus(acc + b_dt[col]), written as bf16.
// ---------------------------------------------------------------------------
__global__ __launch_bounds__(256)
void gemm_bf16_dt(const ushort_t* __restrict__ A, const ushort_t* __restrict__ Bt,
                  ushort_t* __restrict__ dtb, const float* __restrict__ bias)
{
    __shared__ ushort_t As[128 * 32];
    __shared__ ushort_t Bs[128 * 32];
    const int K = DT_RANK;   // 64
    int tid = threadIdx.x;
    int l = tid & 63, wid = tid >> 6;
    int wr = wid >> 1, wc = wid & 1;
    int row0 = blockIdx.y * 128, col0 = blockIdx.x * 128;

    f32x4 acc[4][4];
    #pragma unroll
    for (int m = 0; m < 4; ++m)
        #pragma unroll
        for (int n = 0; n < 4; ++n)
            acc[m][n] = (f32x4){0.f, 0.f, 0.f, 0.f};

    const ushort_t* Ab = A  + (size_t)row0 * K;
    const ushort_t* Bb = Bt + (size_t)col0 * K;
    int arow = wr * 64 + (l & 15);
    int brow = wc * 64 + (l & 15);
    int kb   = (l >> 4) * 8;

    #pragma unroll
    for (int k0 = 0; k0 < K; k0 += 32) {
        stage128x32(Ab + k0, K, As, tid);
        stage128x32(Bb + k0, K, Bs, tid);
        __syncthreads();
        bf16x8 af[4], bfr[4];
        #pragma unroll
        for (int m = 0; m < 4; ++m)
            af[m] = *reinterpret_cast<const bf16x8*>(&As[(arow + m * 16) * 32 + kb]);
        #pragma unroll
        for (int n = 0; n < 4; ++n)
            bfr[n] = *reinterpret_cast<const bf16x8*>(&Bs[(brow + n * 16) * 32 + kb]);
        #pragma unroll
        for (int m = 0; m < 4; ++m)
            #pragma unroll
            for (int n = 0; n < 4; ++n)
                acc[m][n] = __builtin_amdgcn_mfma_f32_16x16x32_bf16(
                    af[m], bfr[n], acc[m][n], 0, 0, 0);
        __syncthreads();
    }

    int ro = (l >> 4) * 4, co = l & 15;
    #pragma unroll
    for (int m = 0; m < 4; ++m) {
        #pragma unroll
        for (int n = 0; n < 4; ++n) {
            int c = col0 + wc * 64 + n * 16 + co;
            float bdt = bias[c];
            #pragma unroll
            for (int reg = 0; reg < 4; ++reg) {
                int r = row0 + wr * 64 + m * 16 + ro + reg;
                float v = acc[m][n][reg] + bdt;
                v = (v > 20.f) ? v : __logf(1.f + __expf(v));   // softplus
                dtb[(size_t)r * D_INNER + c] = f2bf(v);
            }
        }
    }
}

// ---------------------------------------------------------------------------
// xdbl split-K GEMM, 64x128 tile: parts[z][64-row-block][96] = u2 x WtXp^T.
// ---------------------------------------------------------------------------
__global__ __launch_bounds__(256)
void gemm_xdbl64(const ushort_t* __restrict__ A, const ushort_t* __restrict__ Bt,
                 float* __restrict__ parts)
{
    __shared__ ushort_t As[64 * 32];
    __shared__ ushort_t Bs[128 * 32];
    const int K = D_INNER;
    const int KS = D_INNER / KSPLIT_XDBL;      // 256
    int tid = threadIdx.x;
    int l = tid & 63, wid = tid >> 6;
    int wr = wid >> 1, wc = wid & 1;
    int row0 = blockIdx.y * 64;
    int kbeg = blockIdx.z * KS;

    f32x4 acc[2][4];
    #pragma unroll
    for (int m = 0; m < 2; ++m)
        #pragma unroll
        for (int n = 0; n < 4; ++n)
            acc[m][n] = (f32x4){0.f, 0.f, 0.f, 0.f};

    const ushort_t* Ab = A  + (size_t)row0 * K + kbeg;
    const ushort_t* Bb = Bt + kbeg;
    int arow = wr * 32 + (l & 15);
    int brow = wc * 64 + (l & 15);
    int kb   = (l >> 4) * 8;

    #pragma unroll
    for (int k0 = 0; k0 < KS; k0 += 32) {
        stage64x32(Ab + k0, K, As, tid);
        stage128x32(Bb + k0, K, Bs, tid);
        __syncthreads();
        bf16x8 af[2], bfr[4];
        #pragma unroll
        for (int m = 0; m < 2; ++m)
            af[m] = *reinterpret_cast<const bf16x8*>(&As[(arow + m * 16) * 32 + kb]);
        #pragma unroll
        for (int n = 0; n < 4; ++n)
            bfr[n] = *reinterpret_cast<const bf16x8*>(&Bs[(brow + n * 16) * 32 + kb]);
        #pragma unroll
        for (int m = 0; m < 2; ++m)
            #pragma unroll
            for (int n = 0; n < 4; ++n)
                acc[m][n] = __builtin_amdgcn_mfma_f32_16x16x32_bf16(
                    af[m], bfr[n], acc[m][n], 0, 0, 0);
        __syncthreads();
    }

    float* Cp = parts + (size_t)blockIdx.z * NROWS * XDBL_W;
    int ro = (l >> 4) * 4, co = l & 15;
    #pragma unroll
    for (int m = 0; m < 2; ++m) {
        #pragma unroll
        for (int n = 0; n < 4; ++n) {
            int c = wc * 64 + n * 16 + co;
            if (c >= XDBL_W) continue;
            #pragma unroll
            for (int reg = 0; reg < 4; ++reg) {
                int r = row0 + wr * 32 + m * 16 + ro + reg;
                Cp[(size_t)r * XDBL_W + c] = acc[m][n][reg];
            }
        }
    }
}

// ---------------------------------------------------------------------------
// out GEMM, 64x64 tile, BK=64: out = x + rs * (ybf x WtOut^T). XCD-swizzled.
// ---------------------------------------------------------------------------
__global__ __launch_bounds__(256)
void gemm_out64(const ushort_t* __restrict__ A, const ushort_t* __restrict__ Bt,
                const float* __restrict__ x, const float* __restrict__ res_scale,
                float* __restrict__ out)
{
    __shared__ ushort_t As[64 * 64];
    __shared__ ushort_t Bs[64 * 64];
    const int K = D_INNER, N = D_MODEL;
    int bid = blockIdx.x;                       // 512
    int swz = ((bid & 7) << 6) + (bid >> 3);
    int bx = swz & 15, by = swz >> 4;
    int tid = threadIdx.x;
    int l = tid & 63, wid = tid >> 6;
    int wr = wid >> 1, wc = wid & 1;
    int row0 = by * 64, col0 = bx * 64;

    f32x4 acc[2][2];
    #pragma unroll
    for (int m = 0; m < 2; ++m)
        #pragma unroll
        for (int n = 0; n < 2; ++n)
            acc[m][n] = (f32x4){0.f, 0.f, 0.f, 0.f};

    const ushort_t* Ab = A  + (size_t)row0 * K;
    const ushort_t* Bb = Bt + (size_t)col0 * K;
    int arow = wr * 32 + (l & 15);
    int brow = wc * 32 + (l & 15);
    int kb   = (l >> 4) * 8;

    for (int k0 = 0; k0 < K; k0 += 64) {
        stage64x64(Ab + k0, K, As, tid);
        stage64x64(Bb + k0, K, Bs, tid);
        __syncthreads();
        #pragma unroll
        for (int ks = 0; ks < 2; ++ks) {
            bf16x8 af[2], bfr[2];
            #pragma unroll
            for (int m = 0; m < 2; ++m)
                af[m] = *reinterpret_cast<const bf16x8*>(
                    &As[(arow + m * 16) * 64 + ks * 32 + kb]);
            #pragma unroll
            for (int n = 0; n < 2; ++n)
                bfr[n] = *reinterpret_cast<const bf16x8*>(
                    &Bs[(brow + n * 16) * 64 + ks * 32 + kb]);
            #pragma unroll
            for (int m = 0; m < 2; ++m)
                #pragma unroll
                for (int n = 0; n < 2; ++n)
                    acc[m][n] = __builtin_amdgcn_mfma_f32_16x16x32_bf16(
                        af[m], bfr[n], acc[m][n], 0, 0, 0);
        }
        __syncthreads();
    }

    float rs = res_scale[0];
    int ro = (l >> 4) * 4, co = l & 15;
    #pragma unroll
    for (int m = 0; m < 2; ++m) {
        #pragma unroll
        for (int n = 0; n < 2; ++n) {
            int c = col0 + wc * 32 + n * 16 + co;
            #pragma unroll
            for (int reg = 0; reg < 4; ++reg) {
                int r = row0 + wr * 32 + m * 16 + ro + reg;
                out[(size_t)r * N + c] = x[(size_t)r * N + c] + rs * acc[m][n][reg];
            }
        }
    }
}

// Split-K reduction (xdbl): out fp32 [2048][96]; also emit bf16 copy of the
// dt_lo columns (c<64) as the A-operand for the dt GEMM.
__global__ __launch_bounds__(256)
void reduce_partials_kernel(const float* __restrict__ p, float* __restrict__ out,
                            ushort_t* __restrict__ out64bf, int n)
{
    int i = blockIdx.x * 256 + threadIdx.x;
    if (i >= n) return;
    float s = 0.f;
    #pragma unroll
    for (int k = 0; k < KSPLIT_XDBL; ++k) s += p[(size_t)k * n + i];
    out[i] = s;
    int r = i / XDBL_W, c = i - r * XDBL_W;
    if (c < DT_RANK) out64bf[r * DT_RANK + c] = f2bf(s);
}

// ---------------------------------------------------------------------------
// Depthwise causal conv (K=4) + bias + SiLU, vectorized x4 (ushort4).
// ---------------------------------------------------------------------------
__global__ __launch_bounds__(256)
void conv_silu_kernel(const ushort_t* __restrict__ xzbf, const float* __restrict__ cw,
                      const float* __restrict__ cb, ushort_t* __restrict__ u2bf)
{
    int idx4 = blockIdx.x * 256 + threadIdx.x;    // 0 .. 1048575
    int e0 = (idx4 & 511) * 4;
    int l  = (idx4 >> 9) & (SEQLEN - 1);
    int b  = idx4 >> 19;
    size_t row = (size_t)b * SEQLEN + l;
    const ushort_t* base = xzbf + row * (2 * D_INNER) + e0;
    ushort4 r0 = {0,0,0,0}, r1 = {0,0,0,0}, r2 = {0,0,0,0}, r3;
    if (l >= 3) r0 = *reinterpret_cast<const ushort4*>(base - 3 * (size_t)(2 * D_INNER));
    if (l >= 2) r1 = *reinterpret_cast<const ushort4*>(base - 2 * (size_t)(2 * D_INNER));
    if (l >= 1) r2 = *reinterpret_cast<const ushort4*>(base - 1 * (size_t)(2 * D_INNER));
    r3 = *reinterpret_cast<const ushort4*>(base);
    const float4* cwv = reinterpret_cast<const float4*>(cw + (size_t)e0 * 4);
    float4 cb4 = *reinterpret_cast<const float4*>(cb + e0);
    const ushort_t* p0 = (const ushort_t*)&r0;
    const ushort_t* p1 = (const ushort_t*)&r1;
    const ushort_t* p2 = (const ushort_t*)&r2;
    const ushort_t* p3 = (const ushort_t*)&r3;
    const float* cbp = (const float*)&cb4;
    ushort4 o;
    ushort_t* op = (ushort_t*)&o;
    #pragma unroll
    for (int j = 0; j < 4; ++j) {
        float4 w = cwv[j];
        float a = cbp[j] + bf2f(p0[j]) * w.x + bf2f(p1[j]) * w.y
                         + bf2f(p2[j]) * w.z + bf2f(p3[j]) * w.w;
        op[j] = f2bf(a * fast_sigmoid(a));
    }
    reinterpret_cast<ushort4*>(u2bf)[idx4] = o;
}

// ---------------------------------------------------------------------------
// Chunked scan, pass A: one thread per (channel, chunk); 16 states in regs.
// hend written as bf16 (2 x ushort8).
// ---------------------------------------------------------------------------
__global__ __launch_bounds__(256)
void scan_partial_kernel(const ushort_t* __restrict__ dtb, const float* __restrict__ xdbl,
                         const ushort_t* __restrict__ u2bf,
                         const float* __restrict__ A_log,
                         ushort_t* __restrict__ hend, float* __restrict__ sumdt_buf)
{
    int idx = blockIdx.x * 256 + threadIdx.x;   // 0 .. NCHAN*NCHUNK-1
    int p = idx & (NCHAN - 1);                  // channel (64 consecutive/wave)
    int c = idx >> 12;                          // chunk
    int b = p >> 11, e = p & (D_INNER - 1);

    float An[D_STATE];
    {
        const float4* ar = reinterpret_cast<const float4*>(A_log + (size_t)e * D_STATE);
        #pragma unroll
        for (int q = 0; q < 4; ++q) {
            float4 a4 = ar[q];
            An[q * 4 + 0] = -__expf(a4.x);
            An[q * 4 + 1] = -__expf(a4.y);
            An[q * 4 + 2] = -__expf(a4.z);
            An[q * 4 + 3] = -__expf(a4.w);
        }
    }
    float h[D_STATE];
    #pragma unroll
    for (int n = 0; n < D_STATE; ++n) h[n] = 0.f;
    float sdt = 0.f;

    size_t rowbase = (size_t)b * SEQLEN + c * LCHUNK;
    #pragma unroll
    for (int j = 0; j < LCHUNK; ++j) {
        size_t row = rowbase + j;
        float dt = bf2f(dtb[row * D_INNER + e]);
        float u  = bf2f(u2bf[row * D_INNER + e]);
        float dtu = dt * u;
        sdt += dt;
        const float4* xr = reinterpret_cast<const float4*>(xdbl + row * XDBL_W + DT_RANK);
        float Bv[D_STATE];
        #pragma unroll
        for (int q = 0; q < 4; ++q) {
            float4 b4 = xr[q];
            Bv[q * 4 + 0] = b4.x; Bv[q * 4 + 1] = b4.y;
            Bv[q * 4 + 2] = b4.z; Bv[q * 4 + 3] = b4.w;
        }
        #pragma unroll
        for (int n = 0; n < D_STATE; ++n)
            h[n] = __expf(dt * An[n]) * h[n] + dtu * Bv[n];
    }

    ushort8v o0, o1;
    #pragma unroll
    for (int q = 0; q < 8; ++q) { o0[q] = f2bf(h[q]); o1[q] = f2bf(h[8 + q]); }
    ushort8v* hp = reinterpret_cast<ushort8v*>(hend + ((size_t)p * NCHUNK + c) * D_STATE);
    hp[0] = o0; hp[1] = o1;
    sumdt_buf[p * NCHUNK + c] = sdt;
}

// ---------------------------------------------------------------------------
// Pass B: per-channel inter-chunk Hillis-Steele scan (fp32 in LDS);
// reads bf16 hend, writes bf16 exclusive carry in place.
// ---------------------------------------------------------------------------
__global__ __launch_bounds__(1024)
void scan_combine_kernel(const float* __restrict__ A_log,
                         const float* __restrict__ sumdt_buf,
                         ushort_t* __restrict__ hend /* in: hend, out: hcarry */)
{
    __shared__ float Ps[NCHUNK][D_STATE];
    __shared__ float Hs[NCHUNK][D_STATE];
    int tid = threadIdx.x;
    int c = tid >> 4, n = tid & 15;
    int p = blockIdx.x;
    int e = p & (D_INNER - 1);
    float An = -__expf(A_log[e * D_STATE + n]);
    float P = __expf(An * sumdt_buf[p * NCHUNK + c]);
    float H = bf2f(hend[(size_t)p * (NCHUNK * D_STATE) + c * D_STATE + n]);
    Ps[c][n] = P; Hs[c][n] = H;
    __syncthreads();
    #pragma unroll
    for (int d = 1; d < NCHUNK; d <<= 1) {
        float Pl = 1.f, Hl = 0.f;
        if (c >= d) { Pl = Ps[c - d][n]; Hl = Hs[c - d][n]; }
        __syncthreads();
        H = P * Hl + H;   // (P,H) o (Pl,Hl)
        P = P * Pl;
        Ps[c][n] = P; Hs[c][n] = H;
        __syncthreads();
    }
    float carry = (c == 0) ? 0.f : Hs[c - 1][n];
    hend[(size_t)p * (NCHUNK * D_STATE) + c * D_STATE + n] = f2bf(carry);
}

// ---------------------------------------------------------------------------
// Pass C: one thread per (channel, chunk), seeded with bf16 carry; in-register
// dot with C row; fused D-skip + SiLU(z) gate; writes y as bf16.
// ---------------------------------------------------------------------------
__global__ __launch_bounds__(256)
void scan_final_kernel(const ushort_t* __restrict__ dtb, const float* __restrict__ xdbl,
                       const ushort_t* __restrict__ xzbf, const ushort_t* __restrict__ u2bf,
                       ushort_t* __restrict__ ybf,
                       const float* __restrict__ A_log,
                       const float* __restrict__ D_param,
                       const ushort_t* __restrict__ hcarry)
{
    int idx = blockIdx.x * 256 + threadIdx.x;
    int p = idx & (NCHAN - 1);
    int c = idx >> 12;
    int b = p >> 11, e = p & (D_INNER - 1);
    float De = D_param[e];

    float An[D_STATE];
    {
        const float4* ar = reinterpret_cast<const float4*>(A_log + (size_t)e * D_STATE);
        #pragma unroll
        for (int q = 0; q < 4; ++q) {
            float4 a4 = ar[q];
            An[q * 4 + 0] = -__expf(a4.x);
            An[q * 4 + 1] = -__expf(a4.y);
            An[q * 4 + 2] = -__expf(a4.z);
            An[q * 4 + 3] = -__expf(a4.w);
        }
    }
    float h[D_STATE];
    {
        const ushort8v* hp = reinterpret_cast<const ushort8v*>(
            hcarry + ((size_t)p * NCHUNK + c) * D_STATE);
        ushort8v h0 = hp[0], h1 = hp[1];
        #pragma unroll
        for (int q = 0; q < 8; ++q) { h[q] = bf2f(h0[q]); h[8 + q] = bf2f(h1[q]); }
    }

    size_t rowbase = (size_t)b * SEQLEN + c * LCHUNK;
    #pragma unroll
    for (int j = 0; j < LCHUNK; ++j) {
        size_t row = rowbase + j;
        float dt = bf2f(dtb[row * D_INNER + e]);
        float u  = bf2f(u2bf[row * D_INNER + e]);
        float dtu = dt * u;
        const float4* xr = reinterpret_cast<const float4*>(xdbl + row * XDBL_W + DT_RANK);
        float Bv[D_STATE], Cv[D_STATE];
        #pragma unroll
        for (int q = 0; q < 4; ++q) {
            float4 b4 = xr[q];
            Bv[q * 4 + 0] = b4.x; Bv[q * 4 + 1] = b4.y;
            Bv[q * 4 + 2] = b4.z; Bv[q * 4 + 3] = b4.w;
            float4 c4 = xr[q + 4];
            Cv[q * 4 + 0] = c4.x; Cv[q * 4 + 1] = c4.y;
            Cv[q * 4 + 2] = c4.z; Cv[q * 4 + 3] = c4.w;
        }
        float y = 0.f;
        #pragma unroll
        for (int n = 0; n < D_STATE; ++n) {
            h[n] = __expf(dt * An[n]) * h[n] + dtu * Bv[n];
            y += h[n] * Cv[n];
        }
        float z  = bf2f(xzbf[row * (2 * D_INNER) + D_INNER + e]);
        float sz = z * fast_sigmoid(z);
        ybf[row * D_INNER + e] = f2bf((y + u * De) * sz);
    }
}

// ---------------------------------------------------------------------------
extern "C" void kernel_launch(void* const* d_in, const int* in_sizes, int n_in,
                              void* d_out, int out_size, void* d_ws, size_t ws_size,
                              hipStream_t stream)
{
    const float* x       = (const float*)d_in[0];
    const float* ln_g    = (const float*)d_in[1];
    const float* ln_b    = (const float*)d_in[2];
    const float* W_in    = (const float*)d_in[3];
    const float* conv_w  = (const float*)d_in[4];
    const float* conv_b  = (const float*)d_in[5];
    const float* W_xp    = (const float*)d_in[6];
    const float* W_dt    = (const float*)d_in[7];
    const float* b_dt    = (const float*)d_in[8];
    const float* A_log   = (const float*)d_in[9];
    const float* D_param = (const float*)d_in[10];
    const float* W_out   = (const float*)d_in[11];
    const float* res_sc  = (const float*)d_in[12];
    float* out = (float*)d_out;

    char* ws = (char*)d_ws;
    const size_t MB = 1024 * 1024;
    // Workspace (peak 82 MB):
    //   xzbf    [0,16M)      2048x4096 bf16 (u cols 0-2047, z cols 2048-4095)
    //   u2bf    [16M,24M)    2048x2048 bf16
    //   dtb16   [24M,32M)    2048x2048 bf16 (softplus'd dt)
    //   xdbl    [32M,33M)    2048x96 fp32
    //   xdbl64  [33M,34M)    2048x64 bf16 (dt_lo, A-operand for dt GEMM)
    //   hend    [34M,42M)    4096x64x16 bf16 (carry in place)
    //   sumdt   [50M,51M)    4096x64 fp32
    //   xnbf    [51M,55M)    2048x1024 bf16
    //   WtIn    [55M,63M)    4096x1024 bf16
    //   WtOut   [63M,67M)    1024x2048 bf16
    //   WtXp    [67M,67.5M)  128x2048 bf16 (rows 96..127 zeroed via col guard)
    //   WtDt    [67.5M,68M)  2048x64 bf16
    //   ybf     [68M,76M)    2048x2048 bf16
    //   partsX  [76M,82M)    8x2048x96 fp32
    ushort_t* xzbf   = (ushort_t*)(ws);
    ushort_t* u2bf   = (ushort_t*)(ws + 16 * MB);
    ushort_t* dtb16  = (ushort_t*)(ws + 24 * MB);
    float*    xdbl   = (float*)(ws + 32 * MB);
    ushort_t* xdbl64 = (ushort_t*)(ws + 33 * MB);
    ushort_t* hend   = (ushort_t*)(ws + 34 * MB);
    float*    sumdt  = (float*)(ws + 50 * MB);
    ushort_t* xnbf   = (ushort_t*)(ws + 51 * MB);
    ushort_t* WtIn   = (ushort_t*)(ws + 55 * MB);
    ushort_t* WtOut  = (ushort_t*)(ws + 63 * MB);
    ushort_t* WtXp   = (ushort_t*)(ws + 67 * MB);
    ushort_t* WtDt   = (ushort_t*)(ws + 67 * MB + 512 * 1024);
    ushort_t* ybf    = (ushort_t*)(ws + 68 * MB);
    float*    partsX = (float*)(ws + 76 * MB);

    // 0+1. mega-prologue: LayerNorm + all weight transposes (+WtXp pad)
    prologue_kernel<<<PRO_TOTAL, 256, 0, stream>>>(
        x, ln_g, ln_b, xnbf, W_in, WtIn, W_out, WtOut, W_xp, WtXp, W_dt, WtDt);

    // 2. xz = xn @ W_in   [2048 x 4096, K=1024]  (bf16 MFMA, BK=64, swizzled)
    gemm_xz<<<512, 256, 0, stream>>>(xnbf, WtIn, xzbf);

    // 3. u2 = silu(causal_conv(u) + conv_b)   (bf16, x4 vectorized)
    conv_silu_kernel<<<(BATCH * SEQLEN * D_INNER) / 1024, 256, 0, stream>>>(
        xzbf, conv_w, conv_b, u2bf);

    // 4. xdbl = u2 @ W_xp  [2048 x 96, K=2048]  64-row-tile split-K x8 + reduce
    {
        dim3 grid(1, NROWS / 64, KSPLIT_XDBL);
        gemm_xdbl64<<<grid, 256, 0, stream>>>(u2bf, WtXp, partsX);
        reduce_partials_kernel<<<(NROWS * XDBL_W + 255) / 256, 256, 0, stream>>>(
            partsX, xdbl, xdbl64, NROWS * XDBL_W);
    }

    // 5. dt = softplus(dt_lo @ W_dt + b_dt)  [2048 x 2048, K=64]  (bf16 MFMA)
    {
        dim3 grid(D_INNER / 128, NROWS / 128);
        gemm_bf16_dt<<<grid, 256, 0, stream>>>(xdbl64, WtDt, dtb16, b_dt);
    }

    // 6. chunked parallel scan (A: partials, B: inter-chunk, C: final+gate)
    scan_partial_kernel<<<(NCHAN * NCHUNK) / 256, 256, 0, stream>>>(
        dtb16, xdbl, u2bf, A_log, hend, sumdt);
    scan_combine_kernel<<<NCHAN, 1024, 0, stream>>>(A_log, sumdt, hend);
    scan_final_kernel<<<(NCHAN * NCHUNK) / 256, 256, 0, stream>>>(
        dtb16, xdbl, xzbf, u2bf, ybf, A_log, D_param, hend);

    // 7. out = x + rs * (y @ W_out)  [2048 x 1024, K=2048]  64x64 BK=64 direct
    gemm_out64<<<512, 256, 0, stream>>>(ybf, WtOut, x, res_sc, out);
}